// Round 2
// baseline (3214.006 us; speedup 1.0000x reference)
//
#include <hip/hip_runtime.h>
#include <math.h>

#define BS_ 2
#define V_ 4
#define H_ 24
#define W_ 24
#define N_ (V_*H_*W_)        // 2304
#define BN_ (BS_*N_)         // 4608
#define C_ 256
#define K_ 16
#define L_ 6
#define NH_ 8
#define DH_ 32
#define FF_ 1024

// ---------------- reshape in: (B*V,C,H,W) -> (BN, C) ----------------
__global__ __launch_bounds__(256) void reshape_in_kernel(const float* __restrict__ f,
                                                         float* __restrict__ out) {
    int bn = blockIdx.x, c = threadIdx.x;
    int b = bn / N_, rem = bn % N_;
    int v = rem / (H_*W_), hw = rem % (H_*W_);
    out[(size_t)bn*C_ + c] = f[(((size_t)(b*V_ + v)*C_ + c)*(H_*W_)) + hw];
}

// ---------------- reshape out: (BN, C) -> (B*V,C,H,W) ----------------
__global__ __launch_bounds__(256) void reshape_out_kernel(const float* __restrict__ in,
                                                          float* __restrict__ o) {
    int bn = blockIdx.x, c = threadIdx.x;
    int b = bn / N_, rem = bn % N_;
    int v = rem / (H_*W_), hw = rem % (H_*W_);
    o[(((size_t)(b*V_ + v)*C_ + c)*(H_*W_)) + hw] = in[(size_t)bn*C_ + c];
}

// ---------------- KNN: one block per query point ----------------
__global__ __launch_bounds__(256) void knn_kernel(const float* __restrict__ pts,
                                                  int* __restrict__ idx) {
    int point = blockIdx.x;            // 0..BN-1
    int b = point / N_;
    int il = point - b*N_;
    __shared__ float ps[N_*3];
    __shared__ unsigned long long red[4];
    __shared__ int winner;
    int tid = threadIdx.x;
    for (int l = tid; l < N_*3; l += 256) ps[l] = pts[(size_t)b*N_*3 + l];
    __syncthreads();
    float qx = ps[il*3], qy = ps[il*3+1], qz = ps[il*3+2];
    float d2[9];
    #pragma unroll
    for (int s = 0; s < 9; ++s) {
        int j = tid + s*256;
        float dx = qx - ps[j*3], dy = qy - ps[j*3+1], dz = qz - ps[j*3+2];
        d2[s] = dx*dx + dy*dy + dz*dz;
    }
    unsigned sel = 0;
    for (int it = 0; it < K_; ++it) {
        unsigned long long best = ~0ull;
        #pragma unroll
        for (int s = 0; s < 9; ++s) {
            if (sel & (1u << s)) continue;
            unsigned fb = __float_as_uint(d2[s]);
            unsigned long long key = ((unsigned long long)fb << 32) | (unsigned)(tid + s*256);
            if (key < best) best = key;
        }
        #pragma unroll
        for (int off = 32; off; off >>= 1) {
            unsigned long long o = __shfl_xor(best, off, 64);
            if (o < best) best = o;
        }
        if ((tid & 63) == 0) red[tid >> 6] = best;
        __syncthreads();
        if (tid == 0) {
            unsigned long long w0 = red[0] < red[1] ? red[0] : red[1];
            unsigned long long w1 = red[2] < red[3] ? red[2] : red[3];
            unsigned long long w = w0 < w1 ? w0 : w1;
            winner = (int)(w & 0xffffffffull);
            idx[point*K_ + it] = b*N_ + winner;
        }
        __syncthreads();
        int wj = winner;
        if ((wj & 255) == tid) sel |= 1u << (wj >> 8);
        __syncthreads();
    }
}

// ---------------- q_pe = relu(0@W1^T + b1)@W2^T + b2 ----------------
__global__ __launch_bounds__(256) void qpe_kernel(const float* __restrict__ b1,
                                                  const float* __restrict__ W2,
                                                  const float* __restrict__ b2,
                                                  float* __restrict__ qpe) {
    __shared__ float h[C_];
    int tid = threadIdx.x;
    h[tid] = fmaxf(b1[tid], 0.f);
    __syncthreads();
    float acc = 0.f;
    for (int j = 0; j < C_; ++j) acc += h[j] * W2[(size_t)tid*C_ + j];
    qpe[tid] = acc + b2[tid];
}

// ---------------- PE hidden: hidden[row][c] = relu(rel . W1[c] + b1[c]) ----------------
__global__ __launch_bounds__(256) void pe_hidden_kernel(const float* __restrict__ pts,
                                                        const int* __restrict__ idx,
                                                        const float* __restrict__ W1,
                                                        const float* __restrict__ b1,
                                                        float* __restrict__ hidden) {
    int row = blockIdx.x;               // 0..BN*K-1
    int point = row >> 4;
    __shared__ float rel[3];
    if (threadIdx.x < 3) {
        int j = idx[row];
        rel[threadIdx.x] = pts[(size_t)j*3 + threadIdx.x] - pts[(size_t)point*3 + threadIdx.x];
    }
    __syncthreads();
    int c = threadIdx.x;
    float v = rel[0]*W1[c*3+0] + rel[1]*W1[c*3+1] + rel[2]*W1[c*3+2] + b1[c];
    hidden[(size_t)row*C_ + c] = fmaxf(v, 0.f);
}

// ---------------- generic fp32 GEMM: OUT = act(A @ W^T + bias) (+res) ----------------
// A: M x Cin row-major; W: P x Cin row-major; OUT: M x P
template<int ACT, bool RES>
__global__ __launch_bounds__(256) void gemm_tn(const float* __restrict__ A,
                                               const float* __restrict__ W,
                                               const float* __restrict__ bias,
                                               const float* __restrict__ res,
                                               float* __restrict__ OUT,
                                               int M, int P, int Cin) {
    const int TM = 64, TN = 64, TK = 16;
    __shared__ float As[TK][TM+1];
    __shared__ float Ws[TK][TN+1];
    int tid = threadIdx.x;
    int tx = tid & 15, ty = tid >> 4;
    int m0 = blockIdx.y * TM, n0 = blockIdx.x * TN;
    float acc[4][4] = {};
    for (int k0 = 0; k0 < Cin; k0 += TK) {
        for (int l = tid; l < TM*TK; l += 256) {
            int r = l >> 4, kk = l & 15;
            int kg = k0 + kk;
            As[kk][r] = (kg < Cin) ? A[(size_t)(m0 + r)*Cin + kg] : 0.f;
        }
        for (int l = tid; l < TN*TK; l += 256) {
            int r = l >> 4, kk = l & 15;
            int kg = k0 + kk;
            Ws[kk][r] = (kg < Cin) ? W[(size_t)(n0 + r)*Cin + kg] : 0.f;
        }
        __syncthreads();
        #pragma unroll
        for (int kk = 0; kk < TK; ++kk) {
            float a[4], w[4];
            #pragma unroll
            for (int i = 0; i < 4; ++i) a[i] = As[kk][ty + 16*i];
            #pragma unroll
            for (int j = 0; j < 4; ++j) w[j] = Ws[kk][tx + 16*j];
            #pragma unroll
            for (int i = 0; i < 4; ++i)
                #pragma unroll
                for (int j = 0; j < 4; ++j) acc[i][j] += a[i]*w[j];
        }
        __syncthreads();
    }
    #pragma unroll
    for (int i = 0; i < 4; ++i) {
        int m = m0 + ty + 16*i;
        #pragma unroll
        for (int j = 0; j < 4; ++j) {
            int p = n0 + tx + 16*j;
            float v = acc[i][j] + bias[p];
            if (ACT == 1) v = fmaxf(v, 0.f);
            if (RES) v += res[(size_t)m*P + p];
            OUT[(size_t)m*P + p] = v;
        }
    }
}

// ---------------- r[point][h][cin] = sum_d q[point][h*DH+d] * Wk[h*DH+d][cin] ----------------
__global__ __launch_bounds__(256) void r_kernel(const float* __restrict__ q,
                                                const float* __restrict__ Wk,
                                                float* __restrict__ r) {
    int p0 = blockIdx.x * 16;
    int h = blockIdx.y;
    int tid = threadIdx.x;  // cin
    __shared__ float qs[16][DH_];
    for (int l = tid; l < 16*DH_; l += 256) {
        int p = l >> 5, d = l & 31;
        qs[p][d] = q[(size_t)(p0 + p)*C_ + h*DH_ + d];
    }
    __syncthreads();
    float acc[16] = {};
    for (int d = 0; d < DH_; ++d) {
        float w = Wk[(size_t)(h*DH_ + d)*C_ + tid];
        #pragma unroll
        for (int p = 0; p < 16; ++p) acc[p] += qs[p][d] * w;
    }
    #pragma unroll
    for (int p = 0; p < 16; ++p)
        r[(size_t)(p0 + p)*(NH_*C_) + h*C_ + tid] = acc[p];
}

// ---------------- attention: one block per point ----------------
__global__ __launch_bounds__(256) void attn_kernel(const float* __restrict__ q,
                                                   const float* __restrict__ ok,
                                                   const float* __restrict__ ov,
                                                   const float* __restrict__ kpe,
                                                   const float* __restrict__ r,
                                                   const int* __restrict__ idx,
                                                   float* __restrict__ ao) {
    int point = blockIdx.x;
    int tid = threadIdx.x;
    int h = tid >> 5, d = tid & 31;
    __shared__ float kpes[K_][C_];
    __shared__ float rs[NH_][C_];
    __shared__ float qs[C_];
    __shared__ int idxs[K_];
    __shared__ float ss[NH_][K_];
    __shared__ float atts[NH_][K_];
    qs[tid] = q[(size_t)point*C_ + tid];
    for (int l = tid; l < K_*C_; l += 256) kpes[l >> 8][l & 255] = kpe[(size_t)point*K_*C_ + l];
    for (int l = tid; l < NH_*C_; l += 256) rs[l >> 8][l & 255] = r[(size_t)point*NH_*C_ + l];
    if (tid < K_) idxs[tid] = idx[point*K_ + tid];
    __syncthreads();
    const float scale = 0.1767766952966369f;  // 1/sqrt(32)
    for (int k = 0; k < K_; ++k) {
        int j = idxs[k];
        float s1 = qs[h*DH_ + d] * ok[(size_t)j*C_ + h*DH_ + d];
        float s2 = 0.f;
        #pragma unroll
        for (int t = 0; t < 8; ++t) s2 += rs[h][d + 32*t] * kpes[k][d + 32*t];
        float v = s1 + s2;
        #pragma unroll
        for (int off = 16; off; off >>= 1) v += __shfl_xor(v, off, 32);
        if (d == 0) ss[h][k] = v * scale;
    }
    __syncthreads();
    if (tid < NH_*K_) {
        int hh = tid >> 4, k = tid & 15;
        float v = ss[hh][k];
        float m = v;
        #pragma unroll
        for (int off = 8; off; off >>= 1) m = fmaxf(m, __shfl_xor(m, off, 16));
        float e = expf(v - m);
        float sm = e;
        #pragma unroll
        for (int off = 8; off; off >>= 1) sm += __shfl_xor(sm, off, 16);
        atts[hh][k] = e / sm;
    }
    __syncthreads();
    float acc = 0.f;
    #pragma unroll
    for (int k = 0; k < K_; ++k) acc += atts[h][k] * ov[(size_t)idxs[k]*C_ + tid];
    ao[(size_t)point*C_ + tid] = acc;
}

// ---------------- LayerNorm: one block per row (256 cols) ----------------
__global__ __launch_bounds__(256) void ln_kernel(const float* __restrict__ in,
                                                 const float* __restrict__ w,
                                                 const float* __restrict__ b,
                                                 const float* __restrict__ addvec,
                                                 float* __restrict__ out) {
    int row = blockIdx.x, tid = threadIdx.x;
    float x = in[(size_t)row*C_ + tid];
    __shared__ float red[4];
    float v = x;
    #pragma unroll
    for (int off = 32; off; off >>= 1) v += __shfl_xor(v, off, 64);
    if ((tid & 63) == 0) red[tid >> 6] = v;
    __syncthreads();
    float mean = (red[0]+red[1]+red[2]+red[3]) * (1.f/C_);
    __syncthreads();
    float dx = x - mean;
    v = dx*dx;
    #pragma unroll
    for (int off = 32; off; off >>= 1) v += __shfl_xor(v, off, 64);
    if ((tid & 63) == 0) red[tid >> 6] = v;
    __syncthreads();
    float var = (red[0]+red[1]+red[2]+red[3]) * (1.f/C_);
    float y = dx * rsqrtf(var + 1e-5f) * w[tid] + b[tid];
    if (addvec) y += addvec[tid];
    out[(size_t)row*C_ + tid] = y;
}

extern "C" void kernel_launch(void* const* d_in, const int* in_sizes, int n_in,
                              void* d_out, int out_size, void* d_ws, size_t ws_size,
                              hipStream_t stream) {
    const float* feature  = (const float*)d_in[0];
    const float* xyz      = (const float*)d_in[1];   // (BN, 3) flat
    const float* pe_W1    = (const float*)d_in[2];
    const float* pe_b1    = (const float*)d_in[3];
    const float* pe_W2    = (const float*)d_in[4];
    const float* pe_b2    = (const float*)d_in[5];
    const float* Wqkv     = (const float*)d_in[6];
    const float* bqkv     = (const float*)d_in[7];
    const float* Wo       = (const float*)d_in[8];
    const float* bo       = (const float*)d_in[9];
    const float* ln_attn_w= (const float*)d_in[10];
    const float* ln_attn_b= (const float*)d_in[11];
    const float* W1       = (const float*)d_in[12];
    const float* b1       = (const float*)d_in[13];
    const float* W2       = (const float*)d_in[14];
    const float* b2       = (const float*)d_in[15];
    const float* ln_ffn_w = (const float*)d_in[16];
    const float* ln_ffn_b = (const float*)d_in[17];
    const float* ln_out_w = (const float*)d_in[18];
    const float* ln_out_b = (const float*)d_in[19];

    // ---- workspace layout (floats) ----
    float* ws = (float*)d_ws;
    float* w_out = ws;                       // BN*C        = 1,179,648
    float* w_kpe = w_out + (size_t)BN_*C_;   // BN*K*C      = 18,874,368
    float* w_r   = w_kpe + (size_t)BN_*K_*C_;// BN*NH*C     =  9,437,184
    float* w_ffh = w_r   + (size_t)BN_*NH_*C_;// BN*FF      =  4,718,592
    float* w_ao  = w_ffh + (size_t)BN_*FF_;  // BN*C
    float* w_q   = w_ao  + (size_t)BN_*C_;   // BN*C
    float* w_t2  = w_q   + (size_t)BN_*C_;   // BN*C
    float* w_ok  = w_t2  + (size_t)BN_*C_;   // BN*C
    float* w_ov  = w_ok  + (size_t)BN_*C_;   // BN*C
    float* w_qpe = w_ov  + (size_t)BN_*C_;   // C
    int*   w_idx = (int*)(w_qpe + C_);       // BN*K ints
    float* w_hidden = w_r;                   // alias: spans r..ok (exactly BN*K*C floats)

    // ---- preprocessing ----
    reshape_in_kernel<<<BN_, 256, 0, stream>>>(feature, w_out);
    knn_kernel<<<BN_, 256, 0, stream>>>(xyz, w_idx);
    qpe_kernel<<<1, 256, 0, stream>>>(pe_b1, pe_W2, pe_b2, w_qpe);
    pe_hidden_kernel<<<BN_*K_, 256, 0, stream>>>(xyz, w_idx, pe_W1, pe_b1, w_hidden);
    gemm_tn<0,false><<<dim3(C_/64, (BN_*K_)/64), 256, 0, stream>>>(
        w_hidden, pe_W2, pe_b2, nullptr, w_kpe, BN_*K_, C_, C_);

    // ---- layers ----
    for (int i = 0; i < L_; ++i) {
        const float* Wq = Wqkv + (size_t)i*3*C_*C_;
        const float* Wk = Wq + (size_t)C_*C_;
        const float* Wv = Wk + (size_t)C_*C_;
        const float* bq = bqkv + (size_t)i*3*C_;
        const float* bk = bq + C_;
        const float* bv = bq + 2*C_;

        ln_kernel<<<BN_, 256, 0, stream>>>(w_out, ln_attn_w + i*C_, ln_attn_b + i*C_, w_qpe, w_t2);
        gemm_tn<0,false><<<dim3(C_/64, BN_/64), 256, 0, stream>>>(w_t2, Wq, bq, nullptr, w_q, BN_, C_, C_);
        gemm_tn<0,false><<<dim3(C_/64, BN_/64), 256, 0, stream>>>(w_out, Wk, bk, nullptr, w_ok, BN_, C_, C_);
        gemm_tn<0,false><<<dim3(C_/64, BN_/64), 256, 0, stream>>>(w_out, Wv, bv, nullptr, w_ov, BN_, C_, C_);
        r_kernel<<<dim3(BN_/16, NH_), 256, 0, stream>>>(w_q, Wk, w_r);
        attn_kernel<<<BN_, 256, 0, stream>>>(w_q, w_ok, w_ov, w_kpe, w_r, w_idx, w_ao);
        gemm_tn<0,true><<<dim3(C_/64, BN_/64), 256, 0, stream>>>(
            w_ao, Wo + (size_t)i*C_*C_, bo + i*C_, w_out, w_out, BN_, C_, C_);

        ln_kernel<<<BN_, 256, 0, stream>>>(w_out, ln_ffn_w + i*C_, ln_ffn_b + i*C_, nullptr, w_t2);
        gemm_tn<1,false><<<dim3(FF_/64, BN_/64), 256, 0, stream>>>(
            w_t2, W1 + (size_t)i*FF_*C_, b1 + i*FF_, nullptr, w_ffh, BN_, FF_, C_);
        gemm_tn<0,true><<<dim3(C_/64, BN_/64), 256, 0, stream>>>(
            w_ffh, W2 + (size_t)i*C_*FF_, b2 + i*C_, w_out, w_out, BN_, C_, FF_);
        ln_kernel<<<BN_, 256, 0, stream>>>(w_out, ln_out_w + i*C_, ln_out_b + i*C_, nullptr, w_out);
    }

    reshape_out_kernel<<<BN_, 256, 0, stream>>>(w_out, (float*)d_out);
}

// Round 3
// 989.874 us; speedup vs baseline: 3.2469x; 3.2469x over previous
//
#include <hip/hip_runtime.h>
#include <math.h>

#define BS_ 2
#define V_ 4
#define H_ 24
#define W_ 24
#define N_ (V_*H_*W_)        // 2304
#define BN_ (BS_*N_)         // 4608
#define C_ 256
#define K_ 16
#define L_ 6
#define NH_ 8
#define DH_ 32
#define FF_ 1024

typedef __attribute__((ext_vector_type(4))) float f32x4;
typedef __attribute__((ext_vector_type(8))) short bf16x8;

__device__ inline unsigned short f2bf(float x) {
    unsigned u = __float_as_uint(x);
    unsigned r = u + 0x7fffu + ((u >> 16) & 1u);
    return (unsigned short)(r >> 16);
}
__device__ inline float bf2f(unsigned short h) {
    return __uint_as_float(((unsigned)h) << 16);
}

// ---------------- fp32 -> bf16 elementwise ----------------
__global__ __launch_bounds__(256) void f2bf_kernel(const float* __restrict__ in,
                                                   unsigned short* __restrict__ out, int n) {
    int i = blockIdx.x*256 + threadIdx.x;
    if (i < n) out[i] = f2bf(in[i]);
}

// ---------------- reshape in: (B*V,C,H,W) -> (BN, C) fp32 + bf16 ----------------
__global__ __launch_bounds__(256) void reshape_in_kernel(const float* __restrict__ f,
                                                         float* __restrict__ outF,
                                                         unsigned short* __restrict__ outB) {
    int bn = blockIdx.x, c = threadIdx.x;
    int b = bn / N_, rem = bn % N_;
    int v = rem / (H_*W_), hw = rem % (H_*W_);
    float x = f[(((size_t)(b*V_ + v)*C_ + c)*(H_*W_)) + hw];
    outF[(size_t)bn*C_ + c] = x;
    outB[(size_t)bn*C_ + c] = f2bf(x);
}

// ---------------- reshape out: (BN, C) -> (B*V,C,H,W) ----------------
__global__ __launch_bounds__(256) void reshape_out_kernel(const float* __restrict__ in,
                                                          float* __restrict__ o) {
    int bn = blockIdx.x, c = threadIdx.x;
    int b = bn / N_, rem = bn % N_;
    int v = rem / (H_*W_), hw = rem % (H_*W_);
    o[(((size_t)(b*V_ + v)*C_ + c)*(H_*W_)) + hw] = in[(size_t)bn*C_ + c];
}

// ---------------- KNN: one block per query point ----------------
__global__ __launch_bounds__(256) void knn_kernel(const float* __restrict__ pts,
                                                  int* __restrict__ idx) {
    int point = blockIdx.x;            // 0..BN-1
    int b = point / N_;
    int il = point - b*N_;
    __shared__ float ps[N_*3];
    __shared__ unsigned long long red[4];
    __shared__ int winner;
    int tid = threadIdx.x;
    for (int l = tid; l < N_*3; l += 256) ps[l] = pts[(size_t)b*N_*3 + l];
    __syncthreads();
    float qx = ps[il*3], qy = ps[il*3+1], qz = ps[il*3+2];
    float d2[9];
    #pragma unroll
    for (int s = 0; s < 9; ++s) {
        int j = tid + s*256;
        float dx = qx - ps[j*3], dy = qy - ps[j*3+1], dz = qz - ps[j*3+2];
        d2[s] = dx*dx + dy*dy + dz*dz;
    }
    unsigned sel = 0;
    for (int it = 0; it < K_; ++it) {
        unsigned long long best = ~0ull;
        #pragma unroll
        for (int s = 0; s < 9; ++s) {
            if (sel & (1u << s)) continue;
            unsigned fb = __float_as_uint(d2[s]);
            unsigned long long key = ((unsigned long long)fb << 32) | (unsigned)(tid + s*256);
            if (key < best) best = key;
        }
        #pragma unroll
        for (int off = 32; off; off >>= 1) {
            unsigned long long o = __shfl_xor(best, off, 64);
            if (o < best) best = o;
        }
        if ((tid & 63) == 0) red[tid >> 6] = best;
        __syncthreads();
        if (tid == 0) {
            unsigned long long w0 = red[0] < red[1] ? red[0] : red[1];
            unsigned long long w1 = red[2] < red[3] ? red[2] : red[3];
            unsigned long long w = w0 < w1 ? w0 : w1;
            winner = (int)(w & 0xffffffffull);
            idx[point*K_ + it] = b*N_ + winner;
        }
        __syncthreads();
        int wj = winner;
        if ((wj & 255) == tid) sel |= 1u << (wj >> 8);
        __syncthreads();
    }
}

// ---------------- q_pe = relu(b1)@W2^T + b2 (fp32, tiny) ----------------
__global__ __launch_bounds__(256) void qpe_kernel(const float* __restrict__ b1,
                                                  const float* __restrict__ W2,
                                                  const float* __restrict__ b2,
                                                  float* __restrict__ qpe) {
    __shared__ float h[C_];
    int tid = threadIdx.x;
    h[tid] = fmaxf(b1[tid], 0.f);
    __syncthreads();
    float acc = 0.f;
    for (int j = 0; j < C_; ++j) acc += h[j] * W2[(size_t)tid*C_ + j];
    qpe[tid] = acc + b2[tid];
}

// ---------------- PE hidden (bf16 out): hidden[row][c] = relu(rel . W1[c] + b1[c]) ----------------
__global__ __launch_bounds__(256) void pe_hidden_kernel(const float* __restrict__ pts,
                                                        const int* __restrict__ idx,
                                                        const float* __restrict__ W1,
                                                        const float* __restrict__ b1,
                                                        unsigned short* __restrict__ hidden) {
    int row = blockIdx.x;               // 0..BN*K-1
    int point = row >> 4;
    __shared__ float rel[3];
    if (threadIdx.x < 3) {
        int j = idx[row];
        rel[threadIdx.x] = pts[(size_t)j*3 + threadIdx.x] - pts[(size_t)point*3 + threadIdx.x];
    }
    __syncthreads();
    int c = threadIdx.x;
    float v = rel[0]*W1[c*3+0] + rel[1]*W1[c*3+1] + rel[2]*W1[c*3+2] + b1[c];
    hidden[(size_t)row*C_ + c] = f2bf(fmaxf(v, 0.f));
}

// ---------------- bf16 MFMA GEMM: OUT = act(A @ W^T + bias) (+res) ----------------
// A: M x K bf16 row-major; W: P x K bf16 row-major.
// OMODE: 0 = fp32 only, 1 = fp32 + bf16, 2 = bf16 only
template<int ACT, bool RES, int OMODE>
__global__ __launch_bounds__(256) void gemm_bf16(const unsigned short* __restrict__ A,
                                                 const unsigned short* __restrict__ W,
                                                 const float* __restrict__ bias,
                                                 const float* __restrict__ res,
                                                 float* __restrict__ outF,
                                                 unsigned short* __restrict__ outB,
                                                 int M, int P, int K) {
    const int BM = 128, BN = 64, BK = 32;
    __shared__ unsigned short As[BM][BK+8];
    __shared__ unsigned short Ws[BN][BK+8];
    int tid = threadIdx.x;
    int wave = tid >> 6, lane = tid & 63;
    int wr = wave >> 1, wc = wave & 1;           // 2x2 waves, wave tile 64x32
    int m0 = blockIdx.y * BM, n0 = blockIdx.x * BN;
    f32x4 acc[4][2];
    #pragma unroll
    for (int i = 0; i < 4; ++i)
        #pragma unroll
        for (int j = 0; j < 2; ++j) acc[i][j] = (f32x4){0.f, 0.f, 0.f, 0.f};

    for (int k0 = 0; k0 < K; k0 += BK) {
        #pragma unroll
        for (int i = 0; i < 2; ++i) {
            int id = tid + i*256;
            int r = id >> 2, ch = id & 3;
            bf16x8 v = *(const bf16x8*)&A[(size_t)(m0 + r)*K + k0 + ch*8];
            *(bf16x8*)&As[r][ch*8] = v;
        }
        {
            int r = tid >> 2, ch = tid & 3;
            bf16x8 v = *(const bf16x8*)&W[(size_t)(n0 + r)*K + k0 + ch*8];
            *(bf16x8*)&Ws[r][ch*8] = v;
        }
        __syncthreads();
        int kf = (lane >> 4) * 8;
        bf16x8 af[4], wf[2];
        #pragma unroll
        for (int i = 0; i < 4; ++i) af[i] = *(const bf16x8*)&As[wr*64 + i*16 + (lane & 15)][kf];
        #pragma unroll
        for (int j = 0; j < 2; ++j) wf[j] = *(const bf16x8*)&Ws[wc*32 + j*16 + (lane & 15)][kf];
        #pragma unroll
        for (int i = 0; i < 4; ++i)
            #pragma unroll
            for (int j = 0; j < 2; ++j)
                acc[i][j] = __builtin_amdgcn_mfma_f32_16x16x32_bf16(af[i], wf[j], acc[i][j], 0, 0, 0);
        __syncthreads();
    }
    // C/D layout: col = lane&15, row = (lane>>4)*4 + reg
    #pragma unroll
    for (int i = 0; i < 4; ++i) {
        #pragma unroll
        for (int j = 0; j < 2; ++j) {
            #pragma unroll
            for (int rg = 0; rg < 4; ++rg) {
                int m = m0 + wr*64 + i*16 + (lane >> 4)*4 + rg;
                int p = n0 + wc*32 + j*16 + (lane & 15);
                float v = acc[i][j][rg] + bias[p];
                if (ACT == 1) v = fmaxf(v, 0.f);
                if (RES) v += res[(size_t)m*P + p];
                if (OMODE != 2) outF[(size_t)m*P + p] = v;
                if (OMODE != 0) outB[(size_t)m*P + p] = f2bf(v);
            }
        }
    }
}

// ---------------- r[point][h][cin] = sum_d q[point][h*DH+d] * Wk[h*DH+d][cin] ----------------
__global__ __launch_bounds__(256) void r_kernel(const unsigned short* __restrict__ q,
                                                const unsigned short* __restrict__ Wk,
                                                unsigned short* __restrict__ r) {
    int p0 = blockIdx.x * 16;
    int h = blockIdx.y;
    int tid = threadIdx.x;  // cin
    __shared__ float qs[16][DH_];
    for (int l = tid; l < 16*DH_; l += 256) {
        int p = l >> 5, d = l & 31;
        qs[p][d] = bf2f(q[(size_t)(p0 + p)*C_ + h*DH_ + d]);
    }
    __syncthreads();
    float acc[16] = {};
    for (int d = 0; d < DH_; ++d) {
        float w = bf2f(Wk[(size_t)(h*DH_ + d)*C_ + tid]);
        #pragma unroll
        for (int p = 0; p < 16; ++p) acc[p] += qs[p][d] * w;
    }
    #pragma unroll
    for (int p = 0; p < 16; ++p)
        r[(size_t)(p0 + p)*(NH_*C_) + h*C_ + tid] = f2bf(acc[p]);
}

// ---------------- attention: one block per point ----------------
__global__ __launch_bounds__(256) void attn_kernel(const unsigned short* __restrict__ q,
                                                   const unsigned short* __restrict__ ok,
                                                   const unsigned short* __restrict__ ov,
                                                   const unsigned short* __restrict__ kpe,
                                                   const unsigned short* __restrict__ r,
                                                   const int* __restrict__ idx,
                                                   unsigned short* __restrict__ ao) {
    int point = blockIdx.x;
    int tid = threadIdx.x;
    int h = tid >> 5, d = tid & 31;
    __shared__ float kpes[K_][C_];
    __shared__ float rs[NH_][C_];
    __shared__ float qs[C_];
    __shared__ int idxs[K_];
    __shared__ float ss[NH_][K_];
    __shared__ float atts[NH_][K_];
    qs[tid] = bf2f(q[(size_t)point*C_ + tid]);
    for (int l = tid; l < K_*C_; l += 256) kpes[l >> 8][l & 255] = bf2f(kpe[(size_t)point*K_*C_ + l]);
    for (int l = tid; l < NH_*C_; l += 256) rs[l >> 8][l & 255] = bf2f(r[(size_t)point*NH_*C_ + l]);
    if (tid < K_) idxs[tid] = idx[point*K_ + tid];
    __syncthreads();
    const float scale = 0.1767766952966369f;  // 1/sqrt(32)
    for (int k = 0; k < K_; ++k) {
        int j = idxs[k];
        float s1 = qs[h*DH_ + d] * bf2f(ok[(size_t)j*C_ + h*DH_ + d]);
        float s2 = 0.f;
        #pragma unroll
        for (int t = 0; t < 8; ++t) s2 += rs[h][d + 32*t] * kpes[k][d + 32*t];
        float v = s1 + s2;
        #pragma unroll
        for (int off = 16; off; off >>= 1) v += __shfl_xor(v, off, 32);
        if (d == 0) ss[h][k] = v * scale;
    }
    __syncthreads();
    if (tid < NH_*K_) {
        int hh = tid >> 4, k = tid & 15;
        float v = ss[hh][k];
        float m = v;
        #pragma unroll
        for (int off = 8; off; off >>= 1) m = fmaxf(m, __shfl_xor(m, off, 16));
        float e = expf(v - m);
        float sm = e;
        #pragma unroll
        for (int off = 8; off; off >>= 1) sm += __shfl_xor(sm, off, 16);
        atts[hh][k] = e / sm;
    }
    __syncthreads();
    float acc = 0.f;
    #pragma unroll
    for (int k = 0; k < K_; ++k) acc += atts[h][k] * bf2f(ov[(size_t)idxs[k]*C_ + tid]);
    ao[(size_t)point*C_ + tid] = f2bf(acc);
}

// ---------------- LayerNorm: one block per row (256 cols) ----------------
// OMODE: 1 = fp32 + bf16, 2 = bf16 only
template<int OMODE>
__global__ __launch_bounds__(256) void ln_kernel(const float* __restrict__ in,
                                                 const float* __restrict__ w,
                                                 const float* __restrict__ b,
                                                 const float* __restrict__ addvec,
                                                 float* __restrict__ outF,
                                                 unsigned short* __restrict__ outB) {
    int row = blockIdx.x, tid = threadIdx.x;
    float x = in[(size_t)row*C_ + tid];
    __shared__ float red[4];
    float v = x;
    #pragma unroll
    for (int off = 32; off; off >>= 1) v += __shfl_xor(v, off, 64);
    if ((tid & 63) == 0) red[tid >> 6] = v;
    __syncthreads();
    float mean = (red[0]+red[1]+red[2]+red[3]) * (1.f/C_);
    __syncthreads();
    float dx = x - mean;
    v = dx*dx;
    #pragma unroll
    for (int off = 32; off; off >>= 1) v += __shfl_xor(v, off, 64);
    if ((tid & 63) == 0) red[tid >> 6] = v;
    __syncthreads();
    float var = (red[0]+red[1]+red[2]+red[3]) * (1.f/C_);
    float y = dx * rsqrtf(var + 1e-5f) * w[tid] + b[tid];
    if (addvec) y += addvec[tid];
    if (OMODE != 2) outF[(size_t)row*C_ + tid] = y;
    outB[(size_t)row*C_ + tid] = f2bf(y);
}

extern "C" void kernel_launch(void* const* d_in, const int* in_sizes, int n_in,
                              void* d_out, int out_size, void* d_ws, size_t ws_size,
                              hipStream_t stream) {
    const float* feature  = (const float*)d_in[0];
    const float* xyz      = (const float*)d_in[1];   // (BN, 3) flat
    const float* pe_W1    = (const float*)d_in[2];
    const float* pe_b1    = (const float*)d_in[3];
    const float* pe_W2    = (const float*)d_in[4];
    const float* pe_b2    = (const float*)d_in[5];
    const float* Wqkv     = (const float*)d_in[6];
    const float* bqkv     = (const float*)d_in[7];
    const float* Wo       = (const float*)d_in[8];
    const float* bo       = (const float*)d_in[9];
    const float* ln_attn_w= (const float*)d_in[10];
    const float* ln_attn_b= (const float*)d_in[11];
    const float* W1       = (const float*)d_in[12];
    const float* b1       = (const float*)d_in[13];
    const float* W2       = (const float*)d_in[14];
    const float* b2       = (const float*)d_in[15];
    const float* ln_ffn_w = (const float*)d_in[16];
    const float* ln_ffn_b = (const float*)d_in[17];
    const float* ln_out_w = (const float*)d_in[18];
    const float* ln_out_b = (const float*)d_in[19];

    // ---- workspace layout ----
    float* ws = (float*)d_ws;
    float* w_out = ws;                                   // BN*C fp32
    float* w_qpe = w_out + (size_t)BN_*C_;               // C fp32
    unsigned short* bptr = (unsigned short*)(w_qpe + C_ + 64);
    unsigned short* b_out = bptr;  bptr += (size_t)BN_*C_;
    unsigned short* b_t2  = bptr;  bptr += (size_t)BN_*C_;
    unsigned short* b_q   = bptr;  bptr += (size_t)BN_*C_;
    unsigned short* b_ok  = bptr;  bptr += (size_t)BN_*C_;
    unsigned short* b_ov  = bptr;  bptr += (size_t)BN_*C_;
    unsigned short* b_ao  = bptr;  bptr += (size_t)BN_*C_;
    unsigned short* b_ffh = bptr;  bptr += (size_t)BN_*FF_;
    unsigned short* w_kpe = bptr;  bptr += (size_t)BN_*K_*C_;
    unsigned short* w_r   = bptr;  bptr += (size_t)BN_*NH_*C_;
    unsigned short* b_hid = bptr;  bptr += (size_t)BN_*K_*C_;
    unsigned short* bWpe  = bptr;  bptr += (size_t)C_*C_;
    unsigned short* bWqkv = bptr;  bptr += (size_t)L_*3*C_*C_;
    unsigned short* bWo   = bptr;  bptr += (size_t)L_*C_*C_;
    unsigned short* bW1   = bptr;  bptr += (size_t)L_*FF_*C_;
    unsigned short* bW2   = bptr;  bptr += (size_t)L_*C_*FF_;
    int* w_idx = (int*)bptr;

    // ---- weight conversions (cheap, memory-bound) ----
    f2bf_kernel<<<(C_*C_+255)/256, 256, 0, stream>>>(pe_W2, bWpe, C_*C_);
    f2bf_kernel<<<(L_*3*C_*C_+255)/256, 256, 0, stream>>>(Wqkv, bWqkv, L_*3*C_*C_);
    f2bf_kernel<<<(L_*C_*C_+255)/256, 256, 0, stream>>>(Wo, bWo, L_*C_*C_);
    f2bf_kernel<<<(L_*FF_*C_+255)/256, 256, 0, stream>>>(W1, bW1, L_*FF_*C_);
    f2bf_kernel<<<(L_*C_*FF_+255)/256, 256, 0, stream>>>(W2, bW2, L_*C_*FF_);

    // ---- preprocessing ----
    reshape_in_kernel<<<BN_, 256, 0, stream>>>(feature, w_out, b_out);
    knn_kernel<<<BN_, 256, 0, stream>>>(xyz, w_idx);
    qpe_kernel<<<1, 256, 0, stream>>>(pe_b1, pe_W2, pe_b2, w_qpe);
    pe_hidden_kernel<<<BN_*K_, 256, 0, stream>>>(xyz, w_idx, pe_W1, pe_b1, b_hid);
    gemm_bf16<0,false,2><<<dim3(C_/64, (BN_*K_)/128), 256, 0, stream>>>(
        b_hid, bWpe, pe_b2, nullptr, nullptr, w_kpe, BN_*K_, C_, C_);

    // ---- layers ----
    for (int i = 0; i < L_; ++i) {
        const unsigned short* Wq = bWqkv + (size_t)i*3*C_*C_;
        const unsigned short* Wk = Wq + (size_t)C_*C_;
        const unsigned short* Wv = Wk + (size_t)C_*C_;
        const float* bq = bqkv + (size_t)i*3*C_;
        const float* bk = bq + C_;
        const float* bv = bq + 2*C_;

        ln_kernel<2><<<BN_, 256, 0, stream>>>(w_out, ln_attn_w + i*C_, ln_attn_b + i*C_, w_qpe, nullptr, b_t2);
        gemm_bf16<0,false,2><<<dim3(C_/64, BN_/128), 256, 0, stream>>>(
            b_t2, Wq, bq, nullptr, nullptr, b_q, BN_, C_, C_);
        gemm_bf16<0,false,2><<<dim3(C_/64, BN_/128), 256, 0, stream>>>(
            b_out, Wk, bk, nullptr, nullptr, b_ok, BN_, C_, C_);
        gemm_bf16<0,false,2><<<dim3(C_/64, BN_/128), 256, 0, stream>>>(
            b_out, Wv, bv, nullptr, nullptr, b_ov, BN_, C_, C_);
        r_kernel<<<dim3(BN_/16, NH_), 256, 0, stream>>>(b_q, Wk, w_r);
        attn_kernel<<<BN_, 256, 0, stream>>>(b_q, b_ok, b_ov, w_kpe, w_r, w_idx, b_ao);
        gemm_bf16<0,true,0><<<dim3(C_/64, BN_/128), 256, 0, stream>>>(
            b_ao, bWo + (size_t)i*C_*C_, bo + i*C_, w_out, w_out, nullptr, BN_, C_, C_);

        ln_kernel<2><<<BN_, 256, 0, stream>>>(w_out, ln_ffn_w + i*C_, ln_ffn_b + i*C_, nullptr, nullptr, b_t2);
        gemm_bf16<1,false,2><<<dim3(FF_/64, BN_/128), 256, 0, stream>>>(
            b_t2, bW1 + (size_t)i*FF_*C_, b1 + i*FF_, nullptr, nullptr, b_ffh, BN_, FF_, C_);
        gemm_bf16<0,true,0><<<dim3(C_/64, BN_/128), 256, 0, stream>>>(
            b_ffh, bW2 + (size_t)i*C_*FF_, b2 + i*C_, w_out, w_out, nullptr, BN_, C_, FF_);
        ln_kernel<1><<<BN_, 256, 0, stream>>>(w_out, ln_out_w + i*C_, ln_out_b + i*C_, nullptr, w_out, b_out);
    }

    reshape_out_kernel<<<BN_, 256, 0, stream>>>(w_out, (float*)d_out);
}

// Round 4
// 882.709 us; speedup vs baseline: 3.6411x; 1.1214x over previous
//
#include <hip/hip_runtime.h>
#include <math.h>

#define BS_ 2
#define V_ 4
#define H_ 24
#define W_ 24
#define N_ (V_*H_*W_)        // 2304
#define BN_ (BS_*N_)         // 4608
#define C_ 256
#define K_ 16
#define L_ 6
#define NH_ 8
#define DH_ 32
#define FF_ 1024

typedef __attribute__((ext_vector_type(4))) float f32x4;
typedef __attribute__((ext_vector_type(8))) short bf16x8;

__device__ inline unsigned short f2bf(float x) {
    unsigned u = __float_as_uint(x);
    unsigned r = u + 0x7fffu + ((u >> 16) & 1u);
    return (unsigned short)(r >> 16);
}
__device__ inline float bf2f(unsigned short h) {
    return __uint_as_float(((unsigned)h) << 16);
}

// ---------------- fp32 -> bf16 elementwise ----------------
__global__ __launch_bounds__(256) void f2bf_kernel(const float* __restrict__ in,
                                                   unsigned short* __restrict__ out, int n) {
    int i = blockIdx.x*256 + threadIdx.x;
    if (i < n) out[i] = f2bf(in[i]);
}

// ---------------- reshape in: (B*V,C,H,W) -> (BN, C) fp32 + bf16 ----------------
__global__ __launch_bounds__(256) void reshape_in_kernel(const float* __restrict__ f,
                                                         float* __restrict__ outF,
                                                         unsigned short* __restrict__ outB) {
    int bn = blockIdx.x, c = threadIdx.x;
    int b = bn / N_, rem = bn % N_;
    int v = rem / (H_*W_), hw = rem % (H_*W_);
    float x = f[(((size_t)(b*V_ + v)*C_ + c)*(H_*W_)) + hw];
    outF[(size_t)bn*C_ + c] = x;
    outB[(size_t)bn*C_ + c] = f2bf(x);
}

// ---------------- reshape out: (BN, C) -> (B*V,C,H,W) ----------------
__global__ __launch_bounds__(256) void reshape_out_kernel(const float* __restrict__ in,
                                                          float* __restrict__ o) {
    int bn = blockIdx.x, c = threadIdx.x;
    int b = bn / N_, rem = bn % N_;
    int v = rem / (H_*W_), hw = rem % (H_*W_);
    o[(((size_t)(b*V_ + v)*C_ + c)*(H_*W_)) + hw] = in[(size_t)bn*C_ + c];
}

// ---------------- KNN: one WAVE per query point, 4 points/block ----------------
__global__ __launch_bounds__(256) void knn_kernel(const float* __restrict__ pts,
                                                  int* __restrict__ idx) {
    int wid = threadIdx.x >> 6, lane = threadIdx.x & 63;
    int point = blockIdx.x*4 + wid;          // blocks never straddle a batch (2304 % 4 == 0)
    int b = point / N_;
    int il = point % N_;
    __shared__ float ps[N_*3];
    for (int l = threadIdx.x; l < N_*3; l += 256) ps[l] = pts[(size_t)b*N_*3 + l];
    __syncthreads();
    float qx = ps[il*3], qy = ps[il*3+1], qz = ps[il*3+2];
    unsigned long long key[36];              // 64 lanes x 36 = 2304 candidates
    #pragma unroll
    for (int s = 0; s < 36; ++s) {
        int j = lane + 64*s;
        float dx = qx - ps[j*3], dy = qy - ps[j*3+1], dz = qz - ps[j*3+2];
        float d2 = dx*dx + dy*dy + dz*dz;
        key[s] = ((unsigned long long)__float_as_uint(d2) << 32) | (unsigned)j;
    }
    for (int it = 0; it < K_; ++it) {
        unsigned long long best = key[0];
        #pragma unroll
        for (int s = 1; s < 36; ++s) best = key[s] < best ? key[s] : best;
        #pragma unroll
        for (int off = 32; off; off >>= 1) {
            unsigned long long o = __shfl_xor(best, off, 64);
            if (o < best) best = o;
        }
        int wj = (int)(best & 0xffffffffu);
        if (lane == 0) idx[point*K_ + it] = b*N_ + wj;
        if ((wj & 63) == lane) {             // remove winner (static unroll, reg-resident)
            int sw = wj >> 6;
            #pragma unroll
            for (int s = 0; s < 36; ++s) if (s == sw) key[s] = ~0ull;
        }
    }
}

// ---------------- q_pe = relu(b1)@W2^T + b2 (fp32, tiny) ----------------
__global__ __launch_bounds__(256) void qpe_kernel(const float* __restrict__ b1,
                                                  const float* __restrict__ W2,
                                                  const float* __restrict__ b2,
                                                  float* __restrict__ qpe) {
    __shared__ float h[C_];
    int tid = threadIdx.x;
    h[tid] = fmaxf(b1[tid], 0.f);
    __syncthreads();
    float acc = 0.f;
    for (int j = 0; j < C_; ++j) acc += h[j] * W2[(size_t)tid*C_ + j];
    qpe[tid] = acc + b2[tid];
}

// ---------------- PE hidden (bf16): one block per point, 16 rows each ----------------
__global__ __launch_bounds__(256) void pe_hidden_kernel(const float* __restrict__ pts,
                                                        const int* __restrict__ idx,
                                                        const float* __restrict__ W1,
                                                        const float* __restrict__ b1,
                                                        unsigned short* __restrict__ hidden) {
    int point = blockIdx.x;
    int c = threadIdx.x;
    __shared__ float rel[K_][3];
    if (threadIdx.x < K_*3) {
        int k = threadIdx.x / 3, ax = threadIdx.x % 3;
        int j = idx[point*K_ + k];
        rel[k][ax] = pts[(size_t)j*3 + ax] - pts[(size_t)point*3 + ax];
    }
    __syncthreads();
    float w0 = W1[c*3], w1 = W1[c*3+1], w2 = W1[c*3+2], bb = b1[c];
    #pragma unroll
    for (int k = 0; k < K_; ++k) {
        float v = rel[k][0]*w0 + rel[k][1]*w1 + rel[k][2]*w2 + bb;
        hidden[((size_t)point*K_ + k)*C_ + c] = f2bf(fmaxf(v, 0.f));
    }
}

// ---------------- bf16 MFMA GEMM (BM=BN=64): OUT = act(A @ W^T + bias) (+res) ----------------
// A: M x K bf16 row-major; W: P x K bf16 row-major.
// OMODE: 0 = fp32 only, 1 = fp32 + bf16, 2 = bf16 only
template<int ACT, bool RES, int OMODE>
__global__ __launch_bounds__(256) void gemm_bf16(const unsigned short* __restrict__ A,
                                                 const unsigned short* __restrict__ W,
                                                 const float* __restrict__ bias,
                                                 const float* __restrict__ res,
                                                 float* __restrict__ outF,
                                                 unsigned short* __restrict__ outB,
                                                 int M, int P, int K) {
    const int BK = 32;
    __shared__ unsigned short As[64][BK+8];
    __shared__ unsigned short Ws[64][BK+8];
    int tid = threadIdx.x;
    int wave = tid >> 6, lane = tid & 63;
    int wr = wave >> 1, wc = wave & 1;           // 2x2 waves, wave tile 32x32
    int m0 = blockIdx.y * 64, n0 = blockIdx.x * 64;
    f32x4 acc[2][2];
    #pragma unroll
    for (int i = 0; i < 2; ++i)
        #pragma unroll
        for (int j = 0; j < 2; ++j) acc[i][j] = (f32x4){0.f, 0.f, 0.f, 0.f};

    int r = tid >> 2, ch = tid & 3;
    for (int k0 = 0; k0 < K; k0 += BK) {
        *(bf16x8*)&As[r][ch*8] = *(const bf16x8*)&A[(size_t)(m0 + r)*K + k0 + ch*8];
        *(bf16x8*)&Ws[r][ch*8] = *(const bf16x8*)&W[(size_t)(n0 + r)*K + k0 + ch*8];
        __syncthreads();
        int kf = (lane >> 4) * 8;
        bf16x8 af[2], wf[2];
        #pragma unroll
        for (int i = 0; i < 2; ++i) af[i] = *(const bf16x8*)&As[wr*32 + i*16 + (lane & 15)][kf];
        #pragma unroll
        for (int j = 0; j < 2; ++j) wf[j] = *(const bf16x8*)&Ws[wc*32 + j*16 + (lane & 15)][kf];
        #pragma unroll
        for (int i = 0; i < 2; ++i)
            #pragma unroll
            for (int j = 0; j < 2; ++j)
                acc[i][j] = __builtin_amdgcn_mfma_f32_16x16x32_bf16(af[i], wf[j], acc[i][j], 0, 0, 0);
        __syncthreads();
    }
    // C/D layout: col = lane&15, row = (lane>>4)*4 + reg
    #pragma unroll
    for (int i = 0; i < 2; ++i) {
        #pragma unroll
        for (int j = 0; j < 2; ++j) {
            #pragma unroll
            for (int rg = 0; rg < 4; ++rg) {
                int m = m0 + wr*32 + i*16 + (lane >> 4)*4 + rg;
                int p = n0 + wc*32 + j*16 + (lane & 15);
                float v = acc[i][j][rg] + bias[p];
                if (ACT == 1) v = fmaxf(v, 0.f);
                if (RES) v += res[(size_t)m*P + p];
                if (OMODE != 2) outF[(size_t)m*P + p] = v;
                if (OMODE != 0) outB[(size_t)m*P + p] = f2bf(v);
            }
        }
    }
}

// ---------------- r[point][h][cin] = sum_d q[point][h*DH+d] * Wk[h*DH+d][cin] ----------------
__global__ __launch_bounds__(256) void r_kernel(const unsigned short* __restrict__ q,
                                                const unsigned short* __restrict__ Wk,
                                                unsigned short* __restrict__ r) {
    int p0 = blockIdx.x * 16;
    int h = blockIdx.y;
    int tid = threadIdx.x;  // cin
    __shared__ float qs[16][DH_];
    for (int l = tid; l < 16*DH_; l += 256) {
        int p = l >> 5, d = l & 31;
        qs[p][d] = bf2f(q[(size_t)(p0 + p)*C_ + h*DH_ + d]);
    }
    __syncthreads();
    float acc[16] = {};
    for (int d = 0; d < DH_; ++d) {
        float w = bf2f(Wk[(size_t)(h*DH_ + d)*C_ + tid]);
        #pragma unroll
        for (int p = 0; p < 16; ++p) acc[p] += qs[p][d] * w;
    }
    #pragma unroll
    for (int p = 0; p < 16; ++p)
        r[(size_t)(p0 + p)*(NH_*C_) + h*C_ + tid] = f2bf(acc[p]);
}

// ---------------- attention: one block per point (kv combined, stride 512) ----------------
__global__ __launch_bounds__(256) void attn_kernel(const unsigned short* __restrict__ q,
                                                   const unsigned short* __restrict__ kv,
                                                   const unsigned short* __restrict__ kpe,
                                                   const unsigned short* __restrict__ r,
                                                   const int* __restrict__ idx,
                                                   unsigned short* __restrict__ ao) {
    int point = blockIdx.x;
    int tid = threadIdx.x;
    int h = tid >> 5, d = tid & 31;
    __shared__ float kpes[K_][C_];
    __shared__ float rs[NH_][C_];
    __shared__ float qs[C_];
    __shared__ int idxs[K_];
    __shared__ float ss[NH_][K_];
    __shared__ float atts[NH_][K_];
    qs[tid] = bf2f(q[(size_t)point*C_ + tid]);
    for (int l = tid; l < K_*C_; l += 256) kpes[l >> 8][l & 255] = bf2f(kpe[(size_t)point*K_*C_ + l]);
    for (int l = tid; l < NH_*C_; l += 256) rs[l >> 8][l & 255] = bf2f(r[(size_t)point*NH_*C_ + l]);
    if (tid < K_) idxs[tid] = idx[point*K_ + tid];
    __syncthreads();
    const float scale = 0.1767766952966369f;  // 1/sqrt(32)
    for (int k = 0; k < K_; ++k) {
        int j = idxs[k];
        float s1 = qs[h*DH_ + d] * bf2f(kv[(size_t)j*512 + h*DH_ + d]);
        float s2 = 0.f;
        #pragma unroll
        for (int t = 0; t < 8; ++t) s2 += rs[h][d + 32*t] * kpes[k][d + 32*t];
        float v = s1 + s2;
        #pragma unroll
        for (int off = 16; off; off >>= 1) v += __shfl_xor(v, off, 32);
        if (d == 0) ss[h][k] = v * scale;
    }
    __syncthreads();
    if (tid < NH_*K_) {
        int hh = tid >> 4, k = tid & 15;
        float v = ss[hh][k];
        float m = v;
        #pragma unroll
        for (int off = 8; off; off >>= 1) m = fmaxf(m, __shfl_xor(m, off, 16));
        float e = expf(v - m);
        float sm = e;
        #pragma unroll
        for (int off = 8; off; off >>= 1) sm += __shfl_xor(sm, off, 16);
        atts[hh][k] = e / sm;
    }
    __syncthreads();
    float acc = 0.f;
    #pragma unroll
    for (int k = 0; k < K_; ++k) acc += atts[h][k] * bf2f(kv[(size_t)idxs[k]*512 + 256 + tid]);
    ao[(size_t)point*C_ + tid] = f2bf(acc);
}

// ---------------- LayerNorm: one block per row ----------------
// OMODE: 1 = fp32 + bf16, 2 = bf16 only
template<int OMODE>
__global__ __launch_bounds__(256) void ln_kernel(const float* __restrict__ in,
                                                 const float* __restrict__ w,
                                                 const float* __restrict__ b,
                                                 const float* __restrict__ addvec,
                                                 float* __restrict__ outF,
                                                 unsigned short* __restrict__ outB) {
    int row = blockIdx.x, tid = threadIdx.x;
    float x = in[(size_t)row*C_ + tid];
    __shared__ float red[4];
    float v = x;
    #pragma unroll
    for (int off = 32; off; off >>= 1) v += __shfl_xor(v, off, 64);
    if ((tid & 63) == 0) red[tid >> 6] = v;
    __syncthreads();
    float mean = (red[0]+red[1]+red[2]+red[3]) * (1.f/C_);
    __syncthreads();
    float dx = x - mean;
    v = dx*dx;
    #pragma unroll
    for (int off = 32; off; off >>= 1) v += __shfl_xor(v, off, 64);
    if ((tid & 63) == 0) red[tid >> 6] = v;
    __syncthreads();
    float var = (red[0]+red[1]+red[2]+red[3]) * (1.f/C_);
    float y = dx * rsqrtf(var + 1e-5f) * w[tid] + b[tid];
    if (addvec) y += addvec[tid];
    if (OMODE != 2) outF[(size_t)row*C_ + tid] = y;
    outB[(size_t)row*C_ + tid] = f2bf(y);
}

// ---------------- fused ln_out (layer i) + ln_attn (layer i+1) ----------------
__global__ __launch_bounds__(256) void ln2_kernel(const float* __restrict__ in,
                                                  const float* __restrict__ w1, const float* __restrict__ b1v,
                                                  const float* __restrict__ w2, const float* __restrict__ b2v,
                                                  const float* __restrict__ qpe,
                                                  float* __restrict__ outF, unsigned short* __restrict__ outB,
                                                  unsigned short* __restrict__ outT2) {
    int row = blockIdx.x, tid = threadIdx.x;
    float x = in[(size_t)row*C_ + tid];
    __shared__ float red[4];
    float v = x;
    #pragma unroll
    for (int off = 32; off; off >>= 1) v += __shfl_xor(v, off, 64);
    if ((tid & 63) == 0) red[tid >> 6] = v;
    __syncthreads();
    float mean = (red[0]+red[1]+red[2]+red[3]) * (1.f/C_);
    __syncthreads();
    float dx = x - mean;
    v = dx*dx;
    #pragma unroll
    for (int off = 32; off; off >>= 1) v += __shfl_xor(v, off, 64);
    if ((tid & 63) == 0) red[tid >> 6] = v;
    __syncthreads();
    float var = (red[0]+red[1]+red[2]+red[3]) * (1.f/C_);
    float y = dx * rsqrtf(var + 1e-5f) * w1[tid] + b1v[tid];
    outF[(size_t)row*C_ + tid] = y;
    outB[(size_t)row*C_ + tid] = f2bf(y);
    // second LN over y
    v = y;
    #pragma unroll
    for (int off = 32; off; off >>= 1) v += __shfl_xor(v, off, 64);
    __syncthreads();
    if ((tid & 63) == 0) red[tid >> 6] = v;
    __syncthreads();
    float mean2 = (red[0]+red[1]+red[2]+red[3]) * (1.f/C_);
    __syncthreads();
    float dy = y - mean2;
    v = dy*dy;
    #pragma unroll
    for (int off = 32; off; off >>= 1) v += __shfl_xor(v, off, 64);
    if ((tid & 63) == 0) red[tid >> 6] = v;
    __syncthreads();
    float var2 = (red[0]+red[1]+red[2]+red[3]) * (1.f/C_);
    float z = dy * rsqrtf(var2 + 1e-5f) * w2[tid] + b2v[tid] + qpe[tid];
    outT2[(size_t)row*C_ + tid] = f2bf(z);
}

extern "C" void kernel_launch(void* const* d_in, const int* in_sizes, int n_in,
                              void* d_out, int out_size, void* d_ws, size_t ws_size,
                              hipStream_t stream) {
    const float* feature  = (const float*)d_in[0];
    const float* xyz      = (const float*)d_in[1];
    const float* pe_W1    = (const float*)d_in[2];
    const float* pe_b1    = (const float*)d_in[3];
    const float* pe_W2    = (const float*)d_in[4];
    const float* pe_b2    = (const float*)d_in[5];
    const float* Wqkv     = (const float*)d_in[6];
    const float* bqkv     = (const float*)d_in[7];
    const float* Wo       = (const float*)d_in[8];
    const float* bo       = (const float*)d_in[9];
    const float* ln_attn_w= (const float*)d_in[10];
    const float* ln_attn_b= (const float*)d_in[11];
    const float* W1       = (const float*)d_in[12];
    const float* b1       = (const float*)d_in[13];
    const float* W2       = (const float*)d_in[14];
    const float* b2       = (const float*)d_in[15];
    const float* ln_ffn_w = (const float*)d_in[16];
    const float* ln_ffn_b = (const float*)d_in[17];
    const float* ln_out_w = (const float*)d_in[18];
    const float* ln_out_b = (const float*)d_in[19];

    // ---- workspace layout ----
    float* ws = (float*)d_ws;
    float* w_out = ws;                                   // BN*C fp32
    float* w_qpe = w_out + (size_t)BN_*C_;               // C fp32
    unsigned short* bptr = (unsigned short*)(w_qpe + C_ + 64);
    unsigned short* b_out = bptr;  bptr += (size_t)BN_*C_;
    unsigned short* b_t2  = bptr;  bptr += (size_t)BN_*C_;
    unsigned short* b_q   = bptr;  bptr += (size_t)BN_*C_;
    unsigned short* b_kv  = bptr;  bptr += (size_t)BN_*512;
    unsigned short* b_ao  = bptr;  bptr += (size_t)BN_*C_;
    unsigned short* b_ffh = bptr;  bptr += (size_t)BN_*FF_;
    unsigned short* w_kpe = bptr;  bptr += (size_t)BN_*K_*C_;
    unsigned short* w_r   = bptr;  bptr += (size_t)BN_*NH_*C_;
    unsigned short* b_hid = bptr;  bptr += (size_t)BN_*K_*C_;
    unsigned short* bWpe  = bptr;  bptr += (size_t)C_*C_;
    unsigned short* bWqkv = bptr;  bptr += (size_t)L_*3*C_*C_;
    unsigned short* bWo   = bptr;  bptr += (size_t)L_*C_*C_;
    unsigned short* bW1   = bptr;  bptr += (size_t)L_*FF_*C_;
    unsigned short* bW2   = bptr;  bptr += (size_t)L_*C_*FF_;
    int* w_idx = (int*)bptr;

    // ---- weight conversions ----
    f2bf_kernel<<<(C_*C_+255)/256, 256, 0, stream>>>(pe_W2, bWpe, C_*C_);
    f2bf_kernel<<<(L_*3*C_*C_+255)/256, 256, 0, stream>>>(Wqkv, bWqkv, L_*3*C_*C_);
    f2bf_kernel<<<(L_*C_*C_+255)/256, 256, 0, stream>>>(Wo, bWo, L_*C_*C_);
    f2bf_kernel<<<(L_*FF_*C_+255)/256, 256, 0, stream>>>(W1, bW1, L_*FF_*C_);
    f2bf_kernel<<<(L_*C_*FF_+255)/256, 256, 0, stream>>>(W2, bW2, L_*C_*FF_);

    // ---- preprocessing ----
    reshape_in_kernel<<<BN_, 256, 0, stream>>>(feature, w_out, b_out);
    knn_kernel<<<BN_/4, 256, 0, stream>>>(xyz, w_idx);
    qpe_kernel<<<1, 256, 0, stream>>>(pe_b1, pe_W2, pe_b2, w_qpe);
    pe_hidden_kernel<<<BN_, 256, 0, stream>>>(xyz, w_idx, pe_W1, pe_b1, b_hid);
    gemm_bf16<0,false,2><<<dim3(C_/64, (BN_*K_)/64), 256, 0, stream>>>(
        b_hid, bWpe, pe_b2, nullptr, nullptr, w_kpe, BN_*K_, C_, C_);

    // layer 0 ln_attn
    ln_kernel<2><<<BN_, 256, 0, stream>>>(w_out, ln_attn_w, ln_attn_b, w_qpe, nullptr, b_t2);

    // ---- layers ----
    for (int i = 0; i < L_; ++i) {
        const unsigned short* Wq = bWqkv + (size_t)i*3*C_*C_;
        const unsigned short* Wk = Wq + (size_t)C_*C_;
        const float* bq = bqkv + (size_t)i*3*C_;
        const float* bk = bq + C_;

        gemm_bf16<0,false,2><<<dim3(C_/64, BN_/64), 256, 0, stream>>>(
            b_t2, Wq, bq, nullptr, nullptr, b_q, BN_, C_, C_);
        gemm_bf16<0,false,2><<<dim3(512/64, BN_/64), 256, 0, stream>>>(
            b_out, Wk, bk, nullptr, nullptr, b_kv, BN_, 512, C_);
        r_kernel<<<dim3(BN_/16, NH_), 256, 0, stream>>>(b_q, Wk, w_r);
        attn_kernel<<<BN_, 256, 0, stream>>>(b_q, b_kv, w_kpe, w_r, w_idx, b_ao);
        gemm_bf16<0,true,0><<<dim3(C_/64, BN_/64), 256, 0, stream>>>(
            b_ao, bWo + (size_t)i*C_*C_, bo + i*C_, w_out, w_out, nullptr, BN_, C_, C_);

        ln_kernel<2><<<BN_, 256, 0, stream>>>(w_out, ln_ffn_w + i*C_, ln_ffn_b + i*C_, nullptr, nullptr, b_t2);
        gemm_bf16<1,false,2><<<dim3(FF_/64, BN_/64), 256, 0, stream>>>(
            b_t2, bW1 + (size_t)i*FF_*C_, b1 + i*FF_, nullptr, nullptr, b_ffh, BN_, FF_, C_);
        gemm_bf16<0,true,0><<<dim3(C_/64, BN_/64), 256, 0, stream>>>(
            b_ffh, bW2 + (size_t)i*C_*FF_, b2 + i*C_, w_out, w_out, nullptr, BN_, C_, FF_);

        if (i < L_-1) {
            ln2_kernel<<<BN_, 256, 0, stream>>>(w_out, ln_out_w + i*C_, ln_out_b + i*C_,
                                                ln_attn_w + (i+1)*C_, ln_attn_b + (i+1)*C_,
                                                w_qpe, w_out, b_out, b_t2);
        } else {
            ln_kernel<1><<<BN_, 256, 0, stream>>>(w_out, ln_out_w + i*C_, ln_out_b + i*C_, nullptr, w_out, b_out);
        }
    }

    reshape_out_kernel<<<BN_, 256, 0, stream>>>(w_out, (float*)d_out);
}

// Round 5
// 736.633 us; speedup vs baseline: 4.3631x; 1.1983x over previous
//
#include <hip/hip_runtime.h>
#include <math.h>

#define BS_ 2
#define V_ 4
#define H_ 24
#define W_ 24
#define N_ (V_*H_*W_)        // 2304
#define BN_ (BS_*N_)         // 4608
#define C_ 256
#define K_ 16
#define L_ 6
#define NH_ 8
#define DH_ 32
#define FF_ 1024

typedef __attribute__((ext_vector_type(4))) float f32x4;
typedef __attribute__((ext_vector_type(8))) short bf16x8;

__device__ inline unsigned short f2bf(float x) {
    unsigned u = __float_as_uint(x);
    unsigned r = u + 0x7fffu + ((u >> 16) & 1u);
    return (unsigned short)(r >> 16);
}
__device__ inline float bf2f(unsigned short h) {
    return __uint_as_float(((unsigned)h) << 16);
}

// ---------------- fp32 -> bf16 elementwise ----------------
__global__ __launch_bounds__(256) void f2bf_kernel(const float* __restrict__ in,
                                                   unsigned short* __restrict__ out, int n) {
    int i = blockIdx.x*256 + threadIdx.x;
    if (i < n) out[i] = f2bf(in[i]);
}

// ---------------- reshape in: (B*V,C,H,W) -> (BN, C) fp32 + bf16 ----------------
__global__ __launch_bounds__(256) void reshape_in_kernel(const float* __restrict__ f,
                                                         float* __restrict__ outF,
                                                         unsigned short* __restrict__ outB) {
    int bn = blockIdx.x, c = threadIdx.x;
    int b = bn / N_, rem = bn % N_;
    int v = rem / (H_*W_), hw = rem % (H_*W_);
    float x = f[(((size_t)(b*V_ + v)*C_ + c)*(H_*W_)) + hw];
    outF[(size_t)bn*C_ + c] = x;
    outB[(size_t)bn*C_ + c] = f2bf(x);
}

// ---------------- reshape out: (BN, C) -> (B*V,C,H,W) ----------------
__global__ __launch_bounds__(256) void reshape_out_kernel(const float* __restrict__ in,
                                                          float* __restrict__ o) {
    int bn = blockIdx.x, c = threadIdx.x;
    int b = bn / N_, rem = bn % N_;
    int v = rem / (H_*W_), hw = rem % (H_*W_);
    o[(((size_t)(b*V_ + v)*C_ + c)*(H_*W_)) + hw] = in[(size_t)bn*C_ + c];
}

// ---------------- KNN: one WAVE per query point, 4 points/block ----------------
__global__ __launch_bounds__(256) void knn_kernel(const float* __restrict__ pts,
                                                  int* __restrict__ idx) {
    int wid = threadIdx.x >> 6, lane = threadIdx.x & 63;
    int point = blockIdx.x*4 + wid;          // blocks never straddle a batch (2304 % 4 == 0)
    int b = point / N_;
    int il = point % N_;
    __shared__ float ps[N_*3];
    for (int l = threadIdx.x; l < N_*3; l += 256) ps[l] = pts[(size_t)b*N_*3 + l];
    __syncthreads();
    float qx = ps[il*3], qy = ps[il*3+1], qz = ps[il*3+2];
    unsigned long long key[36];              // 64 lanes x 36 = 2304 candidates
    #pragma unroll
    for (int s = 0; s < 36; ++s) {
        int j = lane + 64*s;
        float dx = qx - ps[j*3], dy = qy - ps[j*3+1], dz = qz - ps[j*3+2];
        float d2 = dx*dx + dy*dy + dz*dz;
        key[s] = ((unsigned long long)__float_as_uint(d2) << 32) | (unsigned)j;
    }
    for (int it = 0; it < K_; ++it) {
        unsigned long long best = key[0];
        #pragma unroll
        for (int s = 1; s < 36; ++s) best = key[s] < best ? key[s] : best;
        #pragma unroll
        for (int off = 32; off; off >>= 1) {
            unsigned long long o = __shfl_xor(best, off, 64);
            if (o < best) best = o;
        }
        int wj = (int)(best & 0xffffffffu);
        if (lane == 0) idx[point*K_ + it] = b*N_ + wj;
        if ((wj & 63) == lane) {             // remove winner (static unroll, reg-resident)
            int sw = wj >> 6;
            #pragma unroll
            for (int s = 0; s < 36; ++s) if (s == sw) key[s] = ~0ull;
        }
    }
}

// ---------------- q_pe = relu(b1)@W2^T + b2 (fp32, tiny) ----------------
__global__ __launch_bounds__(256) void qpe_kernel(const float* __restrict__ b1,
                                                  const float* __restrict__ W2,
                                                  const float* __restrict__ b2,
                                                  float* __restrict__ qpe) {
    __shared__ float h[C_];
    int tid = threadIdx.x;
    h[tid] = fmaxf(b1[tid], 0.f);
    __syncthreads();
    float acc = 0.f;
    for (int j = 0; j < C_; ++j) acc += h[j] * W2[(size_t)tid*C_ + j];
    qpe[tid] = acc + b2[tid];
}

// ---------------- PE hidden (bf16): one block per point, 16 rows each ----------------
__global__ __launch_bounds__(256) void pe_hidden_kernel(const float* __restrict__ pts,
                                                        const int* __restrict__ idx,
                                                        const float* __restrict__ W1,
                                                        const float* __restrict__ b1,
                                                        unsigned short* __restrict__ hidden) {
    int point = blockIdx.x;
    int c = threadIdx.x;
    __shared__ float rel[K_][3];
    if (threadIdx.x < K_*3) {
        int k = threadIdx.x / 3, ax = threadIdx.x % 3;
        int j = idx[point*K_ + k];
        rel[k][ax] = pts[(size_t)j*3 + ax] - pts[(size_t)point*3 + ax];
    }
    __syncthreads();
    float w0 = W1[c*3], w1 = W1[c*3+1], w2 = W1[c*3+2], bb = b1[c];
    #pragma unroll
    for (int k = 0; k < K_; ++k) {
        float v = rel[k][0]*w0 + rel[k][1]*w1 + rel[k][2]*w2 + bb;
        hidden[((size_t)point*K_ + k)*C_ + c] = f2bf(fmaxf(v, 0.f));
    }
}

// ---------------- bf16 MFMA GEMM (BM=BN=64): OUT = act(A @ W^T + bias) (+res) ----------------
// A: M x K bf16 row-major; W: P x K bf16 row-major.
// OMODE: 0 = fp32 only, 1 = fp32 + bf16, 2 = bf16 only
template<int ACT, bool RES, int OMODE>
__global__ __launch_bounds__(256) void gemm_bf16(const unsigned short* __restrict__ A,
                                                 const unsigned short* __restrict__ W,
                                                 const float* __restrict__ bias,
                                                 const float* __restrict__ res,
                                                 float* __restrict__ outF,
                                                 unsigned short* __restrict__ outB,
                                                 int M, int P, int K) {
    const int BK = 32;
    __shared__ unsigned short As[64][BK+8];
    __shared__ unsigned short Ws[64][BK+8];
    int tid = threadIdx.x;
    int wave = tid >> 6, lane = tid & 63;
    int wr = wave >> 1, wc = wave & 1;           // 2x2 waves, wave tile 32x32
    int m0 = blockIdx.y * 64, n0 = blockIdx.x * 64;
    f32x4 acc[2][2];
    #pragma unroll
    for (int i = 0; i < 2; ++i)
        #pragma unroll
        for (int j = 0; j < 2; ++j) acc[i][j] = (f32x4){0.f, 0.f, 0.f, 0.f};

    int r = tid >> 2, ch = tid & 3;
    for (int k0 = 0; k0 < K; k0 += BK) {
        *(bf16x8*)&As[r][ch*8] = *(const bf16x8*)&A[(size_t)(m0 + r)*K + k0 + ch*8];
        *(bf16x8*)&Ws[r][ch*8] = *(const bf16x8*)&W[(size_t)(n0 + r)*K + k0 + ch*8];
        __syncthreads();
        int kf = (lane >> 4) * 8;
        bf16x8 af[2], wf[2];
        #pragma unroll
        for (int i = 0; i < 2; ++i) af[i] = *(const bf16x8*)&As[wr*32 + i*16 + (lane & 15)][kf];
        #pragma unroll
        for (int j = 0; j < 2; ++j) wf[j] = *(const bf16x8*)&Ws[wc*32 + j*16 + (lane & 15)][kf];
        #pragma unroll
        for (int i = 0; i < 2; ++i)
            #pragma unroll
            for (int j = 0; j < 2; ++j)
                acc[i][j] = __builtin_amdgcn_mfma_f32_16x16x32_bf16(af[i], wf[j], acc[i][j], 0, 0, 0);
        __syncthreads();
    }
    // C/D layout: col = lane&15, row = (lane>>4)*4 + reg
    #pragma unroll
    for (int i = 0; i < 2; ++i) {
        #pragma unroll
        for (int j = 0; j < 2; ++j) {
            #pragma unroll
            for (int rg = 0; rg < 4; ++rg) {
                int m = m0 + wr*32 + i*16 + (lane >> 4)*4 + rg;
                int p = n0 + wc*32 + j*16 + (lane & 15);
                float v = acc[i][j][rg] + bias[p];
                if (ACT == 1) v = fmaxf(v, 0.f);
                if (RES) v += res[(size_t)m*P + p];
                if (OMODE != 2) outF[(size_t)m*P + p] = v;
                if (OMODE != 0) outB[(size_t)m*P + p] = f2bf(v);
            }
        }
    }
}

// ---------------- r[point][h][cin] = sum_d q[point][h*DH+d] * Wk[h*DH+d][cin] ----------------
__global__ __launch_bounds__(256) void r_kernel(const unsigned short* __restrict__ q,
                                                const unsigned short* __restrict__ Wk,
                                                unsigned short* __restrict__ r) {
    int p0 = blockIdx.x * 16;
    int h = blockIdx.y;
    int tid = threadIdx.x;  // cin
    __shared__ float qs[16][DH_];
    for (int l = tid; l < 16*DH_; l += 256) {
        int p = l >> 5, d = l & 31;
        qs[p][d] = bf2f(q[(size_t)(p0 + p)*C_ + h*DH_ + d]);
    }
    __syncthreads();
    float acc[16] = {};
    for (int d = 0; d < DH_; ++d) {
        float w = bf2f(Wk[(size_t)(h*DH_ + d)*C_ + tid]);
        #pragma unroll
        for (int p = 0; p < 16; ++p) acc[p] += qs[p][d] * w;
    }
    #pragma unroll
    for (int p = 0; p < 16; ++p)
        r[(size_t)(p0 + p)*(NH_*C_) + h*C_ + tid] = f2bf(acc[p]);
}

// ---------------- attention: one WAVE per point, MFMA scores ----------------
// out[k][n] (16x16): cols 0-7 = s2 = kpe_k . r_h ; cols 8-15 = s1 = ok_k . qmask_h
__global__ __launch_bounds__(256) void attn_kernel(const unsigned short* __restrict__ q,
                                                   const unsigned short* __restrict__ kv,
                                                   const unsigned short* __restrict__ kpe,
                                                   const unsigned short* __restrict__ r,
                                                   const int* __restrict__ idx,
                                                   unsigned short* __restrict__ ao) {
    int wid = threadIdx.x >> 6, lane = threadIdx.x & 63;
    int point = blockIdx.x*4 + wid;
    __shared__ __align__(16) unsigned short vs[4][K_][264];
    __shared__ __align__(16) float atts[4][NH_][K_];
    int row = lane & 15;            // M-row of the score tile (neighbor slot) / B-row (head)
    int off8 = (lane >> 4) * 8;     // k-chunk within 32-wide MFMA K step
    int idx_l = idx[point*K_ + row];

    // ---- stage V rows (gathered) into LDS as bf16, vectorized ----
    #pragma unroll
    for (int t = 0; t < 8; ++t) {
        int vr = 2*t + (lane >> 5);
        int j = __shfl(idx_l, vr, 64);
        int cc = (lane & 31) * 8;
        *(bf16x8*)&vs[wid][vr][cc] = *(const bf16x8*)&kv[(size_t)j*512 + 256 + cc];
    }

    // ---- scores via MFMA ----
    f32x4 acc = {0.f, 0.f, 0.f, 0.f};
    const bf16x8 zero8 = {0,0,0,0,0,0,0,0};
    #pragma unroll
    for (int s = 0; s < 8; ++s) {   // s2: A = kpe, B rows 0-7 = r
        bf16x8 a = *(const bf16x8*)&kpe[((size_t)point*K_ + row)*C_ + s*32 + off8];
        bf16x8 b = zero8;
        if (row < 8) b = *(const bf16x8*)&r[(size_t)point*NH_*C_ + row*C_ + s*32 + off8];
        acc = __builtin_amdgcn_mfma_f32_16x16x32_bf16(a, b, acc, 0, 0, 0);
    }
    #pragma unroll
    for (int s = 0; s < 8; ++s) {   // s1: A = gathered k, B row 8+s = q slice of head s
        bf16x8 a = *(const bf16x8*)&kv[(size_t)idx_l*512 + s*32 + off8];
        bf16x8 b = zero8;
        if (row == 8 + s) b = *(const bf16x8*)&q[(size_t)point*C_ + s*32 + off8];
        acc = __builtin_amdgcn_mfma_f32_16x16x32_bf16(a, b, acc, 0, 0, 0);
    }

    // ---- combine s1+s2 (lane n gets col n+8 via xor-8), softmax over k ----
    const float scale = 0.1767766952966369f;  // 1/sqrt(32)
    float sv[4], m = -1e30f;
    #pragma unroll
    for (int rg = 0; rg < 4; ++rg) {
        float o = __shfl_xor(acc[rg], 8, 64);
        sv[rg] = (acc[rg] + o) * scale;
        m = fmaxf(m, sv[rg]);
    }
    m = fmaxf(m, __shfl_xor(m, 16, 64));
    m = fmaxf(m, __shfl_xor(m, 32, 64));
    float sum = 0.f;
    #pragma unroll
    for (int rg = 0; rg < 4; ++rg) { sv[rg] = __expf(sv[rg] - m); sum += sv[rg]; }
    sum += __shfl_xor(sum, 16, 64);
    sum += __shfl_xor(sum, 32, 64);
    float inv = 1.f / sum;
    if (row < 8) {
        f32x4 av = { sv[0]*inv, sv[1]*inv, sv[2]*inv, sv[3]*inv };
        *(f32x4*)&atts[wid][row][(lane >> 4) * 4] = av;   // atts[h][k]
    }

    // ---- PV: lane owns 4 consecutive channels ----
    int h = lane >> 3;              // (lane*4)>>5
    float att_f[16];
    #pragma unroll
    for (int u = 0; u < 4; ++u) {
        f32x4 t4 = *(const f32x4*)&atts[wid][h][u*4];
        att_f[u*4+0] = t4[0]; att_f[u*4+1] = t4[1]; att_f[u*4+2] = t4[2]; att_f[u*4+3] = t4[3];
    }
    int cbase = lane * 4;
    float o0 = 0.f, o1 = 0.f, o2 = 0.f, o3 = 0.f;
    #pragma unroll
    for (int k = 0; k < K_; ++k) {
        unsigned long long vv = *(const unsigned long long*)&vs[wid][k][cbase];
        unsigned lo = (unsigned)vv, hi = (unsigned)(vv >> 32);
        float a = att_f[k];
        o0 += a * __uint_as_float(lo << 16);
        o1 += a * __uint_as_float(lo & 0xffff0000u);
        o2 += a * __uint_as_float(hi << 16);
        o3 += a * __uint_as_float(hi & 0xffff0000u);
    }
    unsigned p0 = (unsigned)f2bf(o0) | ((unsigned)f2bf(o1) << 16);
    unsigned p1 = (unsigned)f2bf(o2) | ((unsigned)f2bf(o3) << 16);
    unsigned out2[2] = { p0, p1 };
    *(unsigned long long*)&ao[(size_t)point*C_ + cbase] = *(const unsigned long long*)out2;
}

// ---------------- LayerNorm: one block per row ----------------
// OMODE: 1 = fp32 + bf16, 2 = bf16 only
template<int OMODE>
__global__ __launch_bounds__(256) void ln_kernel(const float* __restrict__ in,
                                                 const float* __restrict__ w,
                                                 const float* __restrict__ b,
                                                 const float* __restrict__ addvec,
                                                 float* __restrict__ outF,
                                                 unsigned short* __restrict__ outB) {
    int row = blockIdx.x, tid = threadIdx.x;
    float x = in[(size_t)row*C_ + tid];
    __shared__ float red[4];
    float v = x;
    #pragma unroll
    for (int off = 32; off; off >>= 1) v += __shfl_xor(v, off, 64);
    if ((tid & 63) == 0) red[tid >> 6] = v;
    __syncthreads();
    float mean = (red[0]+red[1]+red[2]+red[3]) * (1.f/C_);
    __syncthreads();
    float dx = x - mean;
    v = dx*dx;
    #pragma unroll
    for (int off = 32; off; off >>= 1) v += __shfl_xor(v, off, 64);
    if ((tid & 63) == 0) red[tid >> 6] = v;
    __syncthreads();
    float var = (red[0]+red[1]+red[2]+red[3]) * (1.f/C_);
    float y = dx * rsqrtf(var + 1e-5f) * w[tid] + b[tid];
    if (addvec) y += addvec[tid];
    if (OMODE != 2) outF[(size_t)row*C_ + tid] = y;
    outB[(size_t)row*C_ + tid] = f2bf(y);
}

// ---------------- fused ln_out (layer i) + ln_attn (layer i+1) ----------------
__global__ __launch_bounds__(256) void ln2_kernel(const float* __restrict__ in,
                                                  const float* __restrict__ w1, const float* __restrict__ b1v,
                                                  const float* __restrict__ w2, const float* __restrict__ b2v,
                                                  const float* __restrict__ qpe,
                                                  float* __restrict__ outF, unsigned short* __restrict__ outB,
                                                  unsigned short* __restrict__ outT2) {
    int row = blockIdx.x, tid = threadIdx.x;
    float x = in[(size_t)row*C_ + tid];
    __shared__ float red[4];
    float v = x;
    #pragma unroll
    for (int off = 32; off; off >>= 1) v += __shfl_xor(v, off, 64);
    if ((tid & 63) == 0) red[tid >> 6] = v;
    __syncthreads();
    float mean = (red[0]+red[1]+red[2]+red[3]) * (1.f/C_);
    __syncthreads();
    float dx = x - mean;
    v = dx*dx;
    #pragma unroll
    for (int off = 32; off; off >>= 1) v += __shfl_xor(v, off, 64);
    if ((tid & 63) == 0) red[tid >> 6] = v;
    __syncthreads();
    float var = (red[0]+red[1]+red[2]+red[3]) * (1.f/C_);
    float y = dx * rsqrtf(var + 1e-5f) * w1[tid] + b1v[tid];
    outF[(size_t)row*C_ + tid] = y;
    outB[(size_t)row*C_ + tid] = f2bf(y);
    // second LN over y
    v = y;
    #pragma unroll
    for (int off = 32; off; off >>= 1) v += __shfl_xor(v, off, 64);
    __syncthreads();
    if ((tid & 63) == 0) red[tid >> 6] = v;
    __syncthreads();
    float mean2 = (red[0]+red[1]+red[2]+red[3]) * (1.f/C_);
    __syncthreads();
    float dy = y - mean2;
    v = dy*dy;
    #pragma unroll
    for (int off = 32; off; off >>= 1) v += __shfl_xor(v, off, 64);
    if ((tid & 63) == 0) red[tid >> 6] = v;
    __syncthreads();
    float var2 = (red[0]+red[1]+red[2]+red[3]) * (1.f/C_);
    float z = dy * rsqrtf(var2 + 1e-5f) * w2[tid] + b2v[tid] + qpe[tid];
    outT2[(size_t)row*C_ + tid] = f2bf(z);
}

extern "C" void kernel_launch(void* const* d_in, const int* in_sizes, int n_in,
                              void* d_out, int out_size, void* d_ws, size_t ws_size,
                              hipStream_t stream) {
    const float* feature  = (const float*)d_in[0];
    const float* xyz      = (const float*)d_in[1];
    const float* pe_W1    = (const float*)d_in[2];
    const float* pe_b1    = (const float*)d_in[3];
    const float* pe_W2    = (const float*)d_in[4];
    const float* pe_b2    = (const float*)d_in[5];
    const float* Wqkv     = (const float*)d_in[6];
    const float* bqkv     = (const float*)d_in[7];
    const float* Wo       = (const float*)d_in[8];
    const float* bo       = (const float*)d_in[9];
    const float* ln_attn_w= (const float*)d_in[10];
    const float* ln_attn_b= (const float*)d_in[11];
    const float* W1       = (const float*)d_in[12];
    const float* b1       = (const float*)d_in[13];
    const float* W2       = (const float*)d_in[14];
    const float* b2       = (const float*)d_in[15];
    const float* ln_ffn_w = (const float*)d_in[16];
    const float* ln_ffn_b = (const float*)d_in[17];
    const float* ln_out_w = (const float*)d_in[18];
    const float* ln_out_b = (const float*)d_in[19];

    // ---- workspace layout ----
    float* ws = (float*)d_ws;
    float* w_out = ws;                                   // BN*C fp32
    float* w_qpe = w_out + (size_t)BN_*C_;               // C fp32
    unsigned short* bptr = (unsigned short*)(w_qpe + C_ + 64);
    unsigned short* b_out = bptr;  bptr += (size_t)BN_*C_;
    unsigned short* b_t2  = bptr;  bptr += (size_t)BN_*C_;
    unsigned short* b_q   = bptr;  bptr += (size_t)BN_*C_;
    unsigned short* b_kv  = bptr;  bptr += (size_t)BN_*512;
    unsigned short* b_ao  = bptr;  bptr += (size_t)BN_*C_;
    unsigned short* b_ffh = bptr;  bptr += (size_t)BN_*FF_;
    unsigned short* w_kpe = bptr;  bptr += (size_t)BN_*K_*C_;
    unsigned short* w_r   = bptr;  bptr += (size_t)BN_*NH_*C_;
    unsigned short* b_hid = bptr;  bptr += (size_t)BN_*K_*C_;
    unsigned short* bWpe  = bptr;  bptr += (size_t)C_*C_;
    unsigned short* bWqkv = bptr;  bptr += (size_t)L_*3*C_*C_;
    unsigned short* bWo   = bptr;  bptr += (size_t)L_*C_*C_;
    unsigned short* bW1   = bptr;  bptr += (size_t)L_*FF_*C_;
    unsigned short* bW2   = bptr;  bptr += (size_t)L_*C_*FF_;
    int* w_idx = (int*)bptr;

    // ---- weight conversions ----
    f2bf_kernel<<<(C_*C_+255)/256, 256, 0, stream>>>(pe_W2, bWpe, C_*C_);
    f2bf_kernel<<<(L_*3*C_*C_+255)/256, 256, 0, stream>>>(Wqkv, bWqkv, L_*3*C_*C_);
    f2bf_kernel<<<(L_*C_*C_+255)/256, 256, 0, stream>>>(Wo, bWo, L_*C_*C_);
    f2bf_kernel<<<(L_*FF_*C_+255)/256, 256, 0, stream>>>(W1, bW1, L_*FF_*C_);
    f2bf_kernel<<<(L_*C_*FF_+255)/256, 256, 0, stream>>>(W2, bW2, L_*C_*FF_);

    // ---- preprocessing ----
    reshape_in_kernel<<<BN_, 256, 0, stream>>>(feature, w_out, b_out);
    knn_kernel<<<BN_/4, 256, 0, stream>>>(xyz, w_idx);
    qpe_kernel<<<1, 256, 0, stream>>>(pe_b1, pe_W2, pe_b2, w_qpe);
    pe_hidden_kernel<<<BN_, 256, 0, stream>>>(xyz, w_idx, pe_W1, pe_b1, b_hid);
    gemm_bf16<0,false,2><<<dim3(C_/64, (BN_*K_)/64), 256, 0, stream>>>(
        b_hid, bWpe, pe_b2, nullptr, nullptr, w_kpe, BN_*K_, C_, C_);

    // layer 0 ln_attn
    ln_kernel<2><<<BN_, 256, 0, stream>>>(w_out, ln_attn_w, ln_attn_b, w_qpe, nullptr, b_t2);

    // ---- layers ----
    for (int i = 0; i < L_; ++i) {
        const unsigned short* Wq = bWqkv + (size_t)i*3*C_*C_;
        const unsigned short* Wk = Wq + (size_t)C_*C_;
        const float* bq = bqkv + (size_t)i*3*C_;
        const float* bk = bq + C_;

        gemm_bf16<0,false,2><<<dim3(C_/64, BN_/64), 256, 0, stream>>>(
            b_t2, Wq, bq, nullptr, nullptr, b_q, BN_, C_, C_);
        gemm_bf16<0,false,2><<<dim3(512/64, BN_/64), 256, 0, stream>>>(
            b_out, Wk, bk, nullptr, nullptr, b_kv, BN_, 512, C_);
        r_kernel<<<dim3(BN_/16, NH_), 256, 0, stream>>>(b_q, Wk, w_r);
        attn_kernel<<<BN_/4, 256, 0, stream>>>(b_q, b_kv, w_kpe, w_r, w_idx, b_ao);
        gemm_bf16<0,true,0><<<dim3(C_/64, BN_/64), 256, 0, stream>>>(
            b_ao, bWo + (size_t)i*C_*C_, bo + i*C_, w_out, w_out, nullptr, BN_, C_, C_);

        ln_kernel<2><<<BN_, 256, 0, stream>>>(w_out, ln_ffn_w + i*C_, ln_ffn_b + i*C_, nullptr, nullptr, b_t2);
        gemm_bf16<1,false,2><<<dim3(FF_/64, BN_/64), 256, 0, stream>>>(
            b_t2, bW1 + (size_t)i*FF_*C_, b1 + i*FF_, nullptr, nullptr, b_ffh, BN_, FF_, C_);
        gemm_bf16<0,true,0><<<dim3(C_/64, BN_/64), 256, 0, stream>>>(
            b_ffh, bW2 + (size_t)i*C_*FF_, b2 + i*C_, w_out, w_out, nullptr, BN_, C_, FF_);

        if (i < L_-1) {
            ln2_kernel<<<BN_, 256, 0, stream>>>(w_out, ln_out_w + i*C_, ln_out_b + i*C_,
                                                ln_attn_w + (i+1)*C_, ln_attn_b + (i+1)*C_,
                                                w_qpe, w_out, b_out, b_t2);
        } else {
            ln_kernel<1><<<BN_, 256, 0, stream>>>(w_out, ln_out_w + i*C_, ln_out_b + i*C_, nullptr, w_out, b_out);
        }
    }

    reshape_out_kernel<<<BN_, 256, 0, stream>>>(w_out, (float*)d_out);
}

// Round 6
// 726.860 us; speedup vs baseline: 4.4218x; 1.0134x over previous
//
#include <hip/hip_runtime.h>
#include <math.h>

#define BS_ 2
#define V_ 4
#define H_ 24
#define W_ 24
#define N_ (V_*H_*W_)        // 2304
#define BN_ (BS_*N_)         // 4608
#define C_ 256
#define K_ 16
#define L_ 6
#define NH_ 8
#define DH_ 32
#define FF_ 1024

typedef __attribute__((ext_vector_type(4))) float f32x4;
typedef __attribute__((ext_vector_type(8))) short bf16x8;

__device__ inline unsigned short f2bf(float x) {
    unsigned u = __float_as_uint(x);
    unsigned r = u + 0x7fffu + ((u >> 16) & 1u);
    return (unsigned short)(r >> 16);
}
__device__ inline float bf2f(unsigned short h) {
    return __uint_as_float(((unsigned)h) << 16);
}

// ---------------- fused fp32 -> bf16 for all 5 weight tensors (contiguous dst) ----------------
__global__ __launch_bounds__(256) void f2bf5_kernel(const float* __restrict__ s0,  // pe_W2   65536
                                                    const float* __restrict__ s1,  // Wqkv  1179648
                                                    const float* __restrict__ s2,  // Wo     393216
                                                    const float* __restrict__ s3,  // W1    1572864
                                                    const float* __restrict__ s4,  // W2    1572864
                                                    unsigned short* __restrict__ dst) {
    const int c0 = 65536, c1 = 1245184, c2 = 1638400, c3 = 3211264, c4 = 4784128;
    int i = blockIdx.x*256 + threadIdx.x;
    if (i >= c4) return;
    float v;
    if (i < c0)      v = s0[i];
    else if (i < c1) v = s1[i - c0];
    else if (i < c2) v = s2[i - c1];
    else if (i < c3) v = s3[i - c2];
    else             v = s4[i - c3];
    dst[i] = f2bf(v);
}

// ---------------- reshape in: (B*V,C,H,W) -> (BN, C) fp32 + bf16 ----------------
__global__ __launch_bounds__(256) void reshape_in_kernel(const float* __restrict__ f,
                                                         float* __restrict__ outF,
                                                         unsigned short* __restrict__ outB) {
    int bn = blockIdx.x, c = threadIdx.x;
    int b = bn / N_, rem = bn % N_;
    int v = rem / (H_*W_), hw = rem % (H_*W_);
    float x = f[(((size_t)(b*V_ + v)*C_ + c)*(H_*W_)) + hw];
    outF[(size_t)bn*C_ + c] = x;
    outB[(size_t)bn*C_ + c] = f2bf(x);
}

// ---------------- reshape out: (BN, C) -> (B*V,C,H,W) ----------------
__global__ __launch_bounds__(256) void reshape_out_kernel(const float* __restrict__ in,
                                                          float* __restrict__ o) {
    int bn = blockIdx.x, c = threadIdx.x;
    int b = bn / N_, rem = bn % N_;
    int v = rem / (H_*W_), hw = rem % (H_*W_);
    o[(((size_t)(b*V_ + v)*C_ + c)*(H_*W_)) + hw] = in[(size_t)bn*C_ + c];
}

// ---------------- KNN: one WAVE per query point, 4 points/block ----------------
__global__ __launch_bounds__(256) void knn_kernel(const float* __restrict__ pts,
                                                  int* __restrict__ idx) {
    int wid = threadIdx.x >> 6, lane = threadIdx.x & 63;
    int point = blockIdx.x*4 + wid;          // blocks never straddle a batch (2304 % 4 == 0)
    int b = point / N_;
    int il = point % N_;
    __shared__ float ps[N_*3];
    for (int l = threadIdx.x; l < N_*3; l += 256) ps[l] = pts[(size_t)b*N_*3 + l];
    __syncthreads();
    float qx = ps[il*3], qy = ps[il*3+1], qz = ps[il*3+2];
    unsigned long long key[36];              // 64 lanes x 36 = 2304 candidates
    #pragma unroll
    for (int s = 0; s < 36; ++s) {
        int j = lane + 64*s;
        float dx = qx - ps[j*3], dy = qy - ps[j*3+1], dz = qz - ps[j*3+2];
        float d2 = dx*dx + dy*dy + dz*dz;
        key[s] = ((unsigned long long)__float_as_uint(d2) << 32) | (unsigned)j;
    }
    for (int it = 0; it < K_; ++it) {
        // 4-way ILP tree min over 36 keys
        unsigned long long b0 = key[0], b1 = key[1], b2 = key[2], b3 = key[3];
        #pragma unroll
        for (int s = 4; s < 36; s += 4) {
            b0 = key[s]   < b0 ? key[s]   : b0;
            b1 = key[s+1] < b1 ? key[s+1] : b1;
            b2 = key[s+2] < b2 ? key[s+2] : b2;
            b3 = key[s+3] < b3 ? key[s+3] : b3;
        }
        unsigned long long m01 = b0 < b1 ? b0 : b1;
        unsigned long long m23 = b2 < b3 ? b2 : b3;
        unsigned long long best = m01 < m23 ? m01 : m23;
        #pragma unroll
        for (int off = 32; off; off >>= 1) {
            unsigned long long o = __shfl_xor(best, off, 64);
            if (o < best) best = o;
        }
        int wj = (int)(best & 0xffffffffu);
        if (lane == 0) idx[point*K_ + it] = b*N_ + wj;
        if ((wj & 63) == lane) {             // remove winner (static unroll, reg-resident)
            int sw = wj >> 6;
            #pragma unroll
            for (int s = 0; s < 36; ++s) if (s == sw) key[s] = ~0ull;
        }
    }
}

// ---------------- q_pe = relu(b1)@W2^T + b2 (fp32, tiny) ----------------
__global__ __launch_bounds__(256) void qpe_kernel(const float* __restrict__ b1,
                                                  const float* __restrict__ W2,
                                                  const float* __restrict__ b2,
                                                  float* __restrict__ qpe) {
    __shared__ float h[C_];
    int tid = threadIdx.x;
    h[tid] = fmaxf(b1[tid], 0.f);
    __syncthreads();
    float acc = 0.f;
    for (int j = 0; j < C_; ++j) acc += h[j] * W2[(size_t)tid*C_ + j];
    qpe[tid] = acc + b2[tid];
}

// ---------------- PE hidden (bf16): one block per point, 16 rows each ----------------
__global__ __launch_bounds__(256) void pe_hidden_kernel(const float* __restrict__ pts,
                                                        const int* __restrict__ idx,
                                                        const float* __restrict__ W1,
                                                        const float* __restrict__ b1,
                                                        unsigned short* __restrict__ hidden) {
    int point = blockIdx.x;
    int c = threadIdx.x;
    __shared__ float rel[K_][3];
    if (threadIdx.x < K_*3) {
        int k = threadIdx.x / 3, ax = threadIdx.x % 3;
        int j = idx[point*K_ + k];
        rel[k][ax] = pts[(size_t)j*3 + ax] - pts[(size_t)point*3 + ax];
    }
    __syncthreads();
    float w0 = W1[c*3], w1 = W1[c*3+1], w2 = W1[c*3+2], bb = b1[c];
    #pragma unroll
    for (int k = 0; k < K_; ++k) {
        float v = rel[k][0]*w0 + rel[k][1]*w1 + rel[k][2]*w2 + bb;
        hidden[((size_t)point*K_ + k)*C_ + c] = f2bf(fmaxf(v, 0.f));
    }
}

// ---------------- bf16 MFMA GEMM body: dbuf LDS, 1 barrier/K-step, async-stage split ----------
// D = act(A @ W^T + bias) (+res). A: rows stride sA; W pre-offset to block's 64 n-rows, stride sW.
// Epilogue: bias col = bcol0+pl (if bias), out col = on0+pl, out/res row stride sO.
template<int ACT, bool RES, int OMODE>
__device__ __forceinline__ void gemm_body(const unsigned short* __restrict__ A, int sA,
                                          const unsigned short* __restrict__ W, int sW,
                                          const float* __restrict__ bias, int bcol0,
                                          const float* __restrict__ res,
                                          float* __restrict__ outF,
                                          unsigned short* __restrict__ outB,
                                          int sO, int on0, int m0, int K) {
    __shared__ unsigned short As[2][64][40];
    __shared__ unsigned short Ws[2][64][40];
    int tid = threadIdx.x;
    int wave = tid >> 6, lane = tid & 63;
    int wr = wave >> 1, wc = wave & 1;           // 2x2 waves, wave tile 32x32
    f32x4 acc[2][2];
    #pragma unroll
    for (int i = 0; i < 2; ++i)
        #pragma unroll
        for (int j = 0; j < 2; ++j) acc[i][j] = (f32x4){0.f, 0.f, 0.f, 0.f};

    int r = tid >> 2, ch = tid & 3;
    const unsigned short* pA = A + (size_t)(m0 + r)*sA + ch*8;
    const unsigned short* pW = W + (size_t)r*sW + ch*8;
    // prologue: stage tile 0 into buf 0
    *(bf16x8*)&As[0][r][ch*8] = *(const bf16x8*)pA;
    *(bf16x8*)&Ws[0][r][ch*8] = *(const bf16x8*)pW;
    __syncthreads();
    int nk = K >> 5;
    for (int t = 0; t < nk; ++t) {
        int cur = t & 1;
        bool has_next = (t + 1 < nk);
        bf16x8 la, lw;
        if (has_next) {                      // issue next-tile loads EARLY (hide under MFMA)
            la = *(const bf16x8*)(pA + (t+1)*32);
            lw = *(const bf16x8*)(pW + (t+1)*32);
        }
        int kf = (lane >> 4) * 8;
        bf16x8 af[2], wf[2];
        #pragma unroll
        for (int i = 0; i < 2; ++i) af[i] = *(const bf16x8*)&As[cur][wr*32 + i*16 + (lane & 15)][kf];
        #pragma unroll
        for (int j = 0; j < 2; ++j) wf[j] = *(const bf16x8*)&Ws[cur][wc*32 + j*16 + (lane & 15)][kf];
        #pragma unroll
        for (int i = 0; i < 2; ++i)
            #pragma unroll
            for (int j = 0; j < 2; ++j)
                acc[i][j] = __builtin_amdgcn_mfma_f32_16x16x32_bf16(af[i], wf[j], acc[i][j], 0, 0, 0);
        if (has_next) {                      // ds_write LATE (vmcnt wait lands after MFMAs)
            *(bf16x8*)&As[cur^1][r][ch*8] = la;
            *(bf16x8*)&Ws[cur^1][r][ch*8] = lw;
        }
        __syncthreads();
    }
    // C/D layout: col = lane&15, row = (lane>>4)*4 + reg
    #pragma unroll
    for (int i = 0; i < 2; ++i) {
        #pragma unroll
        for (int j = 0; j < 2; ++j) {
            #pragma unroll
            for (int rg = 0; rg < 4; ++rg) {
                int m = m0 + wr*32 + i*16 + (lane >> 4)*4 + rg;
                int pl = wc*32 + j*16 + (lane & 15);
                float v = acc[i][j][rg];
                if (bias) v += bias[bcol0 + pl];
                if (ACT == 1) v = fmaxf(v, 0.f);
                if (RES) v += res[(size_t)m*sO + on0 + pl];
                if (OMODE != 2) outF[(size_t)m*sO + on0 + pl] = v;
                if (OMODE != 0) outB[(size_t)m*sO + on0 + pl] = f2bf(v);
            }
        }
    }
}

// generic GEMM wrapper: OUT[M x P] = act(A[M x K] @ W[P x K]^T + bias) (+res)
template<int ACT, bool RES, int OMODE>
__global__ __launch_bounds__(256) void gemm_k(const unsigned short* __restrict__ A,
                                              const unsigned short* __restrict__ W,
                                              const float* __restrict__ bias,
                                              const float* __restrict__ res,
                                              float* __restrict__ outF,
                                              unsigned short* __restrict__ outB,
                                              int P, int K) {
    int n0 = blockIdx.x * 64, m0 = blockIdx.y * 64;
    gemm_body<ACT,RES,OMODE>(A, K, W + (size_t)n0*K, K, bias, n0, res, outF, outB, P, n0, m0, K);
}

// fused q + kv GEMM: blockIdx.x 0..3 -> q (A=t2), 4..11 -> k,v (A=out)
__global__ __launch_bounds__(256) void qkv_kernel(const unsigned short* __restrict__ t2,
                                                  const unsigned short* __restrict__ outb,
                                                  const unsigned short* __restrict__ Wqkv_l,
                                                  const float* __restrict__ bqkv_l,
                                                  unsigned short* __restrict__ b_q,
                                                  unsigned short* __restrict__ b_kv) {
    int bx = blockIdx.x;
    int n0 = bx * 64;                       // 0..767 into Wqkv_l rows
    int m0 = blockIdx.y * 64;
    if (bx < 4) {
        gemm_body<0,false,2>(t2, C_, Wqkv_l + (size_t)n0*C_, C_, bqkv_l, n0,
                             nullptr, nullptr, b_q, 256, n0, m0, C_);
    } else {
        gemm_body<0,false,2>(outb, C_, Wqkv_l + (size_t)n0*C_, C_, bqkv_l, n0,
                             nullptr, nullptr, b_kv, 512, n0 - 256, m0, C_);
    }
}

// ---------------- r via MFMA: per-head GEMM r_h[BN x 256] = q_h[BN x 32] @ Wk_h^T ----------------
__global__ __launch_bounds__(256) void rk_kernel(const unsigned short* __restrict__ q,
                                                 const unsigned short* __restrict__ Wqkv_l,
                                                 unsigned short* __restrict__ r) {
    int n0 = blockIdx.x * 64, m0 = blockIdx.y * 64, h = blockIdx.z;
    __shared__ unsigned short As[64][40];   // [point][d]
    __shared__ unsigned short Ws[64][40];   // [cin][d]  (transposed Wk slice)
    int tid = threadIdx.x;
    int wave = tid >> 6, lane = tid & 63;
    int wr = wave >> 1, wc = wave & 1;
    // stage A
    *(bf16x8*)&As[tid>>2][(tid&3)*8] =
        *(const bf16x8*)&q[(size_t)(m0 + (tid>>2))*C_ + h*DH_ + (tid&3)*8];
    // stage W transposed: Wk[h*32+d][cin] -> Ws[cin][d]
    {
        int d = tid >> 3, cg = tid & 7;
        bf16x8 wv = *(const bf16x8*)&Wqkv_l[(size_t)(C_ + h*DH_ + d)*C_ + n0 + cg*8];
        #pragma unroll
        for (int j = 0; j < 8; ++j) Ws[cg*8 + j][d] = (unsigned short)wv[j];
    }
    __syncthreads();
    int kf = (lane >> 4) * 8;
    bf16x8 af[2], wf[2];
    #pragma unroll
    for (int i = 0; i < 2; ++i) af[i] = *(const bf16x8*)&As[wr*32 + i*16 + (lane & 15)][kf];
    #pragma unroll
    for (int j = 0; j < 2; ++j) wf[j] = *(const bf16x8*)&Ws[wc*32 + j*16 + (lane & 15)][kf];
    f32x4 acc[2][2];
    #pragma unroll
    for (int i = 0; i < 2; ++i)
        #pragma unroll
        for (int j = 0; j < 2; ++j)
            acc[i][j] = __builtin_amdgcn_mfma_f32_16x16x32_bf16(af[i], wf[j],
                          (f32x4){0.f,0.f,0.f,0.f}, 0, 0, 0);
    #pragma unroll
    for (int i = 0; i < 2; ++i)
        #pragma unroll
        for (int j = 0; j < 2; ++j)
            #pragma unroll
            for (int rg = 0; rg < 4; ++rg) {
                int m = m0 + wr*32 + i*16 + (lane >> 4)*4 + rg;
                int pl = wc*32 + j*16 + (lane & 15);
                r[(size_t)m*(NH_*C_) + h*C_ + n0 + pl] = f2bf(acc[i][j][rg]);
            }
}

// ---------------- attention: one WAVE per point, MFMA scores ----------------
__global__ __launch_bounds__(256) void attn_kernel(const unsigned short* __restrict__ q,
                                                   const unsigned short* __restrict__ kv,
                                                   const unsigned short* __restrict__ kpe,
                                                   const unsigned short* __restrict__ r,
                                                   const int* __restrict__ idx,
                                                   unsigned short* __restrict__ ao) {
    int wid = threadIdx.x >> 6, lane = threadIdx.x & 63;
    int point = blockIdx.x*4 + wid;
    __shared__ __align__(16) unsigned short vs[4][K_][264];
    __shared__ __align__(16) float atts[4][NH_][K_];
    int row = lane & 15;
    int off8 = (lane >> 4) * 8;
    int idx_l = idx[point*K_ + row];

    #pragma unroll
    for (int t = 0; t < 8; ++t) {
        int vr = 2*t + (lane >> 5);
        int j = __shfl(idx_l, vr, 64);
        int cc = (lane & 31) * 8;
        *(bf16x8*)&vs[wid][vr][cc] = *(const bf16x8*)&kv[(size_t)j*512 + 256 + cc];
    }

    f32x4 acc = {0.f, 0.f, 0.f, 0.f};
    const bf16x8 zero8 = {0,0,0,0,0,0,0,0};
    #pragma unroll
    for (int s = 0; s < 8; ++s) {   // s2: A = kpe, B rows 0-7 = r
        bf16x8 a = *(const bf16x8*)&kpe[((size_t)point*K_ + row)*C_ + s*32 + off8];
        bf16x8 b = zero8;
        if (row < 8) b = *(const bf16x8*)&r[(size_t)point*NH_*C_ + row*C_ + s*32 + off8];
        acc = __builtin_amdgcn_mfma_f32_16x16x32_bf16(a, b, acc, 0, 0, 0);
    }
    #pragma unroll
    for (int s = 0; s < 8; ++s) {   // s1: A = gathered k, B row 8+s = q slice of head s
        bf16x8 a = *(const bf16x8*)&kv[(size_t)idx_l*512 + s*32 + off8];
        bf16x8 b = zero8;
        if (row == 8 + s) b = *(const bf16x8*)&q[(size_t)point*C_ + s*32 + off8];
        acc = __builtin_amdgcn_mfma_f32_16x16x32_bf16(a, b, acc, 0, 0, 0);
    }

    const float scale = 0.1767766952966369f;
    float sv[4], m = -1e30f;
    #pragma unroll
    for (int rg = 0; rg < 4; ++rg) {
        float o = __shfl_xor(acc[rg], 8, 64);
        sv[rg] = (acc[rg] + o) * scale;
        m = fmaxf(m, sv[rg]);
    }
    m = fmaxf(m, __shfl_xor(m, 16, 64));
    m = fmaxf(m, __shfl_xor(m, 32, 64));
    float sum = 0.f;
    #pragma unroll
    for (int rg = 0; rg < 4; ++rg) { sv[rg] = __expf(sv[rg] - m); sum += sv[rg]; }
    sum += __shfl_xor(sum, 16, 64);
    sum += __shfl_xor(sum, 32, 64);
    float inv = 1.f / sum;
    if (row < 8) {
        f32x4 av = { sv[0]*inv, sv[1]*inv, sv[2]*inv, sv[3]*inv };
        *(f32x4*)&atts[wid][row][(lane >> 4) * 4] = av;
    }

    int h = lane >> 3;
    float att_f[16];
    #pragma unroll
    for (int u = 0; u < 4; ++u) {
        f32x4 t4 = *(const f32x4*)&atts[wid][h][u*4];
        att_f[u*4+0] = t4[0]; att_f[u*4+1] = t4[1]; att_f[u*4+2] = t4[2]; att_f[u*4+3] = t4[3];
    }
    int cbase = lane * 4;
    float o0 = 0.f, o1 = 0.f, o2 = 0.f, o3 = 0.f;
    #pragma unroll
    for (int k = 0; k < K_; ++k) {
        unsigned long long vv = *(const unsigned long long*)&vs[wid][k][cbase];
        unsigned lo = (unsigned)vv, hi = (unsigned)(vv >> 32);
        float a = att_f[k];
        o0 += a * __uint_as_float(lo << 16);
        o1 += a * __uint_as_float(lo & 0xffff0000u);
        o2 += a * __uint_as_float(hi << 16);
        o3 += a * __uint_as_float(hi & 0xffff0000u);
    }
    unsigned p0 = (unsigned)f2bf(o0) | ((unsigned)f2bf(o1) << 16);
    unsigned p1 = (unsigned)f2bf(o2) | ((unsigned)f2bf(o3) << 16);
    unsigned out2[2] = { p0, p1 };
    *(unsigned long long*)&ao[(size_t)point*C_ + cbase] = *(const unsigned long long*)out2;
}

// ---------------- LayerNorm: one block per row ----------------
template<int OMODE>
__global__ __launch_bounds__(256) void ln_kernel(const float* __restrict__ in,
                                                 const float* __restrict__ w,
                                                 const float* __restrict__ b,
                                                 const float* __restrict__ addvec,
                                                 float* __restrict__ outF,
                                                 unsigned short* __restrict__ outB) {
    int row = blockIdx.x, tid = threadIdx.x;
    float x = in[(size_t)row*C_ + tid];
    __shared__ float red[4];
    float v = x;
    #pragma unroll
    for (int off = 32; off; off >>= 1) v += __shfl_xor(v, off, 64);
    if ((tid & 63) == 0) red[tid >> 6] = v;
    __syncthreads();
    float mean = (red[0]+red[1]+red[2]+red[3]) * (1.f/C_);
    __syncthreads();
    float dx = x - mean;
    v = dx*dx;
    #pragma unroll
    for (int off = 32; off; off >>= 1) v += __shfl_xor(v, off, 64);
    if ((tid & 63) == 0) red[tid >> 6] = v;
    __syncthreads();
    float var = (red[0]+red[1]+red[2]+red[3]) * (1.f/C_);
    float y = dx * rsqrtf(var + 1e-5f) * w[tid] + b[tid];
    if (addvec) y += addvec[tid];
    if (OMODE != 2) outF[(size_t)row*C_ + tid] = y;
    outB[(size_t)row*C_ + tid] = f2bf(y);
}

// ---------------- fused ln_out (layer i) + ln_attn (layer i+1) ----------------
__global__ __launch_bounds__(256) void ln2_kernel(const float* __restrict__ in,
                                                  const float* __restrict__ w1, const float* __restrict__ b1v,
                                                  const float* __restrict__ w2, const float* __restrict__ b2v,
                                                  const float* __restrict__ qpe,
                                                  float* __restrict__ outF, unsigned short* __restrict__ outB,
                                                  unsigned short* __restrict__ outT2) {
    int row = blockIdx.x, tid = threadIdx.x;
    float x = in[(size_t)row*C_ + tid];
    __shared__ float red[4];
    float v = x;
    #pragma unroll
    for (int off = 32; off; off >>= 1) v += __shfl_xor(v, off, 64);
    if ((tid & 63) == 0) red[tid >> 6] = v;
    __syncthreads();
    float mean = (red[0]+red[1]+red[2]+red[3]) * (1.f/C_);
    __syncthreads();
    float dx = x - mean;
    v = dx*dx;
    #pragma unroll
    for (int off = 32; off; off >>= 1) v += __shfl_xor(v, off, 64);
    if ((tid & 63) == 0) red[tid >> 6] = v;
    __syncthreads();
    float var = (red[0]+red[1]+red[2]+red[3]) * (1.f/C_);
    float y = dx * rsqrtf(var + 1e-5f) * w1[tid] + b1v[tid];
    outF[(size_t)row*C_ + tid] = y;
    outB[(size_t)row*C_ + tid] = f2bf(y);
    // second LN over y
    v = y;
    #pragma unroll
    for (int off = 32; off; off >>= 1) v += __shfl_xor(v, off, 64);
    __syncthreads();
    if ((tid & 63) == 0) red[tid >> 6] = v;
    __syncthreads();
    float mean2 = (red[0]+red[1]+red[2]+red[3]) * (1.f/C_);
    __syncthreads();
    float dy = y - mean2;
    v = dy*dy;
    #pragma unroll
    for (int off = 32; off; off >>= 1) v += __shfl_xor(v, off, 64);
    if ((tid & 63) == 0) red[tid >> 6] = v;
    __syncthreads();
    float var2 = (red[0]+red[1]+red[2]+red[3]) * (1.f/C_);
    float z = dy * rsqrtf(var2 + 1e-5f) * w2[tid] + b2v[tid] + qpe[tid];
    outT2[(size_t)row*C_ + tid] = f2bf(z);
}

extern "C" void kernel_launch(void* const* d_in, const int* in_sizes, int n_in,
                              void* d_out, int out_size, void* d_ws, size_t ws_size,
                              hipStream_t stream) {
    const float* feature  = (const float*)d_in[0];
    const float* xyz      = (const float*)d_in[1];
    const float* pe_W1    = (const float*)d_in[2];
    const float* pe_b1    = (const float*)d_in[3];
    const float* pe_W2    = (const float*)d_in[4];
    const float* pe_b2    = (const float*)d_in[5];
    const float* Wqkv     = (const float*)d_in[6];
    const float* bqkv     = (const float*)d_in[7];
    const float* Wo       = (const float*)d_in[8];
    const float* bo       = (const float*)d_in[9];
    const float* ln_attn_w= (const float*)d_in[10];
    const float* ln_attn_b= (const float*)d_in[11];
    const float* W1       = (const float*)d_in[12];
    const float* b1       = (const float*)d_in[13];
    const float* W2       = (const float*)d_in[14];
    const float* b2       = (const float*)d_in[15];
    const float* ln_ffn_w = (const float*)d_in[16];
    const float* ln_ffn_b = (const float*)d_in[17];
    const float* ln_out_w = (const float*)d_in[18];
    const float* ln_out_b = (const float*)d_in[19];

    // ---- workspace layout ----
    float* ws = (float*)d_ws;
    float* w_out = ws;                                   // BN*C fp32
    float* w_qpe = w_out + (size_t)BN_*C_;               // C fp32
    unsigned short* bptr = (unsigned short*)(w_qpe + C_ + 64);
    unsigned short* b_out = bptr;  bptr += (size_t)BN_*C_;
    unsigned short* b_t2  = bptr;  bptr += (size_t)BN_*C_;
    unsigned short* b_q   = bptr;  bptr += (size_t)BN_*C_;
    unsigned short* b_kv  = bptr;  bptr += (size_t)BN_*512;
    unsigned short* b_ao  = bptr;  bptr += (size_t)BN_*C_;
    unsigned short* b_ffh = bptr;  bptr += (size_t)BN_*FF_;
    unsigned short* w_kpe = bptr;  bptr += (size_t)BN_*K_*C_;
    unsigned short* w_r   = bptr;  bptr += (size_t)BN_*NH_*C_;
    unsigned short* b_hid = bptr;  bptr += (size_t)BN_*K_*C_;
    unsigned short* bWpe  = bptr;  bptr += (size_t)C_*C_;        // contiguous weight block:
    unsigned short* bWqkv = bptr;  bptr += (size_t)L_*3*C_*C_;   //   bWpe..bW2
    unsigned short* bWo   = bptr;  bptr += (size_t)L_*C_*C_;
    unsigned short* bW1   = bptr;  bptr += (size_t)L_*FF_*C_;
    unsigned short* bW2   = bptr;  bptr += (size_t)L_*C_*FF_;
    int* w_idx = (int*)bptr;

    // ---- fused weight conversion (dst = contiguous bWpe..bW2) ----
    f2bf5_kernel<<<(4784128 + 255)/256, 256, 0, stream>>>(pe_W2, Wqkv, Wo, W1, W2, bWpe);

    // ---- preprocessing ----
    reshape_in_kernel<<<BN_, 256, 0, stream>>>(feature, w_out, b_out);
    knn_kernel<<<BN_/4, 256, 0, stream>>>(xyz, w_idx);
    qpe_kernel<<<1, 256, 0, stream>>>(pe_b1, pe_W2, pe_b2, w_qpe);
    pe_hidden_kernel<<<BN_, 256, 0, stream>>>(xyz, w_idx, pe_W1, pe_b1, b_hid);
    gemm_k<0,false,2><<<dim3(C_/64, (BN_*K_)/64), 256, 0, stream>>>(
        b_hid, bWpe, pe_b2, nullptr, nullptr, w_kpe, C_, C_);

    // layer 0 ln_attn
    ln_kernel<2><<<BN_, 256, 0, stream>>>(w_out, ln_attn_w, ln_attn_b, w_qpe, nullptr, b_t2);

    // ---- layers ----
    for (int i = 0; i < L_; ++i) {
        const unsigned short* Wqkv_l = bWqkv + (size_t)i*3*C_*C_;
        const float* bqkv_l = bqkv + (size_t)i*3*C_;

        qkv_kernel<<<dim3(12, BN_/64), 256, 0, stream>>>(b_t2, b_out, Wqkv_l, bqkv_l, b_q, b_kv);
        rk_kernel<<<dim3(4, BN_/64, NH_), 256, 0, stream>>>(b_q, Wqkv_l, w_r);
        attn_kernel<<<BN_/4, 256, 0, stream>>>(b_q, b_kv, w_kpe, w_r, w_idx, b_ao);
        gemm_k<0,true,0><<<dim3(C_/64, BN_/64), 256, 0, stream>>>(
            b_ao, bWo + (size_t)i*C_*C_, bo + i*C_, w_out, w_out, nullptr, C_, C_);

        ln_kernel<2><<<BN_, 256, 0, stream>>>(w_out, ln_ffn_w + i*C_, ln_ffn_b + i*C_, nullptr, nullptr, b_t2);
        gemm_k<1,false,2><<<dim3(FF_/64, BN_/64), 256, 0, stream>>>(
            b_t2, bW1 + (size_t)i*FF_*C_, b1 + i*FF_, nullptr, nullptr, b_ffh, FF_, C_);
        gemm_k<0,true,0><<<dim3(C_/64, BN_/64), 256, 0, stream>>>(
            b_ffh, bW2 + (size_t)i*C_*FF_, b2 + i*C_, w_out, w_out, nullptr, C_, FF_);

        if (i < L_-1) {
            ln2_kernel<<<BN_, 256, 0, stream>>>(w_out, ln_out_w + i*C_, ln_out_b + i*C_,
                                                ln_attn_w + (i+1)*C_, ln_attn_b + (i+1)*C_,
                                                w_qpe, w_out, b_out, b_t2);
        } else {
            ln_kernel<1><<<BN_, 256, 0, stream>>>(w_out, ln_out_w + i*C_, ln_out_b + i*C_, nullptr, w_out, b_out);
        }
    }

    reshape_out_kernel<<<BN_, 256, 0, stream>>>(w_out, (float*)d_out);
}

// Round 7
// 682.560 us; speedup vs baseline: 4.7087x; 1.0649x over previous
//
#include <hip/hip_runtime.h>
#include <math.h>

#define BS_ 2
#define V_ 4
#define H_ 24
#define W_ 24
#define N_ (V_*H_*W_)        // 2304
#define BN_ (BS_*N_)         // 4608
#define C_ 256
#define K_ 16
#define L_ 6
#define NH_ 8
#define DH_ 32
#define FF_ 1024

typedef __attribute__((ext_vector_type(4))) float f32x4;
typedef __attribute__((ext_vector_type(8))) short bf16x8;
typedef __attribute__((ext_vector_type(4))) unsigned u32x4;

__device__ inline unsigned short f2bf(float x) {
    unsigned u = __float_as_uint(x);
    unsigned r = u + 0x7fffu + ((u >> 16) & 1u);
    return (unsigned short)(r >> 16);
}
__device__ inline float bf2f(unsigned short h) {
    return __uint_as_float(((unsigned)h) << 16);
}

// ---------------- fused fp32 -> bf16 for all 5 weight tensors (contiguous dst) ----------------
__global__ __launch_bounds__(256) void f2bf5_kernel(const float* __restrict__ s0,
                                                    const float* __restrict__ s1,
                                                    const float* __restrict__ s2,
                                                    const float* __restrict__ s3,
                                                    const float* __restrict__ s4,
                                                    unsigned short* __restrict__ dst) {
    const int c0 = 65536, c1 = 1245184, c2 = 1638400, c3 = 3211264, c4 = 4784128;
    int i = blockIdx.x*256 + threadIdx.x;
    if (i >= c4) return;
    float v;
    if (i < c0)      v = s0[i];
    else if (i < c1) v = s1[i - c0];
    else if (i < c2) v = s2[i - c1];
    else if (i < c3) v = s3[i - c2];
    else             v = s4[i - c3];
    dst[i] = f2bf(v);
}

// ---------------- reshape in + ln_attn(layer0) + qpe ----------------
__global__ __launch_bounds__(256) void reshape_in_ln(const float* __restrict__ f,
                                                     const float* __restrict__ lnw,
                                                     const float* __restrict__ lnb,
                                                     const float* __restrict__ qpe,
                                                     float* __restrict__ w_out,
                                                     unsigned short* __restrict__ b_out,
                                                     unsigned short* __restrict__ b_t2) {
    int bn = blockIdx.x, c = threadIdx.x;
    int b = bn / N_, rem = bn % N_;
    int v = rem / (H_*W_), hw = rem % (H_*W_);
    float x = f[(((size_t)(b*V_ + v)*C_ + c)*(H_*W_)) + hw];
    w_out[(size_t)bn*C_ + c] = x;
    b_out[(size_t)bn*C_ + c] = f2bf(x);
    __shared__ float red[4];
    float s = x;
    #pragma unroll
    for (int off = 32; off; off >>= 1) s += __shfl_xor(s, off, 64);
    if ((c & 63) == 0) red[c >> 6] = s;
    __syncthreads();
    float mean = (red[0]+red[1]+red[2]+red[3]) * (1.f/C_);
    __syncthreads();
    float dx = x - mean;
    s = dx*dx;
    #pragma unroll
    for (int off = 32; off; off >>= 1) s += __shfl_xor(s, off, 64);
    if ((c & 63) == 0) red[c >> 6] = s;
    __syncthreads();
    float var = (red[0]+red[1]+red[2]+red[3]) * (1.f/C_);
    float y = dx * rsqrtf(var + 1e-5f) * lnw[c] + lnb[c] + qpe[c];
    b_t2[(size_t)bn*C_ + c] = f2bf(y);
}

// ---------------- reshape out: (BN, C) -> (B*V,C,H,W) ----------------
__global__ __launch_bounds__(256) void reshape_out_kernel(const float* __restrict__ in,
                                                          float* __restrict__ o) {
    int bn = blockIdx.x, c = threadIdx.x;
    int b = bn / N_, rem = bn % N_;
    int v = rem / (H_*W_), hw = rem % (H_*W_);
    o[(((size_t)(b*V_ + v)*C_ + c)*(H_*W_)) + hw] = in[(size_t)bn*C_ + c];
}

// ---------------- KNN: one WAVE per query point, 4 points/block ----------------
__global__ __launch_bounds__(256) void knn_kernel(const float* __restrict__ pts,
                                                  int* __restrict__ idx) {
    int wid = threadIdx.x >> 6, lane = threadIdx.x & 63;
    int point = blockIdx.x*4 + wid;
    int b = point / N_;
    int il = point % N_;
    __shared__ float ps[N_*3];
    for (int l = threadIdx.x; l < N_*3; l += 256) ps[l] = pts[(size_t)b*N_*3 + l];
    __syncthreads();
    float qx = ps[il*3], qy = ps[il*3+1], qz = ps[il*3+2];
    unsigned long long key[36];
    #pragma unroll
    for (int s = 0; s < 36; ++s) {
        int j = lane + 64*s;
        float dx = qx - ps[j*3], dy = qy - ps[j*3+1], dz = qz - ps[j*3+2];
        float d2 = dx*dx + dy*dy + dz*dz;
        key[s] = ((unsigned long long)__float_as_uint(d2) << 32) | (unsigned)j;
    }
    for (int it = 0; it < K_; ++it) {
        unsigned long long b0 = key[0], b1 = key[1], b2 = key[2], b3 = key[3];
        #pragma unroll
        for (int s = 4; s < 36; s += 4) {
            b0 = key[s]   < b0 ? key[s]   : b0;
            b1 = key[s+1] < b1 ? key[s+1] : b1;
            b2 = key[s+2] < b2 ? key[s+2] : b2;
            b3 = key[s+3] < b3 ? key[s+3] : b3;
        }
        unsigned long long m01 = b0 < b1 ? b0 : b1;
        unsigned long long m23 = b2 < b3 ? b2 : b3;
        unsigned long long best = m01 < m23 ? m01 : m23;
        #pragma unroll
        for (int off = 32; off; off >>= 1) {
            unsigned long long o = __shfl_xor(best, off, 64);
            if (o < best) best = o;
        }
        int wj = (int)(best & 0xffffffffu);
        if (lane == 0) idx[point*K_ + it] = b*N_ + wj;
        if ((wj & 63) == lane) {
            int sw = wj >> 6;
            #pragma unroll
            for (int s = 0; s < 36; ++s) if (s == sw) key[s] = ~0ull;
        }
    }
}

// ---------------- q_pe = relu(b1)@W2^T + b2 (fp32, tiny) ----------------
__global__ __launch_bounds__(256) void qpe_kernel(const float* __restrict__ b1,
                                                  const float* __restrict__ W2,
                                                  const float* __restrict__ b2,
                                                  float* __restrict__ qpe) {
    __shared__ float h[C_];
    int tid = threadIdx.x;
    h[tid] = fmaxf(b1[tid], 0.f);
    __syncthreads();
    float acc = 0.f;
    for (int j = 0; j < C_; ++j) acc += h[j] * W2[(size_t)tid*C_ + j];
    qpe[tid] = acc + b2[tid];
}

// ---------------- fused pe_hidden + kpe GEMM ----------------
// kpe[row][col] = relu(rel[row] @ W1^T + b1) @ Wpe^T + b2, rows = BN*K
__global__ __launch_bounds__(256) void kpe_kernel(const float* __restrict__ pts,
                                                  const int* __restrict__ idx,
                                                  const float* __restrict__ W1,
                                                  const float* __restrict__ b1,
                                                  const unsigned short* __restrict__ Wpe,
                                                  const float* __restrict__ pb2,
                                                  unsigned short* __restrict__ kpe) {
    int tid = threadIdx.x;
    int wave = tid >> 6, lane = tid & 63;
    int wr = wave >> 1, wc = wave & 1;
    int n0 = blockIdx.x * 64;
    int m0 = blockIdx.y * 64;
    __shared__ float relS[64][4];
    __shared__ float w1S[256][4];
    __shared__ unsigned short hid[64][264];
    __shared__ unsigned short Ws[2][64][40];
    w1S[tid][0] = W1[tid*3+0];
    w1S[tid][1] = W1[tid*3+1];
    w1S[tid][2] = W1[tid*3+2];
    w1S[tid][3] = b1[tid];
    if (tid < 64) {
        int row = m0 + tid;
        int p = row >> 4;
        int j = idx[row];
        relS[tid][0] = pts[(size_t)j*3+0] - pts[(size_t)p*3+0];
        relS[tid][1] = pts[(size_t)j*3+1] - pts[(size_t)p*3+1];
        relS[tid][2] = pts[(size_t)j*3+2] - pts[(size_t)p*3+2];
    }
    int rw = tid >> 2, ch = tid & 3;
    const unsigned short* pW = Wpe + (size_t)(n0 + rw)*C_ + ch*8;
    *(bf16x8*)&Ws[0][rw][ch*8] = *(const bf16x8*)pW;
    __syncthreads();
    {
        int r = tid >> 2, cq = (tid & 3) * 64;
        float r0 = relS[r][0], r1 = relS[r][1], r2 = relS[r][2];
        #pragma unroll
        for (int u8 = 0; u8 < 8; ++u8) {
            unsigned short tmp[8];
            #pragma unroll
            for (int v = 0; v < 8; ++v) {
                int c = cq + u8*8 + v;
                f32x4 w4 = *(const f32x4*)&w1S[c][0];
                float val = r0*w4[0] + r1*w4[1] + r2*w4[2] + w4[3];
                tmp[v] = f2bf(fmaxf(val, 0.f));
            }
            *(bf16x8*)&hid[r][cq + u8*8] = *(bf16x8*)tmp;
        }
    }
    __syncthreads();
    f32x4 acc[2][2];
    #pragma unroll
    for (int i = 0; i < 2; ++i)
        #pragma unroll
        for (int j = 0; j < 2; ++j) acc[i][j] = (f32x4){0.f,0.f,0.f,0.f};
    for (int t = 0; t < 8; ++t) {
        int cur = t & 1;
        bool nx = (t < 7);
        bf16x8 lw;
        if (nx) lw = *(const bf16x8*)(pW + (t+1)*32);
        int kf = (lane >> 4) * 8;
        bf16x8 af[2], wf[2];
        #pragma unroll
        for (int i = 0; i < 2; ++i) af[i] = *(const bf16x8*)&hid[wr*32 + i*16 + (lane & 15)][t*32 + kf];
        #pragma unroll
        for (int j = 0; j < 2; ++j) wf[j] = *(const bf16x8*)&Ws[cur][wc*32 + j*16 + (lane & 15)][kf];
        #pragma unroll
        for (int i = 0; i < 2; ++i)
            #pragma unroll
            for (int j = 0; j < 2; ++j)
                acc[i][j] = __builtin_amdgcn_mfma_f32_16x16x32_bf16(af[i], wf[j], acc[i][j], 0, 0, 0);
        if (nx) *(bf16x8*)&Ws[cur^1][rw][ch*8] = lw;
        __syncthreads();
    }
    #pragma unroll
    for (int i = 0; i < 2; ++i)
        #pragma unroll
        for (int j = 0; j < 2; ++j)
            #pragma unroll
            for (int rg = 0; rg < 4; ++rg) {
                int mr = m0 + wr*32 + i*16 + (lane >> 4)*4 + rg;
                int col = n0 + wc*32 + j*16 + (lane & 15);
                kpe[(size_t)mr*C_ + col] = f2bf(acc[i][j][rg] + pb2[col]);
            }
}

// ---------------- bf16 MFMA GEMM body (64x64, dbuf, 1 barrier/K-step) ----------------
template<int ACT, bool RES, int OMODE>
__device__ __forceinline__ void gemm_body(const unsigned short* __restrict__ A, int sA,
                                          const unsigned short* __restrict__ W, int sW,
                                          const float* __restrict__ bias, int bcol0,
                                          const float* __restrict__ res,
                                          float* __restrict__ outF,
                                          unsigned short* __restrict__ outB,
                                          int sO, int on0, int m0, int K) {
    __shared__ unsigned short As[2][64][40];
    __shared__ unsigned short Ws[2][64][40];
    int tid = threadIdx.x;
    int wave = tid >> 6, lane = tid & 63;
    int wr = wave >> 1, wc = wave & 1;
    f32x4 acc[2][2];
    #pragma unroll
    for (int i = 0; i < 2; ++i)
        #pragma unroll
        for (int j = 0; j < 2; ++j) acc[i][j] = (f32x4){0.f, 0.f, 0.f, 0.f};

    int r = tid >> 2, ch = tid & 3;
    const unsigned short* pA = A + (size_t)(m0 + r)*sA + ch*8;
    const unsigned short* pW = W + (size_t)r*sW + ch*8;
    *(bf16x8*)&As[0][r][ch*8] = *(const bf16x8*)pA;
    *(bf16x8*)&Ws[0][r][ch*8] = *(const bf16x8*)pW;
    __syncthreads();
    int nk = K >> 5;
    for (int t = 0; t < nk; ++t) {
        int cur = t & 1;
        bool has_next = (t + 1 < nk);
        bf16x8 la, lw;
        if (has_next) {
            la = *(const bf16x8*)(pA + (t+1)*32);
            lw = *(const bf16x8*)(pW + (t+1)*32);
        }
        int kf = (lane >> 4) * 8;
        bf16x8 af[2], wf[2];
        #pragma unroll
        for (int i = 0; i < 2; ++i) af[i] = *(const bf16x8*)&As[cur][wr*32 + i*16 + (lane & 15)][kf];
        #pragma unroll
        for (int j = 0; j < 2; ++j) wf[j] = *(const bf16x8*)&Ws[cur][wc*32 + j*16 + (lane & 15)][kf];
        #pragma unroll
        for (int i = 0; i < 2; ++i)
            #pragma unroll
            for (int j = 0; j < 2; ++j)
                acc[i][j] = __builtin_amdgcn_mfma_f32_16x16x32_bf16(af[i], wf[j], acc[i][j], 0, 0, 0);
        if (has_next) {
            *(bf16x8*)&As[cur^1][r][ch*8] = la;
            *(bf16x8*)&Ws[cur^1][r][ch*8] = lw;
        }
        __syncthreads();
    }
    #pragma unroll
    for (int i = 0; i < 2; ++i) {
        #pragma unroll
        for (int j = 0; j < 2; ++j) {
            #pragma unroll
            for (int rg = 0; rg < 4; ++rg) {
                int m = m0 + wr*32 + i*16 + (lane >> 4)*4 + rg;
                int pl = wc*32 + j*16 + (lane & 15);
                float v = acc[i][j][rg];
                if (bias) v += bias[bcol0 + pl];
                if (ACT == 1) v = fmaxf(v, 0.f);
                if (RES) v += res[(size_t)m*sO + on0 + pl];
                if (OMODE != 2) outF[(size_t)m*sO + on0 + pl] = v;
                if (OMODE != 0) outB[(size_t)m*sO + on0 + pl] = f2bf(v);
            }
        }
    }
}

template<int ACT, bool RES, int OMODE>
__global__ __launch_bounds__(256) void gemm_k(const unsigned short* __restrict__ A,
                                              const unsigned short* __restrict__ W,
                                              const float* __restrict__ bias,
                                              const float* __restrict__ res,
                                              float* __restrict__ outF,
                                              unsigned short* __restrict__ outB,
                                              int P, int K) {
    int n0 = blockIdx.x * 64, m0 = blockIdx.y * 64;
    gemm_body<ACT,RES,OMODE>(A, K, W + (size_t)n0*K, K, bias, n0, res, outF, outB, P, n0, m0, K);
}

// fused q + kv GEMM: blockIdx.x 0..3 -> q (A=t2), 4..11 -> k,v (A=out)
__global__ __launch_bounds__(256) void qkv_kernel(const unsigned short* __restrict__ t2,
                                                  const unsigned short* __restrict__ outb,
                                                  const unsigned short* __restrict__ Wqkv_l,
                                                  const float* __restrict__ bqkv_l,
                                                  unsigned short* __restrict__ b_q,
                                                  unsigned short* __restrict__ b_kv) {
    int bx = blockIdx.x;
    int n0 = bx * 64;
    int m0 = blockIdx.y * 64;
    if (bx < 4) {
        gemm_body<0,false,2>(t2, C_, Wqkv_l + (size_t)n0*C_, C_, bqkv_l, n0,
                             nullptr, nullptr, b_q, 256, n0, m0, C_);
    } else {
        gemm_body<0,false,2>(outb, C_, Wqkv_l + (size_t)n0*C_, C_, bqkv_l, n0,
                             nullptr, nullptr, b_kv, 512, n0 - 256, m0, C_);
    }
}

// ---------------- GEMM (BM=16, full P=256) + LN epilogue ----------------
// x = A@W^T + bias + res; y1 = LN1(x)
// VAR 0 (Wo):   outF = x,  outT2 = bf16(y1)                      [ln_ffn]
// VAR 1 (FFN2): outF = y1, outB = bf16(y1), outT2 = bf16(LN2(y1)+qpe)
// VAR 2 (last): outF = y1
template<int VAR>
__global__ __launch_bounds__(256) void gemm_ln(const unsigned short* __restrict__ A,
                                               const unsigned short* __restrict__ W,
                                               const float* __restrict__ bias,
                                               const float* __restrict__ res,
                                               const float* __restrict__ lnw1, const float* __restrict__ lnb1,
                                               const float* __restrict__ lnw2, const float* __restrict__ lnb2,
                                               const float* __restrict__ qpe,
                                               float* __restrict__ outF,
                                               unsigned short* __restrict__ outB,
                                               unsigned short* __restrict__ outT2,
                                               int K) {
    __shared__ unsigned short Ws[2][256][40];
    __shared__ unsigned short As[2][16][40];
    int tid = threadIdx.x;
    int wave = tid >> 6, lane = tid & 63;
    int m0 = blockIdx.x * 16;
    f32x4 acc[4];
    #pragma unroll
    for (int j = 0; j < 4; ++j) acc[j] = (f32x4){0.f,0.f,0.f,0.f};
    int rw = tid >> 2, ch = tid & 3;
    const unsigned short* pW = W + (size_t)rw*K + ch*8;
    const unsigned short* pA = A + (size_t)(m0 + ((tid & 63) >> 2))*K + (tid & 3)*8;
    #pragma unroll
    for (int c = 0; c < 4; ++c)
        *(bf16x8*)&Ws[0][c*64 + rw][ch*8] = *(const bf16x8*)(pW + (size_t)c*64*K);
    if (tid < 64) *(bf16x8*)&As[0][tid >> 2][(tid & 3)*8] = *(const bf16x8*)pA;
    __syncthreads();
    int nk = K >> 5;
    for (int t = 0; t < nk; ++t) {
        int cur = t & 1;
        bool nx = (t + 1 < nk);
        bf16x8 lw0, lw1, lw2, lw3, la;
        if (nx) {
            lw0 = *(const bf16x8*)(pW + (size_t)0*64*K + (t+1)*32);
            lw1 = *(const bf16x8*)(pW + (size_t)1*64*K + (t+1)*32);
            lw2 = *(const bf16x8*)(pW + (size_t)2*64*K + (t+1)*32);
            lw3 = *(const bf16x8*)(pW + (size_t)3*64*K + (t+1)*32);
            if (tid < 64) la = *(const bf16x8*)(pA + (t+1)*32);
        }
        int kf = (lane >> 4) * 8;
        bf16x8 af = *(const bf16x8*)&As[cur][lane & 15][kf];
        #pragma unroll
        for (int j = 0; j < 4; ++j) {
            bf16x8 wf = *(const bf16x8*)&Ws[cur][wave*64 + j*16 + (lane & 15)][kf];
            acc[j] = __builtin_amdgcn_mfma_f32_16x16x32_bf16(af, wf, acc[j], 0, 0, 0);
        }
        if (nx) {
            *(bf16x8*)&Ws[cur^1][0*64 + rw][ch*8] = lw0;
            *(bf16x8*)&Ws[cur^1][1*64 + rw][ch*8] = lw1;
            *(bf16x8*)&Ws[cur^1][2*64 + rw][ch*8] = lw2;
            *(bf16x8*)&Ws[cur^1][3*64 + rw][ch*8] = lw3;
            if (tid < 64) *(bf16x8*)&As[cur^1][tid >> 2][(tid & 3)*8] = la;
        }
        __syncthreads();
    }
    // epilogue: x = acc + bias + res -> S (overlay on Ws; all Ws reads are behind the barrier)
    float* S = (float*)&Ws[0][0][0];   // [16][260]
    #pragma unroll
    for (int j = 0; j < 4; ++j) {
        int col = wave*64 + j*16 + (lane & 15);
        #pragma unroll
        for (int rg = 0; rg < 4; ++rg) {
            int row = (lane >> 4)*4 + rg;
            S[row*260 + col] = acc[j][rg] + bias[col] + res[(size_t)(m0+row)*C_ + col];
        }
    }
    __syncthreads();
    int row = tid >> 4, g = tid & 15;
    size_t m = m0 + row;
    float x[16];
    #pragma unroll
    for (int u = 0; u < 4; ++u) {
        f32x4 v4 = *(const f32x4*)&S[row*260 + g*16 + u*4];
        x[u*4+0] = v4[0]; x[u*4+1] = v4[1]; x[u*4+2] = v4[2]; x[u*4+3] = v4[3];
    }
    float s1 = 0.f, s2 = 0.f;
    #pragma unroll
    for (int u = 0; u < 16; ++u) { s1 += x[u]; s2 += x[u]*x[u]; }
    #pragma unroll
    for (int off = 8; off; off >>= 1) { s1 += __shfl_xor(s1, off, 16); s2 += __shfl_xor(s2, off, 16); }
    float mean = s1 * (1.f/C_);
    float var  = s2 * (1.f/C_) - mean*mean;
    float rstd = rsqrtf(var + 1e-5f);
    float y1[16];
    #pragma unroll
    for (int u = 0; u < 4; ++u) {
        f32x4 w4 = *(const f32x4*)&lnw1[g*16 + u*4];
        f32x4 b4 = *(const f32x4*)&lnb1[g*16 + u*4];
        #pragma unroll
        for (int v = 0; v < 4; ++v)
            y1[u*4+v] = (x[u*4+v] - mean)*rstd*w4[v] + b4[v];
    }
    if (VAR == 0) {
        #pragma unroll
        for (int u = 0; u < 4; ++u) {
            f32x4 v4 = { x[u*4], x[u*4+1], x[u*4+2], x[u*4+3] };
            *(f32x4*)&outF[m*C_ + g*16 + u*4] = v4;
        }
        unsigned pk[8];
        #pragma unroll
        for (int u = 0; u < 8; ++u) pk[u] = (unsigned)f2bf(y1[2*u]) | ((unsigned)f2bf(y1[2*u+1]) << 16);
        *(u32x4*)&outT2[m*C_ + g*16]     = *(u32x4*)&pk[0];
        *(u32x4*)&outT2[m*C_ + g*16 + 8] = *(u32x4*)&pk[4];
    } else {
        #pragma unroll
        for (int u = 0; u < 4; ++u) {
            f32x4 v4 = { y1[u*4], y1[u*4+1], y1[u*4+2], y1[u*4+3] };
            *(f32x4*)&outF[m*C_ + g*16 + u*4] = v4;
        }
        if (VAR == 1) {
            unsigned pk[8];
            #pragma unroll
            for (int u = 0; u < 8; ++u) pk[u] = (unsigned)f2bf(y1[2*u]) | ((unsigned)f2bf(y1[2*u+1]) << 16);
            *(u32x4*)&outB[m*C_ + g*16]     = *(u32x4*)&pk[0];
            *(u32x4*)&outB[m*C_ + g*16 + 8] = *(u32x4*)&pk[4];
            float t1 = 0.f, t2s = 0.f;
            #pragma unroll
            for (int u = 0; u < 16; ++u) { t1 += y1[u]; t2s += y1[u]*y1[u]; }
            #pragma unroll
            for (int off = 8; off; off >>= 1) { t1 += __shfl_xor(t1, off, 16); t2s += __shfl_xor(t2s, off, 16); }
            float mean2 = t1 * (1.f/C_);
            float var2  = t2s * (1.f/C_) - mean2*mean2;
            float rstd2 = rsqrtf(var2 + 1e-5f);
            unsigned pk2[8];
            #pragma unroll
            for (int u = 0; u < 4; ++u) {
                f32x4 w4 = *(const f32x4*)&lnw2[g*16 + u*4];
                f32x4 b4 = *(const f32x4*)&lnb2[g*16 + u*4];
                f32x4 q4 = *(const f32x4*)&qpe[g*16 + u*4];
                float z0 = (y1[u*4+0]-mean2)*rstd2*w4[0] + b4[0] + q4[0];
                float z1 = (y1[u*4+1]-mean2)*rstd2*w4[1] + b4[1] + q4[1];
                float z2 = (y1[u*4+2]-mean2)*rstd2*w4[2] + b4[2] + q4[2];
                float z3 = (y1[u*4+3]-mean2)*rstd2*w4[3] + b4[3] + q4[3];
                pk2[u*2]   = (unsigned)f2bf(z0) | ((unsigned)f2bf(z1) << 16);
                pk2[u*2+1] = (unsigned)f2bf(z2) | ((unsigned)f2bf(z3) << 16);
            }
            *(u32x4*)&outT2[m*C_ + g*16]     = *(u32x4*)&pk2[0];
            *(u32x4*)&outT2[m*C_ + g*16 + 8] = *(u32x4*)&pk2[4];
        }
    }
}

// ---------------- r via MFMA: per-head GEMM r_h[BN x 256] = q_h[BN x 32] @ Wk_h^T ----------------
__global__ __launch_bounds__(256) void rk_kernel(const unsigned short* __restrict__ q,
                                                 const unsigned short* __restrict__ Wqkv_l,
                                                 unsigned short* __restrict__ r) {
    int n0 = blockIdx.x * 64, m0 = blockIdx.y * 64, h = blockIdx.z;
    __shared__ unsigned short As[64][40];
    __shared__ unsigned short Ws[64][40];
    int tid = threadIdx.x;
    int wave = tid >> 6, lane = tid & 63;
    int wr = wave >> 1, wc = wave & 1;
    *(bf16x8*)&As[tid>>2][(tid&3)*8] =
        *(const bf16x8*)&q[(size_t)(m0 + (tid>>2))*C_ + h*DH_ + (tid&3)*8];
    {
        int d = tid >> 3, cg = tid & 7;
        bf16x8 wv = *(const bf16x8*)&Wqkv_l[(size_t)(C_ + h*DH_ + d)*C_ + n0 + cg*8];
        #pragma unroll
        for (int j = 0; j < 8; ++j) Ws[cg*8 + j][d] = (unsigned short)wv[j];
    }
    __syncthreads();
    int kf = (lane >> 4) * 8;
    bf16x8 af[2], wf[2];
    #pragma unroll
    for (int i = 0; i < 2; ++i) af[i] = *(const bf16x8*)&As[wr*32 + i*16 + (lane & 15)][kf];
    #pragma unroll
    for (int j = 0; j < 2; ++j) wf[j] = *(const bf16x8*)&Ws[wc*32 + j*16 + (lane & 15)][kf];
    f32x4 acc[2][2];
    #pragma unroll
    for (int i = 0; i < 2; ++i)
        #pragma unroll
        for (int j = 0; j < 2; ++j)
            acc[i][j] = __builtin_amdgcn_mfma_f32_16x16x32_bf16(af[i], wf[j],
                          (f32x4){0.f,0.f,0.f,0.f}, 0, 0, 0);
    #pragma unroll
    for (int i = 0; i < 2; ++i)
        #pragma unroll
        for (int j = 0; j < 2; ++j)
            #pragma unroll
            for (int rg = 0; rg < 4; ++rg) {
                int m = m0 + wr*32 + i*16 + (lane >> 4)*4 + rg;
                int pl = wc*32 + j*16 + (lane & 15);
                r[(size_t)m*(NH_*C_) + h*C_ + n0 + pl] = f2bf(acc[i][j][rg]);
            }
}

// ---------------- attention: one WAVE per point, MFMA scores ----------------
__global__ __launch_bounds__(256) void attn_kernel(const unsigned short* __restrict__ q,
                                                   const unsigned short* __restrict__ kv,
                                                   const unsigned short* __restrict__ kpe,
                                                   const unsigned short* __restrict__ r,
                                                   const int* __restrict__ idx,
                                                   unsigned short* __restrict__ ao) {
    int wid = threadIdx.x >> 6, lane = threadIdx.x & 63;
    int point = blockIdx.x*4 + wid;
    __shared__ __align__(16) unsigned short vs[4][K_][264];
    __shared__ __align__(16) float atts[4][NH_][K_];
    int row = lane & 15;
    int off8 = (lane >> 4) * 8;
    int idx_l = idx[point*K_ + row];

    #pragma unroll
    for (int t = 0; t < 8; ++t) {
        int vr = 2*t + (lane >> 5);
        int j = __shfl(idx_l, vr, 64);
        int cc = (lane & 31) * 8;
        *(bf16x8*)&vs[wid][vr][cc] = *(const bf16x8*)&kv[(size_t)j*512 + 256 + cc];
    }

    f32x4 acc = {0.f, 0.f, 0.f, 0.f};
    const bf16x8 zero8 = {0,0,0,0,0,0,0,0};
    #pragma unroll
    for (int s = 0; s < 8; ++s) {
        bf16x8 a = *(const bf16x8*)&kpe[((size_t)point*K_ + row)*C_ + s*32 + off8];
        bf16x8 b = zero8;
        if (row < 8) b = *(const bf16x8*)&r[(size_t)point*NH_*C_ + row*C_ + s*32 + off8];
        acc = __builtin_amdgcn_mfma_f32_16x16x32_bf16(a, b, acc, 0, 0, 0);
    }
    #pragma unroll
    for (int s = 0; s < 8; ++s) {
        bf16x8 a = *(const bf16x8*)&kv[(size_t)idx_l*512 + s*32 + off8];
        bf16x8 b = zero8;
        if (row == 8 + s) b = *(const bf16x8*)&q[(size_t)point*C_ + s*32 + off8];
        acc = __builtin_amdgcn_mfma_f32_16x16x32_bf16(a, b, acc, 0, 0, 0);
    }

    const float scale = 0.1767766952966369f;
    float sv[4], m = -1e30f;
    #pragma unroll
    for (int rg = 0; rg < 4; ++rg) {
        float o = __shfl_xor(acc[rg], 8, 64);
        sv[rg] = (acc[rg] + o) * scale;
        m = fmaxf(m, sv[rg]);
    }
    m = fmaxf(m, __shfl_xor(m, 16, 64));
    m = fmaxf(m, __shfl_xor(m, 32, 64));
    float sum = 0.f;
    #pragma unroll
    for (int rg = 0; rg < 4; ++rg) { sv[rg] = __expf(sv[rg] - m); sum += sv[rg]; }
    sum += __shfl_xor(sum, 16, 64);
    sum += __shfl_xor(sum, 32, 64);
    float inv = 1.f / sum;
    if (row < 8) {
        f32x4 av = { sv[0]*inv, sv[1]*inv, sv[2]*inv, sv[3]*inv };
        *(f32x4*)&atts[wid][row][(lane >> 4) * 4] = av;
    }

    int h = lane >> 3;
    float att_f[16];
    #pragma unroll
    for (int u = 0; u < 4; ++u) {
        f32x4 t4 = *(const f32x4*)&atts[wid][h][u*4];
        att_f[u*4+0] = t4[0]; att_f[u*4+1] = t4[1]; att_f[u*4+2] = t4[2]; att_f[u*4+3] = t4[3];
    }
    int cbase = lane * 4;
    float o0 = 0.f, o1 = 0.f, o2 = 0.f, o3 = 0.f;
    #pragma unroll
    for (int k = 0; k < K_; ++k) {
        unsigned long long vv = *(const unsigned long long*)&vs[wid][k][cbase];
        unsigned lo = (unsigned)vv, hi = (unsigned)(vv >> 32);
        float a = att_f[k];
        o0 += a * __uint_as_float(lo << 16);
        o1 += a * __uint_as_float(lo & 0xffff0000u);
        o2 += a * __uint_as_float(hi << 16);
        o3 += a * __uint_as_float(hi & 0xffff0000u);
    }
    unsigned p0 = (unsigned)f2bf(o0) | ((unsigned)f2bf(o1) << 16);
    unsigned p1 = (unsigned)f2bf(o2) | ((unsigned)f2bf(o3) << 16);
    unsigned out2[2] = { p0, p1 };
    *(unsigned long long*)&ao[(size_t)point*C_ + cbase] = *(const unsigned long long*)out2;
}

extern "C" void kernel_launch(void* const* d_in, const int* in_sizes, int n_in,
                              void* d_out, int out_size, void* d_ws, size_t ws_size,
                              hipStream_t stream) {
    const float* feature  = (const float*)d_in[0];
    const float* xyz      = (const float*)d_in[1];
    const float* pe_W1    = (const float*)d_in[2];
    const float* pe_b1    = (const float*)d_in[3];
    const float* pe_W2    = (const float*)d_in[4];
    const float* pe_b2    = (const float*)d_in[5];
    const float* Wqkv     = (const float*)d_in[6];
    const float* bqkv     = (const float*)d_in[7];
    const float* Wo       = (const float*)d_in[8];
    const float* bo       = (const float*)d_in[9];
    const float* ln_attn_w= (const float*)d_in[10];
    const float* ln_attn_b= (const float*)d_in[11];
    const float* W1       = (const float*)d_in[12];
    const float* b1       = (const float*)d_in[13];
    const float* W2       = (const float*)d_in[14];
    const float* b2       = (const float*)d_in[15];
    const float* ln_ffn_w = (const float*)d_in[16];
    const float* ln_ffn_b = (const float*)d_in[17];
    const float* ln_out_w = (const float*)d_in[18];
    const float* ln_out_b = (const float*)d_in[19];

    // ---- workspace layout ----
    float* ws = (float*)d_ws;
    float* w_out = ws;                                   // BN*C fp32
    float* w_qpe = w_out + (size_t)BN_*C_;               // C fp32
    unsigned short* bptr = (unsigned short*)(w_qpe + C_ + 64);
    unsigned short* b_out = bptr;  bptr += (size_t)BN_*C_;
    unsigned short* b_t2  = bptr;  bptr += (size_t)BN_*C_;
    unsigned short* b_q   = bptr;  bptr += (size_t)BN_*C_;
    unsigned short* b_kv  = bptr;  bptr += (size_t)BN_*512;
    unsigned short* b_ao  = bptr;  bptr += (size_t)BN_*C_;
    unsigned short* b_ffh = bptr;  bptr += (size_t)BN_*FF_;
    unsigned short* w_kpe = bptr;  bptr += (size_t)BN_*K_*C_;
    unsigned short* w_r   = bptr;  bptr += (size_t)BN_*NH_*C_;
    unsigned short* bWpe  = bptr;  bptr += (size_t)C_*C_;        // contiguous weight block
    unsigned short* bWqkv = bptr;  bptr += (size_t)L_*3*C_*C_;
    unsigned short* bWo   = bptr;  bptr += (size_t)L_*C_*C_;
    unsigned short* bW1   = bptr;  bptr += (size_t)L_*FF_*C_;
    unsigned short* bW2   = bptr;  bptr += (size_t)L_*C_*FF_;
    int* w_idx = (int*)bptr;

    // ---- preprocessing ----
    f2bf5_kernel<<<(4784128 + 255)/256, 256, 0, stream>>>(pe_W2, Wqkv, Wo, W1, W2, bWpe);
    knn_kernel<<<BN_/4, 256, 0, stream>>>(xyz, w_idx);
    qpe_kernel<<<1, 256, 0, stream>>>(pe_b1, pe_W2, pe_b2, w_qpe);
    reshape_in_ln<<<BN_, 256, 0, stream>>>(feature, ln_attn_w, ln_attn_b, w_qpe,
                                           w_out, b_out, b_t2);
    kpe_kernel<<<dim3(C_/64, (BN_*K_)/64), 256, 0, stream>>>(xyz, w_idx, pe_W1, pe_b1,
                                                             bWpe, pe_b2, w_kpe);

    // ---- layers ----
    for (int i = 0; i < L_; ++i) {
        const unsigned short* Wqkv_l = bWqkv + (size_t)i*3*C_*C_;
        const float* bqkv_l = bqkv + (size_t)i*3*C_;

        qkv_kernel<<<dim3(12, BN_/64), 256, 0, stream>>>(b_t2, b_out, Wqkv_l, bqkv_l, b_q, b_kv);
        rk_kernel<<<dim3(4, BN_/64, NH_), 256, 0, stream>>>(b_q, Wqkv_l, w_r);
        attn_kernel<<<BN_/4, 256, 0, stream>>>(b_q, b_kv, w_kpe, w_r, w_idx, b_ao);
        gemm_ln<0><<<BN_/16, 256, 0, stream>>>(
            b_ao, bWo + (size_t)i*C_*C_, bo + i*C_, w_out,
            ln_ffn_w + i*C_, ln_ffn_b + i*C_, nullptr, nullptr, nullptr,
            w_out, nullptr, b_t2, C_);
        gemm_k<1,false,2><<<dim3(FF_/64, BN_/64), 256, 0, stream>>>(
            b_t2, bW1 + (size_t)i*FF_*C_, b1 + i*FF_, nullptr, nullptr, b_ffh, FF_, C_);
        if (i < L_-1) {
            gemm_ln<1><<<BN_/16, 256, 0, stream>>>(
                b_ffh, bW2 + (size_t)i*C_*FF_, b2 + i*C_, w_out,
                ln_out_w + i*C_, ln_out_b + i*C_,
                ln_attn_w + (i+1)*C_, ln_attn_b + (i+1)*C_, w_qpe,
                w_out, b_out, b_t2, FF_);
        } else {
            gemm_ln<2><<<BN_/16, 256, 0, stream>>>(
                b_ffh, bW2 + (size_t)i*C_*FF_, b2 + i*C_, w_out,
                ln_out_w + i*C_, ln_out_b + i*C_, nullptr, nullptr, nullptr,
                w_out, nullptr, nullptr, FF_);
        }
    }

    reshape_out_kernel<<<BN_, 256, 0, stream>>>(w_out, (float*)d_out);
}

// Round 8
// 666.742 us; speedup vs baseline: 4.8205x; 1.0237x over previous
//
#include <hip/hip_runtime.h>
#include <math.h>

#define BS_ 2
#define V_ 4
#define H_ 24
#define W_ 24
#define N_ (V_*H_*W_)        // 2304
#define BN_ (BS_*N_)         // 4608
#define C_ 256
#define K_ 16
#define L_ 6
#define NH_ 8
#define DH_ 32
#define FF_ 1024

typedef __attribute__((ext_vector_type(4))) float f32x4;
typedef __attribute__((ext_vector_type(8))) short bf16x8;
typedef __attribute__((ext_vector_type(4))) unsigned u32x4;

__device__ inline unsigned short f2bf(float x) {
    unsigned u = __float_as_uint(x);
    unsigned r = u + 0x7fffu + ((u >> 16) & 1u);
    return (unsigned short)(r >> 16);
}
__device__ inline float bf2f(unsigned short h) {
    return __uint_as_float(((unsigned)h) << 16);
}

// ---------------- fp32 -> bf16 elementwise (row-major copy for rk) ----------------
__global__ __launch_bounds__(256) void f2bf_kernel(const float* __restrict__ in,
                                                   unsigned short* __restrict__ out, int n) {
    int i = blockIdx.x*256 + threadIdx.x;
    if (i < n) out[i] = f2bf(in[i]);
}

// ---------------- weight -> MFMA B-fragment tiles ----------------
// W[P][K] fp32 -> F: tile (tn=n/16, tk=k/32), F[tile*512 + lane*8 + j] =
//   bf16(W[tn*16 + (lane&15)][tk*32 + (lane>>4)*8 + j])
__global__ __launch_bounds__(256) void w2frag_kernel(const float* __restrict__ W,
                                                     unsigned short* __restrict__ F,
                                                     int P, int K) {
    int wid = threadIdx.x >> 6, lane = threadIdx.x & 63;
    int tile = blockIdx.x*4 + wid;
    int nkt = K >> 5;
    int tn = tile / nkt, tk = tile - tn*nkt;
    const float* src = W + (size_t)(tn*16 + (lane & 15))*K + tk*32 + (lane >> 4)*8;
    unsigned short tmp[8];
    #pragma unroll
    for (int j = 0; j < 8; ++j) tmp[j] = f2bf(src[j]);
    *(bf16x8*)&F[(size_t)tile*512 + lane*8] = *(bf16x8*)tmp;
}

// ---------------- reshape in + ln_attn(layer0) + qpe ----------------
__global__ __launch_bounds__(256) void reshape_in_ln(const float* __restrict__ f,
                                                     const float* __restrict__ lnw,
                                                     const float* __restrict__ lnb,
                                                     const float* __restrict__ qpe,
                                                     float* __restrict__ w_out,
                                                     unsigned short* __restrict__ b_out,
                                                     unsigned short* __restrict__ b_t2) {
    int bn = blockIdx.x, c = threadIdx.x;
    int b = bn / N_, rem = bn % N_;
    int v = rem / (H_*W_), hw = rem % (H_*W_);
    float x = f[(((size_t)(b*V_ + v)*C_ + c)*(H_*W_)) + hw];
    w_out[(size_t)bn*C_ + c] = x;
    b_out[(size_t)bn*C_ + c] = f2bf(x);
    __shared__ float red[4];
    float s = x;
    #pragma unroll
    for (int off = 32; off; off >>= 1) s += __shfl_xor(s, off, 64);
    if ((c & 63) == 0) red[c >> 6] = s;
    __syncthreads();
    float mean = (red[0]+red[1]+red[2]+red[3]) * (1.f/C_);
    __syncthreads();
    float dx = x - mean;
    s = dx*dx;
    #pragma unroll
    for (int off = 32; off; off >>= 1) s += __shfl_xor(s, off, 64);
    if ((c & 63) == 0) red[c >> 6] = s;
    __syncthreads();
    float var = (red[0]+red[1]+red[2]+red[3]) * (1.f/C_);
    float y = dx * rsqrtf(var + 1e-5f) * lnw[c] + lnb[c] + qpe[c];
    b_t2[(size_t)bn*C_ + c] = f2bf(y);
}

// ---------------- reshape out: (BN, C) -> (B*V,C,H,W) ----------------
__global__ __launch_bounds__(256) void reshape_out_kernel(const float* __restrict__ in,
                                                          float* __restrict__ o) {
    int bn = blockIdx.x, c = threadIdx.x;
    int b = bn / N_, rem = bn % N_;
    int v = rem / (H_*W_), hw = rem % (H_*W_);
    o[(((size_t)(b*V_ + v)*C_ + c)*(H_*W_)) + hw] = in[(size_t)bn*C_ + c];
}

// ---------------- KNN: one WAVE per query point, 4 points/block ----------------
__global__ __launch_bounds__(256) void knn_kernel(const float* __restrict__ pts,
                                                  int* __restrict__ idx) {
    int wid = threadIdx.x >> 6, lane = threadIdx.x & 63;
    int point = blockIdx.x*4 + wid;
    int b = point / N_;
    int il = point % N_;
    __shared__ float ps[N_*3];
    for (int l = threadIdx.x; l < N_*3; l += 256) ps[l] = pts[(size_t)b*N_*3 + l];
    __syncthreads();
    float qx = ps[il*3], qy = ps[il*3+1], qz = ps[il*3+2];
    unsigned long long key[36];
    #pragma unroll
    for (int s = 0; s < 36; ++s) {
        int j = lane + 64*s;
        float dx = qx - ps[j*3], dy = qy - ps[j*3+1], dz = qz - ps[j*3+2];
        float d2 = dx*dx + dy*dy + dz*dz;
        key[s] = ((unsigned long long)__float_as_uint(d2) << 32) | (unsigned)j;
    }
    for (int it = 0; it < K_; ++it) {
        unsigned long long b0 = key[0], b1 = key[1], b2 = key[2], b3 = key[3];
        #pragma unroll
        for (int s = 4; s < 36; s += 4) {
            b0 = key[s]   < b0 ? key[s]   : b0;
            b1 = key[s+1] < b1 ? key[s+1] : b1;
            b2 = key[s+2] < b2 ? key[s+2] : b2;
            b3 = key[s+3] < b3 ? key[s+3] : b3;
        }
        unsigned long long m01 = b0 < b1 ? b0 : b1;
        unsigned long long m23 = b2 < b3 ? b2 : b3;
        unsigned long long best = m01 < m23 ? m01 : m23;
        #pragma unroll
        for (int off = 32; off; off >>= 1) {
            unsigned long long o = __shfl_xor(best, off, 64);
            if (o < best) best = o;
        }
        int wj = (int)(best & 0xffffffffu);
        if (lane == 0) idx[point*K_ + it] = b*N_ + wj;
        if ((wj & 63) == lane) {
            int sw = wj >> 6;
            #pragma unroll
            for (int s = 0; s < 36; ++s) if (s == sw) key[s] = ~0ull;
        }
    }
}

// ---------------- q_pe = relu(b1)@W2^T + b2 (fp32, tiny) ----------------
__global__ __launch_bounds__(256) void qpe_kernel(const float* __restrict__ b1,
                                                  const float* __restrict__ W2,
                                                  const float* __restrict__ b2,
                                                  float* __restrict__ qpe) {
    __shared__ float h[C_];
    int tid = threadIdx.x;
    h[tid] = fmaxf(b1[tid], 0.f);
    __syncthreads();
    float acc = 0.f;
    for (int j = 0; j < C_; ++j) acc += h[j] * W2[(size_t)tid*C_ + j];
    qpe[tid] = acc + b2[tid];
}

// ---------------- PE hidden (bf16): one block per point, 16 rows each ----------------
__global__ __launch_bounds__(256) void pe_hidden_kernel(const float* __restrict__ pts,
                                                        const int* __restrict__ idx,
                                                        const float* __restrict__ W1,
                                                        const float* __restrict__ b1,
                                                        unsigned short* __restrict__ hidden) {
    int point = blockIdx.x;
    int c = threadIdx.x;
    __shared__ float rel[K_][3];
    if (threadIdx.x < K_*3) {
        int k = threadIdx.x / 3, ax = threadIdx.x % 3;
        int j = idx[point*K_ + k];
        rel[k][ax] = pts[(size_t)j*3 + ax] - pts[(size_t)point*3 + ax];
    }
    __syncthreads();
    float w0 = W1[c*3], w1 = W1[c*3+1], w2 = W1[c*3+2], bb = b1[c];
    #pragma unroll
    for (int k = 0; k < K_; ++k) {
        float v = rel[k][0]*w0 + rel[k][1]*w1 + rel[k][2]*w2 + bb;
        hidden[((size_t)point*K_ + k)*C_ + c] = f2bf(fmaxf(v, 0.f));
    }
}

// ---------------- GEMM body (64x64): A dbuf-LDS, B direct-from-global frag tiles ----------------
// Wf pre-offset to the block's first n-tile; nkt = K/32 tiles per n-tile row.
template<int ACT, bool RES, int OMODE>
__device__ __forceinline__ void gemm_body2(const unsigned short* __restrict__ A, int sA,
                                           const unsigned short* __restrict__ Wf,
                                           const float* __restrict__ bias, int bcol0,
                                           const float* __restrict__ res,
                                           float* __restrict__ outF,
                                           unsigned short* __restrict__ outB,
                                           int sO, int on0, int m0, int K) {
    __shared__ unsigned short As[2][64][40];
    int tid = threadIdx.x;
    int wave = tid >> 6, lane = tid & 63;
    int wr = wave >> 1, wc = wave & 1;
    int nkt = K >> 5;
    f32x4 acc[2][2];
    #pragma unroll
    for (int i = 0; i < 2; ++i)
        #pragma unroll
        for (int j = 0; j < 2; ++j) acc[i][j] = (f32x4){0.f, 0.f, 0.f, 0.f};

    int r = tid >> 2, ch = tid & 3;
    const unsigned short* pA = A + (size_t)(m0 + r)*sA + ch*8;
    const unsigned short* bb = Wf + (size_t)(wc*2)*nkt*512 + lane*8;
    *(bf16x8*)&As[0][r][ch*8] = *(const bf16x8*)pA;
    bf16x8 bw0 = *(const bf16x8*)bb;
    bf16x8 bw1 = *(const bf16x8*)(bb + (size_t)nkt*512);
    __syncthreads();
    for (int t = 0; t < nkt; ++t) {
        int cur = t & 1;
        bool nx = (t + 1 < nkt);
        bf16x8 la, nb0, nb1;
        if (nx) {
            la  = *(const bf16x8*)(pA + (t+1)*32);
            nb0 = *(const bf16x8*)(bb + (size_t)(t+1)*512);
            nb1 = *(const bf16x8*)(bb + (size_t)nkt*512 + (size_t)(t+1)*512);
        }
        int kf = (lane >> 4) * 8;
        bf16x8 af0 = *(const bf16x8*)&As[cur][wr*32 + (lane & 15)][kf];
        bf16x8 af1 = *(const bf16x8*)&As[cur][wr*32 + 16 + (lane & 15)][kf];
        acc[0][0] = __builtin_amdgcn_mfma_f32_16x16x32_bf16(af0, bw0, acc[0][0], 0, 0, 0);
        acc[0][1] = __builtin_amdgcn_mfma_f32_16x16x32_bf16(af0, bw1, acc[0][1], 0, 0, 0);
        acc[1][0] = __builtin_amdgcn_mfma_f32_16x16x32_bf16(af1, bw0, acc[1][0], 0, 0, 0);
        acc[1][1] = __builtin_amdgcn_mfma_f32_16x16x32_bf16(af1, bw1, acc[1][1], 0, 0, 0);
        if (nx) *(bf16x8*)&As[cur^1][r][ch*8] = la;
        bw0 = nb0; bw1 = nb1;
        __syncthreads();
    }
    #pragma unroll
    for (int i = 0; i < 2; ++i) {
        #pragma unroll
        for (int j = 0; j < 2; ++j) {
            #pragma unroll
            for (int rg = 0; rg < 4; ++rg) {
                int m = m0 + wr*32 + i*16 + (lane >> 4)*4 + rg;
                int pl = wc*32 + j*16 + (lane & 15);
                float v = acc[i][j][rg];
                if (bias) v += bias[bcol0 + pl];
                if (ACT == 1) v = fmaxf(v, 0.f);
                if (RES) v += res[(size_t)m*sO + on0 + pl];
                if (OMODE != 2) outF[(size_t)m*sO + on0 + pl] = v;
                if (OMODE != 0) outB[(size_t)m*sO + on0 + pl] = f2bf(v);
            }
        }
    }
}

template<int ACT, bool RES, int OMODE>
__global__ __launch_bounds__(256) void gemm_k2(const unsigned short* __restrict__ A,
                                               const unsigned short* __restrict__ Wf0,
                                               const float* __restrict__ bias,
                                               const float* __restrict__ res,
                                               float* __restrict__ outF,
                                               unsigned short* __restrict__ outB,
                                               int P, int K) {
    int n0 = blockIdx.x * 64, m0 = blockIdx.y * 64;
    const unsigned short* Wf = Wf0 + (size_t)(n0 >> 4)*(K >> 5)*512;
    gemm_body2<ACT,RES,OMODE>(A, K, Wf, bias, n0, res, outF, outB, P, n0, m0, K);
}

// fused q + kv GEMM: blockIdx.x 0..3 -> q (A=t2), 4..11 -> k,v (A=out)
__global__ __launch_bounds__(256) void qkv_kernel2(const unsigned short* __restrict__ t2,
                                                   const unsigned short* __restrict__ outb,
                                                   const unsigned short* __restrict__ Fqkv_l,
                                                   const float* __restrict__ bqkv_l,
                                                   unsigned short* __restrict__ b_q,
                                                   unsigned short* __restrict__ b_kv) {
    int bx = blockIdx.x;
    int m0 = blockIdx.y * 64;
    const unsigned short* Wf = Fqkv_l + (size_t)(bx*4)*8*512;   // nkt=8 for K=256
    if (bx < 4) {
        gemm_body2<0,false,2>(t2, C_, Wf, bqkv_l, bx*64, nullptr, nullptr, b_q, 256, bx*64, m0, C_);
    } else {
        gemm_body2<0,false,2>(outb, C_, Wf, bqkv_l, bx*64, nullptr, nullptr, b_kv, 512, bx*64 - 256, m0, C_);
    }
}

// ---------------- GEMM (BM=16, full P=256, B-from-global) + LN epilogue ----------------
// VAR 0 (Wo):   outF = x,  outT2 = bf16(LN1(x))
// VAR 1 (FFN2): outF = y1, outB = bf16(y1), outT2 = bf16(LN2(y1)+qpe)
// VAR 2 (last): outF = y1
template<int VAR>
__global__ __launch_bounds__(256) void gemm_ln2(const unsigned short* __restrict__ A,
                                                const unsigned short* __restrict__ Wf,
                                                const float* __restrict__ bias,
                                                const float* __restrict__ res,
                                                const float* __restrict__ lnw1, const float* __restrict__ lnb1,
                                                const float* __restrict__ lnw2, const float* __restrict__ lnb2,
                                                const float* __restrict__ qpe,
                                                float* __restrict__ outF,
                                                unsigned short* __restrict__ outB,
                                                unsigned short* __restrict__ outT2,
                                                int K) {
    __shared__ unsigned short As[2][16][40];
    __shared__ float S[16][260];
    int tid = threadIdx.x;
    int wave = tid >> 6, lane = tid & 63;
    int m0 = blockIdx.x * 16;
    int nkt = K >> 5;
    f32x4 acc[4];
    #pragma unroll
    for (int j = 0; j < 4; ++j) acc[j] = (f32x4){0.f,0.f,0.f,0.f};
    const unsigned short* pA = A + (size_t)(m0 + ((tid & 63) >> 2))*K + (tid & 3)*8;
    const unsigned short* bb = Wf + (size_t)(wave*4)*nkt*512 + lane*8;
    if (tid < 64) *(bf16x8*)&As[0][tid >> 2][(tid & 3)*8] = *(const bf16x8*)pA;
    bf16x8 bw[4];
    #pragma unroll
    for (int j = 0; j < 4; ++j) bw[j] = *(const bf16x8*)(bb + (size_t)j*nkt*512);
    __syncthreads();
    for (int t = 0; t < nkt; ++t) {
        int cur = t & 1;
        bool nx = (t + 1 < nkt);
        bf16x8 la, nb0, nb1, nb2, nb3;
        if (nx) {
            nb0 = *(const bf16x8*)(bb + (size_t)0*nkt*512 + (size_t)(t+1)*512);
            nb1 = *(const bf16x8*)(bb + (size_t)1*nkt*512 + (size_t)(t+1)*512);
            nb2 = *(const bf16x8*)(bb + (size_t)2*nkt*512 + (size_t)(t+1)*512);
            nb3 = *(const bf16x8*)(bb + (size_t)3*nkt*512 + (size_t)(t+1)*512);
            if (tid < 64) la = *(const bf16x8*)(pA + (t+1)*32);
        }
        int kf = (lane >> 4) * 8;
        bf16x8 af = *(const bf16x8*)&As[cur][lane & 15][kf];
        acc[0] = __builtin_amdgcn_mfma_f32_16x16x32_bf16(af, bw[0], acc[0], 0, 0, 0);
        acc[1] = __builtin_amdgcn_mfma_f32_16x16x32_bf16(af, bw[1], acc[1], 0, 0, 0);
        acc[2] = __builtin_amdgcn_mfma_f32_16x16x32_bf16(af, bw[2], acc[2], 0, 0, 0);
        acc[3] = __builtin_amdgcn_mfma_f32_16x16x32_bf16(af, bw[3], acc[3], 0, 0, 0);
        if (nx) {
            if (tid < 64) *(bf16x8*)&As[cur^1][tid >> 2][(tid & 3)*8] = la;
            bw[0] = nb0; bw[1] = nb1; bw[2] = nb2; bw[3] = nb3;
        }
        __syncthreads();
    }
    // epilogue: x = acc + bias + res
    #pragma unroll
    for (int j = 0; j < 4; ++j) {
        int col = wave*64 + j*16 + (lane & 15);
        #pragma unroll
        for (int rg = 0; rg < 4; ++rg) {
            int row = (lane >> 4)*4 + rg;
            S[row][col] = acc[j][rg] + bias[col] + res[(size_t)(m0+row)*C_ + col];
        }
    }
    __syncthreads();
    int row = tid >> 4, g = tid & 15;
    size_t m = m0 + row;
    float x[16];
    #pragma unroll
    for (int u = 0; u < 4; ++u) {
        f32x4 v4 = *(const f32x4*)&S[row][g*16 + u*4];
        x[u*4+0] = v4[0]; x[u*4+1] = v4[1]; x[u*4+2] = v4[2]; x[u*4+3] = v4[3];
    }
    float s1 = 0.f, s2 = 0.f;
    #pragma unroll
    for (int u = 0; u < 16; ++u) { s1 += x[u]; s2 += x[u]*x[u]; }
    #pragma unroll
    for (int off = 8; off; off >>= 1) { s1 += __shfl_xor(s1, off, 16); s2 += __shfl_xor(s2, off, 16); }
    float mean = s1 * (1.f/C_);
    float var  = s2 * (1.f/C_) - mean*mean;
    float rstd = rsqrtf(var + 1e-5f);
    float y1[16];
    #pragma unroll
    for (int u = 0; u < 4; ++u) {
        f32x4 w4 = *(const f32x4*)&lnw1[g*16 + u*4];
        f32x4 b4 = *(const f32x4*)&lnb1[g*16 + u*4];
        #pragma unroll
        for (int v = 0; v < 4; ++v)
            y1[u*4+v] = (x[u*4+v] - mean)*rstd*w4[v] + b4[v];
    }
    if (VAR == 0) {
        #pragma unroll
        for (int u = 0; u < 4; ++u) {
            f32x4 v4 = { x[u*4], x[u*4+1], x[u*4+2], x[u*4+3] };
            *(f32x4*)&outF[m*C_ + g*16 + u*4] = v4;
        }
        unsigned pk[8];
        #pragma unroll
        for (int u = 0; u < 8; ++u) pk[u] = (unsigned)f2bf(y1[2*u]) | ((unsigned)f2bf(y1[2*u+1]) << 16);
        *(u32x4*)&outT2[m*C_ + g*16]     = *(u32x4*)&pk[0];
        *(u32x4*)&outT2[m*C_ + g*16 + 8] = *(u32x4*)&pk[4];
    } else {
        #pragma unroll
        for (int u = 0; u < 4; ++u) {
            f32x4 v4 = { y1[u*4], y1[u*4+1], y1[u*4+2], y1[u*4+3] };
            *(f32x4*)&outF[m*C_ + g*16 + u*4] = v4;
        }
        if (VAR == 1) {
            unsigned pk[8];
            #pragma unroll
            for (int u = 0; u < 8; ++u) pk[u] = (unsigned)f2bf(y1[2*u]) | ((unsigned)f2bf(y1[2*u+1]) << 16);
            *(u32x4*)&outB[m*C_ + g*16]     = *(u32x4*)&pk[0];
            *(u32x4*)&outB[m*C_ + g*16 + 8] = *(u32x4*)&pk[4];
            float t1 = 0.f, t2s = 0.f;
            #pragma unroll
            for (int u = 0; u < 16; ++u) { t1 += y1[u]; t2s += y1[u]*y1[u]; }
            #pragma unroll
            for (int off = 8; off; off >>= 1) { t1 += __shfl_xor(t1, off, 16); t2s += __shfl_xor(t2s, off, 16); }
            float mean2 = t1 * (1.f/C_);
            float var2  = t2s * (1.f/C_) - mean2*mean2;
            float rstd2 = rsqrtf(var2 + 1e-5f);
            unsigned pk2[8];
            #pragma unroll
            for (int u = 0; u < 4; ++u) {
                f32x4 w4 = *(const f32x4*)&lnw2[g*16 + u*4];
                f32x4 b4 = *(const f32x4*)&lnb2[g*16 + u*4];
                f32x4 q4 = *(const f32x4*)&qpe[g*16 + u*4];
                float z0 = (y1[u*4+0]-mean2)*rstd2*w4[0] + b4[0] + q4[0];
                float z1 = (y1[u*4+1]-mean2)*rstd2*w4[1] + b4[1] + q4[1];
                float z2 = (y1[u*4+2]-mean2)*rstd2*w4[2] + b4[2] + q4[2];
                float z3 = (y1[u*4+3]-mean2)*rstd2*w4[3] + b4[3] + q4[3];
                pk2[u*2]   = (unsigned)f2bf(z0) | ((unsigned)f2bf(z1) << 16);
                pk2[u*2+1] = (unsigned)f2bf(z2) | ((unsigned)f2bf(z3) << 16);
            }
            *(u32x4*)&outT2[m*C_ + g*16]     = *(u32x4*)&pk2[0];
            *(u32x4*)&outT2[m*C_ + g*16 + 8] = *(u32x4*)&pk2[4];
        }
    }
}

// ---------------- r via MFMA: per-head GEMM r_h[BN x 256] = q_h[BN x 32] @ Wk_h^T ----------------
__global__ __launch_bounds__(256) void rk_kernel(const unsigned short* __restrict__ q,
                                                 const unsigned short* __restrict__ Wqkv_l,
                                                 unsigned short* __restrict__ r) {
    int n0 = blockIdx.x * 64, m0 = blockIdx.y * 64, h = blockIdx.z;
    __shared__ unsigned short As[64][40];
    __shared__ unsigned short Ws[64][40];
    int tid = threadIdx.x;
    int wave = tid >> 6, lane = tid & 63;
    int wr = wave >> 1, wc = wave & 1;
    *(bf16x8*)&As[tid>>2][(tid&3)*8] =
        *(const bf16x8*)&q[(size_t)(m0 + (tid>>2))*C_ + h*DH_ + (tid&3)*8];
    {
        int d = tid >> 3, cg = tid & 7;
        bf16x8 wv = *(const bf16x8*)&Wqkv_l[(size_t)(C_ + h*DH_ + d)*C_ + n0 + cg*8];
        #pragma unroll
        for (int j = 0; j < 8; ++j) Ws[cg*8 + j][d] = (unsigned short)wv[j];
    }
    __syncthreads();
    int kf = (lane >> 4) * 8;
    bf16x8 af[2], wf[2];
    #pragma unroll
    for (int i = 0; i < 2; ++i) af[i] = *(const bf16x8*)&As[wr*32 + i*16 + (lane & 15)][kf];
    #pragma unroll
    for (int j = 0; j < 2; ++j) wf[j] = *(const bf16x8*)&Ws[wc*32 + j*16 + (lane & 15)][kf];
    f32x4 acc[2][2];
    #pragma unroll
    for (int i = 0; i < 2; ++i)
        #pragma unroll
        for (int j = 0; j < 2; ++j)
            acc[i][j] = __builtin_amdgcn_mfma_f32_16x16x32_bf16(af[i], wf[j],
                          (f32x4){0.f,0.f,0.f,0.f}, 0, 0, 0);
    #pragma unroll
    for (int i = 0; i < 2; ++i)
        #pragma unroll
        for (int j = 0; j < 2; ++j)
            #pragma unroll
            for (int rg = 0; rg < 4; ++rg) {
                int m = m0 + wr*32 + i*16 + (lane >> 4)*4 + rg;
                int pl = wc*32 + j*16 + (lane & 15);
                r[(size_t)m*(NH_*C_) + h*C_ + n0 + pl] = f2bf(acc[i][j][rg]);
            }
}

// ---------------- attention: one WAVE per point, MFMA scores ----------------
__global__ __launch_bounds__(256) void attn_kernel(const unsigned short* __restrict__ q,
                                                   const unsigned short* __restrict__ kv,
                                                   const unsigned short* __restrict__ kpe,
                                                   const unsigned short* __restrict__ r,
                                                   const int* __restrict__ idx,
                                                   unsigned short* __restrict__ ao) {
    int wid = threadIdx.x >> 6, lane = threadIdx.x & 63;
    int point = blockIdx.x*4 + wid;
    __shared__ __align__(16) unsigned short vs[4][K_][264];
    __shared__ __align__(16) float atts[4][NH_][K_];
    int row = lane & 15;
    int off8 = (lane >> 4) * 8;
    int idx_l = idx[point*K_ + row];

    #pragma unroll
    for (int t = 0; t < 8; ++t) {
        int vr = 2*t + (lane >> 5);
        int j = __shfl(idx_l, vr, 64);
        int cc = (lane & 31) * 8;
        *(bf16x8*)&vs[wid][vr][cc] = *(const bf16x8*)&kv[(size_t)j*512 + 256 + cc];
    }

    f32x4 acc = {0.f, 0.f, 0.f, 0.f};
    const bf16x8 zero8 = {0,0,0,0,0,0,0,0};
    #pragma unroll
    for (int s = 0; s < 8; ++s) {
        bf16x8 a = *(const bf16x8*)&kpe[((size_t)point*K_ + row)*C_ + s*32 + off8];
        bf16x8 b = zero8;
        if (row < 8) b = *(const bf16x8*)&r[(size_t)point*NH_*C_ + row*C_ + s*32 + off8];
        acc = __builtin_amdgcn_mfma_f32_16x16x32_bf16(a, b, acc, 0, 0, 0);
    }
    #pragma unroll
    for (int s = 0; s < 8; ++s) {
        bf16x8 a = *(const bf16x8*)&kv[(size_t)idx_l*512 + s*32 + off8];
        bf16x8 b = zero8;
        if (row == 8 + s) b = *(const bf16x8*)&q[(size_t)point*C_ + s*32 + off8];
        acc = __builtin_amdgcn_mfma_f32_16x16x32_bf16(a, b, acc, 0, 0, 0);
    }

    const float scale = 0.1767766952966369f;
    float sv[4], m = -1e30f;
    #pragma unroll
    for (int rg = 0; rg < 4; ++rg) {
        float o = __shfl_xor(acc[rg], 8, 64);
        sv[rg] = (acc[rg] + o) * scale;
        m = fmaxf(m, sv[rg]);
    }
    m = fmaxf(m, __shfl_xor(m, 16, 64));
    m = fmaxf(m, __shfl_xor(m, 32, 64));
    float sum = 0.f;
    #pragma unroll
    for (int rg = 0; rg < 4; ++rg) { sv[rg] = __expf(sv[rg] - m); sum += sv[rg]; }
    sum += __shfl_xor(sum, 16, 64);
    sum += __shfl_xor(sum, 32, 64);
    float inv = 1.f / sum;
    if (row < 8) {
        f32x4 av = { sv[0]*inv, sv[1]*inv, sv[2]*inv, sv[3]*inv };
        *(f32x4*)&atts[wid][row][(lane >> 4) * 4] = av;
    }

    int h = lane >> 3;
    float att_f[16];
    #pragma unroll
    for (int u = 0; u < 4; ++u) {
        f32x4 t4 = *(const f32x4*)&atts[wid][h][u*4];
        att_f[u*4+0] = t4[0]; att_f[u*4+1] = t4[1]; att_f[u*4+2] = t4[2]; att_f[u*4+3] = t4[3];
    }
    int cbase = lane * 4;
    float o0 = 0.f, o1 = 0.f, o2 = 0.f, o3 = 0.f;
    #pragma unroll
    for (int k = 0; k < K_; ++k) {
        unsigned long long vv = *(const unsigned long long*)&vs[wid][k][cbase];
        unsigned lo = (unsigned)vv, hi = (unsigned)(vv >> 32);
        float a = att_f[k];
        o0 += a * __uint_as_float(lo << 16);
        o1 += a * __uint_as_float(lo & 0xffff0000u);
        o2 += a * __uint_as_float(hi << 16);
        o3 += a * __uint_as_float(hi & 0xffff0000u);
    }
    unsigned p0 = (unsigned)f2bf(o0) | ((unsigned)f2bf(o1) << 16);
    unsigned p1 = (unsigned)f2bf(o2) | ((unsigned)f2bf(o3) << 16);
    unsigned out2[2] = { p0, p1 };
    *(unsigned long long*)&ao[(size_t)point*C_ + cbase] = *(const unsigned long long*)out2;
}

extern "C" void kernel_launch(void* const* d_in, const int* in_sizes, int n_in,
                              void* d_out, int out_size, void* d_ws, size_t ws_size,
                              hipStream_t stream) {
    const float* feature  = (const float*)d_in[0];
    const float* xyz      = (const float*)d_in[1];
    const float* pe_W1    = (const float*)d_in[2];
    const float* pe_b1    = (const float*)d_in[3];
    const float* pe_W2    = (const float*)d_in[4];
    const float* pe_b2    = (const float*)d_in[5];
    const float* Wqkv     = (const float*)d_in[6];
    const float* bqkv     = (const float*)d_in[7];
    const float* Wo       = (const float*)d_in[8];
    const float* bo       = (const float*)d_in[9];
    const float* ln_attn_w= (const float*)d_in[10];
    const float* ln_attn_b= (const float*)d_in[11];
    const float* W1       = (const float*)d_in[12];
    const float* b1       = (const float*)d_in[13];
    const float* W2       = (const float*)d_in[14];
    const float* b2       = (const float*)d_in[15];
    const float* ln_ffn_w = (const float*)d_in[16];
    const float* ln_ffn_b = (const float*)d_in[17];
    const float* ln_out_w = (const float*)d_in[18];
    const float* ln_out_b = (const float*)d_in[19];

    // ---- workspace layout ----
    float* ws = (float*)d_ws;
    float* w_out = ws;                                   // BN*C fp32
    float* w_qpe = w_out + (size_t)BN_*C_;               // C fp32
    unsigned short* bptr = (unsigned short*)(w_qpe + C_ + 64);
    unsigned short* b_out = bptr;  bptr += (size_t)BN_*C_;
    unsigned short* b_t2  = bptr;  bptr += (size_t)BN_*C_;
    unsigned short* b_q   = bptr;  bptr += (size_t)BN_*C_;
    unsigned short* b_kv  = bptr;  bptr += (size_t)BN_*512;
    unsigned short* b_ao  = bptr;  bptr += (size_t)BN_*C_;
    unsigned short* b_ffh = bptr;  bptr += (size_t)BN_*FF_;
    unsigned short* w_kpe = bptr;  bptr += (size_t)BN_*K_*C_;
    unsigned short* w_r   = bptr;  bptr += (size_t)BN_*NH_*C_;
    unsigned short* b_hid = bptr;  bptr += (size_t)BN_*K_*C_;
    unsigned short* bWqkv = bptr;  bptr += (size_t)L_*3*C_*C_;   // row-major (rk)
    unsigned short* Fqkv  = bptr;  bptr += (size_t)L_*3*C_*C_;   // frag tiles
    unsigned short* Fo    = bptr;  bptr += (size_t)L_*C_*C_;
    unsigned short* F1    = bptr;  bptr += (size_t)L_*FF_*C_;
    unsigned short* F2    = bptr;  bptr += (size_t)L_*C_*FF_;
    unsigned short* Fpe   = bptr;  bptr += (size_t)C_*C_;
    int* w_idx = (int*)bptr;

    // ---- weight conversions ----
    f2bf_kernel<<<(L_*3*C_*C_+255)/256, 256, 0, stream>>>(Wqkv, bWqkv, L_*3*C_*C_);
    w2frag_kernel<<<(L_*3*C_*C_/512)/4, 256, 0, stream>>>(Wqkv, Fqkv, L_*3*C_, C_);
    w2frag_kernel<<<(L_*C_*C_/512)/4,   256, 0, stream>>>(Wo,   Fo,   L_*C_,   C_);
    w2frag_kernel<<<(L_*FF_*C_/512)/4,  256, 0, stream>>>(W1,   F1,   L_*FF_,  C_);
    w2frag_kernel<<<(L_*C_*FF_/512)/4,  256, 0, stream>>>(W2,   F2,   L_*C_,   FF_);
    w2frag_kernel<<<(C_*C_/512)/4,      256, 0, stream>>>(pe_W2, Fpe, C_,      C_);

    // ---- preprocessing ----
    knn_kernel<<<BN_/4, 256, 0, stream>>>(xyz, w_idx);
    qpe_kernel<<<1, 256, 0, stream>>>(pe_b1, pe_W2, pe_b2, w_qpe);
    reshape_in_ln<<<BN_, 256, 0, stream>>>(feature, ln_attn_w, ln_attn_b, w_qpe,
                                           w_out, b_out, b_t2);
    pe_hidden_kernel<<<BN_, 256, 0, stream>>>(xyz, w_idx, pe_W1, pe_b1, b_hid);
    gemm_k2<0,false,2><<<dim3(C_/64, (BN_*K_)/64), 256, 0, stream>>>(
        b_hid, Fpe, pe_b2, nullptr, nullptr, w_kpe, C_, C_);

    // ---- layers ----
    for (int i = 0; i < L_; ++i) {
        const unsigned short* Fqkv_l = Fqkv + (size_t)i*3*C_*C_;
        const float* bqkv_l = bqkv + (size_t)i*3*C_;

        qkv_kernel2<<<dim3(12, BN_/64), 256, 0, stream>>>(b_t2, b_out, Fqkv_l, bqkv_l, b_q, b_kv);
        rk_kernel<<<dim3(4, BN_/64, NH_), 256, 0, stream>>>(b_q, bWqkv + (size_t)i*3*C_*C_, w_r);
        attn_kernel<<<BN_/4, 256, 0, stream>>>(b_q, b_kv, w_kpe, w_r, w_idx, b_ao);
        gemm_ln2<0><<<BN_/16, 256, 0, stream>>>(
            b_ao, Fo + (size_t)i*C_*C_, bo + i*C_, w_out,
            ln_ffn_w + i*C_, ln_ffn_b + i*C_, nullptr, nullptr, nullptr,
            w_out, nullptr, b_t2, C_);
        gemm_k2<1,false,2><<<dim3(FF_/64, BN_/64), 256, 0, stream>>>(
            b_t2, F1 + (size_t)i*FF_*C_, b1 + i*FF_, nullptr, nullptr, b_ffh, FF_, C_);
        if (i < L_-1) {
            gemm_ln2<1><<<BN_/16, 256, 0, stream>>>(
                b_ffh, F2 + (size_t)i*C_*FF_, b2 + i*C_, w_out,
                ln_out_w + i*C_, ln_out_b + i*C_,
                ln_attn_w + (i+1)*C_, ln_attn_b + (i+1)*C_, w_qpe,
                w_out, b_out, b_t2, FF_);
        } else {
            gemm_ln2<2><<<BN_/16, 256, 0, stream>>>(
                b_ffh, F2 + (size_t)i*C_*FF_, b2 + i*C_, w_out,
                ln_out_w + i*C_, ln_out_b + i*C_, nullptr, nullptr, nullptr,
                w_out, nullptr, nullptr, FF_);
        }
    }

    reshape_out_kernel<<<BN_, 256, 0, stream>>>(w_out, (float*)d_out);
}

// Round 9
// 599.174 us; speedup vs baseline: 5.3641x; 1.1128x over previous
//
#include <hip/hip_runtime.h>
#include <math.h>

#define BS_ 2
#define V_ 4
#define H_ 24
#define W_ 24
#define N_ (V_*H_*W_)        // 2304
#define BN_ (BS_*N_)         // 4608
#define C_ 256
#define K_ 16
#define L_ 6
#define NH_ 8
#define DH_ 32
#define FF_ 1024

typedef __attribute__((ext_vector_type(4))) float f32x4;
typedef __attribute__((ext_vector_type(8))) short bf16x8;
typedef __attribute__((ext_vector_type(4))) unsigned u32x4;

__device__ inline unsigned short f2bf(float x) {
    unsigned u = __float_as_uint(x);
    unsigned r = u + 0x7fffu + ((u >> 16) & 1u);
    return (unsigned short)(r >> 16);
}
__device__ inline float bf2f(unsigned short h) {
    return __uint_as_float(((unsigned)h) << 16);
}

// ---------------- fp32 -> bf16 elementwise (row-major copy for rk) ----------------
__global__ __launch_bounds__(256) void f2bf_kernel(const float* __restrict__ in,
                                                   unsigned short* __restrict__ out, int n) {
    int i = blockIdx.x*256 + threadIdx.x;
    if (i < n) out[i] = f2bf(in[i]);
}

// ---------------- weight -> MFMA B-fragment tiles ----------------
// W[P][K] fp32 -> F: tile (tn=n/16, tk=k/32), F[tile*512 + lane*8 + j] =
//   bf16(W[tn*16 + (lane&15)][tk*32 + (lane>>4)*8 + j])
__global__ __launch_bounds__(256) void w2frag_kernel(const float* __restrict__ W,
                                                     unsigned short* __restrict__ F,
                                                     int P, int K) {
    int wid = threadIdx.x >> 6, lane = threadIdx.x & 63;
    int tile = blockIdx.x*4 + wid;
    int nkt = K >> 5;
    int tn = tile / nkt, tk = tile - tn*nkt;
    const float* src = W + (size_t)(tn*16 + (lane & 15))*K + tk*32 + (lane >> 4)*8;
    unsigned short tmp[8];
    #pragma unroll
    for (int j = 0; j < 8; ++j) tmp[j] = f2bf(src[j]);
    *(bf16x8*)&F[(size_t)tile*512 + lane*8] = *(bf16x8*)tmp;
}

// ---------------- reshape in + ln_attn(layer0) + qpe ----------------
__global__ __launch_bounds__(256) void reshape_in_ln(const float* __restrict__ f,
                                                     const float* __restrict__ lnw,
                                                     const float* __restrict__ lnb,
                                                     const float* __restrict__ qpe,
                                                     float* __restrict__ w_out,
                                                     unsigned short* __restrict__ b_out,
                                                     unsigned short* __restrict__ b_t2) {
    int bn = blockIdx.x, c = threadIdx.x;
    int b = bn / N_, rem = bn % N_;
    int v = rem / (H_*W_), hw = rem % (H_*W_);
    float x = f[(((size_t)(b*V_ + v)*C_ + c)*(H_*W_)) + hw];
    w_out[(size_t)bn*C_ + c] = x;
    b_out[(size_t)bn*C_ + c] = f2bf(x);
    __shared__ float red[4];
    float s = x;
    #pragma unroll
    for (int off = 32; off; off >>= 1) s += __shfl_xor(s, off, 64);
    if ((c & 63) == 0) red[c >> 6] = s;
    __syncthreads();
    float mean = (red[0]+red[1]+red[2]+red[3]) * (1.f/C_);
    __syncthreads();
    float dx = x - mean;
    s = dx*dx;
    #pragma unroll
    for (int off = 32; off; off >>= 1) s += __shfl_xor(s, off, 64);
    if ((c & 63) == 0) red[c >> 6] = s;
    __syncthreads();
    float var = (red[0]+red[1]+red[2]+red[3]) * (1.f/C_);
    float y = dx * rsqrtf(var + 1e-5f) * lnw[c] + lnb[c] + qpe[c];
    b_t2[(size_t)bn*C_ + c] = f2bf(y);
}

// ---------------- reshape out: (BN, C) -> (B*V,C,H,W) ----------------
__global__ __launch_bounds__(256) void reshape_out_kernel(const float* __restrict__ in,
                                                          float* __restrict__ o) {
    int bn = blockIdx.x, c = threadIdx.x;
    int b = bn / N_, rem = bn % N_;
    int v = rem / (H_*W_), hw = rem % (H_*W_);
    o[(((size_t)(b*V_ + v)*C_ + c)*(H_*W_)) + hw] = in[(size_t)bn*C_ + c];
}

// ---------------- KNN: one WAVE per query point, 4 points/block ----------------
__global__ __launch_bounds__(256) void knn_kernel(const float* __restrict__ pts,
                                                  int* __restrict__ idx) {
    int wid = threadIdx.x >> 6, lane = threadIdx.x & 63;
    int point = blockIdx.x*4 + wid;
    int b = point / N_;
    int il = point % N_;
    __shared__ float ps[N_*3];
    for (int l = threadIdx.x; l < N_*3; l += 256) ps[l] = pts[(size_t)b*N_*3 + l];
    __syncthreads();
    float qx = ps[il*3], qy = ps[il*3+1], qz = ps[il*3+2];
    unsigned long long key[36];
    #pragma unroll
    for (int s = 0; s < 36; ++s) {
        int j = lane + 64*s;
        float dx = qx - ps[j*3], dy = qy - ps[j*3+1], dz = qz - ps[j*3+2];
        float d2 = dx*dx + dy*dy + dz*dz;
        key[s] = ((unsigned long long)__float_as_uint(d2) << 32) | (unsigned)j;
    }
    for (int it = 0; it < K_; ++it) {
        unsigned long long b0 = key[0], b1 = key[1], b2 = key[2], b3 = key[3];
        #pragma unroll
        for (int s = 4; s < 36; s += 4) {
            b0 = key[s]   < b0 ? key[s]   : b0;
            b1 = key[s+1] < b1 ? key[s+1] : b1;
            b2 = key[s+2] < b2 ? key[s+2] : b2;
            b3 = key[s+3] < b3 ? key[s+3] : b3;
        }
        unsigned long long m01 = b0 < b1 ? b0 : b1;
        unsigned long long m23 = b2 < b3 ? b2 : b3;
        unsigned long long best = m01 < m23 ? m01 : m23;
        #pragma unroll
        for (int off = 32; off; off >>= 1) {
            unsigned long long o = __shfl_xor(best, off, 64);
            if (o < best) best = o;
        }
        int wj = (int)(best & 0xffffffffu);
        if (lane == 0) idx[point*K_ + it] = b*N_ + wj;
        if ((wj & 63) == lane) {
            int sw = wj >> 6;
            #pragma unroll
            for (int s = 0; s < 36; ++s) if (s == sw) key[s] = ~0ull;
        }
    }
}

// ---------------- q_pe = relu(b1)@W2^T + b2 (fp32, tiny) ----------------
__global__ __launch_bounds__(256) void qpe_kernel(const float* __restrict__ b1,
                                                  const float* __restrict__ W2,
                                                  const float* __restrict__ b2,
                                                  float* __restrict__ qpe) {
    __shared__ float h[C_];
    int tid = threadIdx.x;
    h[tid] = fmaxf(b1[tid], 0.f);
    __syncthreads();
    float acc = 0.f;
    for (int j = 0; j < C_; ++j) acc += h[j] * W2[(size_t)tid*C_ + j];
    qpe[tid] = acc + b2[tid];
}

// ---------------- PE hidden (bf16): one block per point, 16 rows each ----------------
__global__ __launch_bounds__(256) void pe_hidden_kernel(const float* __restrict__ pts,
                                                        const int* __restrict__ idx,
                                                        const float* __restrict__ W1,
                                                        const float* __restrict__ b1,
                                                        unsigned short* __restrict__ hidden) {
    int point = blockIdx.x;
    int c = threadIdx.x;
    __shared__ float rel[K_][3];
    if (threadIdx.x < K_*3) {
        int k = threadIdx.x / 3, ax = threadIdx.x % 3;
        int j = idx[point*K_ + k];
        rel[k][ax] = pts[(size_t)j*3 + ax] - pts[(size_t)point*3 + ax];
    }
    __syncthreads();
    float w0 = W1[c*3], w1 = W1[c*3+1], w2 = W1[c*3+2], bb = b1[c];
    #pragma unroll
    for (int k = 0; k < K_; ++k) {
        float v = rel[k][0]*w0 + rel[k][1]*w1 + rel[k][2]*w2 + bb;
        hidden[((size_t)point*K_ + k)*C_ + c] = f2bf(fmaxf(v, 0.f));
    }
}

// ---------------- GEMM body (64x64): A dbuf-LDS, B direct-from-global frag tiles ----------------
template<int ACT, bool RES, int OMODE>
__device__ __forceinline__ void gemm_body2(const unsigned short* __restrict__ A, int sA,
                                           const unsigned short* __restrict__ Wf,
                                           const float* __restrict__ bias, int bcol0,
                                           const float* __restrict__ res,
                                           float* __restrict__ outF,
                                           unsigned short* __restrict__ outB,
                                           int sO, int on0, int m0, int K) {
    __shared__ unsigned short As[2][64][40];
    int tid = threadIdx.x;
    int wave = tid >> 6, lane = tid & 63;
    int wr = wave >> 1, wc = wave & 1;
    int nkt = K >> 5;
    f32x4 acc[2][2];
    #pragma unroll
    for (int i = 0; i < 2; ++i)
        #pragma unroll
        for (int j = 0; j < 2; ++j) acc[i][j] = (f32x4){0.f, 0.f, 0.f, 0.f};

    int r = tid >> 2, ch = tid & 3;
    const unsigned short* pA = A + (size_t)(m0 + r)*sA + ch*8;
    const unsigned short* bb = Wf + (size_t)(wc*2)*nkt*512 + lane*8;
    *(bf16x8*)&As[0][r][ch*8] = *(const bf16x8*)pA;
    bf16x8 bw0 = *(const bf16x8*)bb;
    bf16x8 bw1 = *(const bf16x8*)(bb + (size_t)nkt*512);
    __syncthreads();
    for (int t = 0; t < nkt; ++t) {
        int cur = t & 1;
        bool nx = (t + 1 < nkt);
        bf16x8 la, nb0, nb1;
        if (nx) {
            la  = *(const bf16x8*)(pA + (t+1)*32);
            nb0 = *(const bf16x8*)(bb + (size_t)(t+1)*512);
            nb1 = *(const bf16x8*)(bb + (size_t)nkt*512 + (size_t)(t+1)*512);
        }
        int kf = (lane >> 4) * 8;
        bf16x8 af0 = *(const bf16x8*)&As[cur][wr*32 + (lane & 15)][kf];
        bf16x8 af1 = *(const bf16x8*)&As[cur][wr*32 + 16 + (lane & 15)][kf];
        acc[0][0] = __builtin_amdgcn_mfma_f32_16x16x32_bf16(af0, bw0, acc[0][0], 0, 0, 0);
        acc[0][1] = __builtin_amdgcn_mfma_f32_16x16x32_bf16(af0, bw1, acc[0][1], 0, 0, 0);
        acc[1][0] = __builtin_amdgcn_mfma_f32_16x16x32_bf16(af1, bw0, acc[1][0], 0, 0, 0);
        acc[1][1] = __builtin_amdgcn_mfma_f32_16x16x32_bf16(af1, bw1, acc[1][1], 0, 0, 0);
        if (nx) *(bf16x8*)&As[cur^1][r][ch*8] = la;
        bw0 = nb0; bw1 = nb1;
        __syncthreads();
    }
    #pragma unroll
    for (int i = 0; i < 2; ++i) {
        #pragma unroll
        for (int j = 0; j < 2; ++j) {
            #pragma unroll
            for (int rg = 0; rg < 4; ++rg) {
                int m = m0 + wr*32 + i*16 + (lane >> 4)*4 + rg;
                int pl = wc*32 + j*16 + (lane & 15);
                float v = acc[i][j][rg];
                if (bias) v += bias[bcol0 + pl];
                if (ACT == 1) v = fmaxf(v, 0.f);
                if (RES) v += res[(size_t)m*sO + on0 + pl];
                if (OMODE != 2) outF[(size_t)m*sO + on0 + pl] = v;
                if (OMODE != 0) outB[(size_t)m*sO + on0 + pl] = f2bf(v);
            }
        }
    }
}

template<int ACT, bool RES, int OMODE>
__global__ __launch_bounds__(256) void gemm_k2(const unsigned short* __restrict__ A,
                                               const unsigned short* __restrict__ Wf0,
                                               const float* __restrict__ bias,
                                               const float* __restrict__ res,
                                               float* __restrict__ outF,
                                               unsigned short* __restrict__ outB,
                                               int P, int K) {
    int n0 = blockIdx.x * 64, m0 = blockIdx.y * 64;
    const unsigned short* Wf = Wf0 + (size_t)(n0 >> 4)*(K >> 5)*512;
    gemm_body2<ACT,RES,OMODE>(A, K, Wf, bias, n0, res, outF, outB, P, n0, m0, K);
}

// fused q + kv GEMM: blockIdx.x 0..3 -> q (A=t2), 4..11 -> k,v (A=out)
__global__ __launch_bounds__(256) void qkv_kernel2(const unsigned short* __restrict__ t2,
                                                   const unsigned short* __restrict__ outb,
                                                   const unsigned short* __restrict__ Fqkv_l,
                                                   const float* __restrict__ bqkv_l,
                                                   unsigned short* __restrict__ b_q,
                                                   unsigned short* __restrict__ b_kv) {
    int bx = blockIdx.x;
    int m0 = blockIdx.y * 64;
    const unsigned short* Wf = Fqkv_l + (size_t)(bx*4)*8*512;   // nkt=8 for K=256
    if (bx < 4) {
        gemm_body2<0,false,2>(t2, C_, Wf, bqkv_l, bx*64, nullptr, nullptr, b_q, 256, bx*64, m0, C_);
    } else {
        gemm_body2<0,false,2>(outb, C_, Wf, bqkv_l, bx*64, nullptr, nullptr, b_kv, 512, bx*64 - 256, m0, C_);
    }
}

// ---------------- shared LN epilogue helper (x in S[16][260], row/thread mapping fixed) ----------
// VAR 0 (Wo):   outF = x,  outT2 = bf16(LN1(x))
// VAR 1 (FFN2): outF = y1, outB = bf16(y1), outT2 = bf16(LN2(y1)+qpe)
// VAR 2 (last): outF = y1
template<int VAR>
__device__ __forceinline__ void ln_epilogue(float (*S)[260], int m0,
                                            const float* __restrict__ lnw1, const float* __restrict__ lnb1,
                                            const float* __restrict__ lnw2, const float* __restrict__ lnb2,
                                            const float* __restrict__ qpe,
                                            float* __restrict__ outF,
                                            unsigned short* __restrict__ outB,
                                            unsigned short* __restrict__ outT2) {
    int tid = threadIdx.x;
    int row = tid >> 4, g = tid & 15;
    size_t m = m0 + row;
    float x[16];
    #pragma unroll
    for (int u = 0; u < 4; ++u) {
        f32x4 v4 = *(const f32x4*)&S[row][g*16 + u*4];
        x[u*4+0] = v4[0]; x[u*4+1] = v4[1]; x[u*4+2] = v4[2]; x[u*4+3] = v4[3];
    }
    float s1 = 0.f, s2 = 0.f;
    #pragma unroll
    for (int u = 0; u < 16; ++u) { s1 += x[u]; s2 += x[u]*x[u]; }
    #pragma unroll
    for (int off = 8; off; off >>= 1) { s1 += __shfl_xor(s1, off, 16); s2 += __shfl_xor(s2, off, 16); }
    float mean = s1 * (1.f/C_);
    float var  = s2 * (1.f/C_) - mean*mean;
    float rstd = rsqrtf(var + 1e-5f);
    float y1[16];
    #pragma unroll
    for (int u = 0; u < 4; ++u) {
        f32x4 w4 = *(const f32x4*)&lnw1[g*16 + u*4];
        f32x4 b4 = *(const f32x4*)&lnb1[g*16 + u*4];
        #pragma unroll
        for (int v = 0; v < 4; ++v)
            y1[u*4+v] = (x[u*4+v] - mean)*rstd*w4[v] + b4[v];
    }
    if (VAR == 0) {
        #pragma unroll
        for (int u = 0; u < 4; ++u) {
            f32x4 v4 = { x[u*4], x[u*4+1], x[u*4+2], x[u*4+3] };
            *(f32x4*)&outF[m*C_ + g*16 + u*4] = v4;
        }
        unsigned pk[8];
        #pragma unroll
        for (int u = 0; u < 8; ++u) pk[u] = (unsigned)f2bf(y1[2*u]) | ((unsigned)f2bf(y1[2*u+1]) << 16);
        *(u32x4*)&outT2[m*C_ + g*16]     = *(u32x4*)&pk[0];
        *(u32x4*)&outT2[m*C_ + g*16 + 8] = *(u32x4*)&pk[4];
    } else {
        #pragma unroll
        for (int u = 0; u < 4; ++u) {
            f32x4 v4 = { y1[u*4], y1[u*4+1], y1[u*4+2], y1[u*4+3] };
            *(f32x4*)&outF[m*C_ + g*16 + u*4] = v4;
        }
        if (VAR == 1) {
            unsigned pk[8];
            #pragma unroll
            for (int u = 0; u < 8; ++u) pk[u] = (unsigned)f2bf(y1[2*u]) | ((unsigned)f2bf(y1[2*u+1]) << 16);
            *(u32x4*)&outB[m*C_ + g*16]     = *(u32x4*)&pk[0];
            *(u32x4*)&outB[m*C_ + g*16 + 8] = *(u32x4*)&pk[4];
            float t1 = 0.f, t2s = 0.f;
            #pragma unroll
            for (int u = 0; u < 16; ++u) { t1 += y1[u]; t2s += y1[u]*y1[u]; }
            #pragma unroll
            for (int off = 8; off; off >>= 1) { t1 += __shfl_xor(t1, off, 16); t2s += __shfl_xor(t2s, off, 16); }
            float mean2 = t1 * (1.f/C_);
            float var2  = t2s * (1.f/C_) - mean2*mean2;
            float rstd2 = rsqrtf(var2 + 1e-5f);
            unsigned pk2[8];
            #pragma unroll
            for (int u = 0; u < 4; ++u) {
                f32x4 w4 = *(const f32x4*)&lnw2[g*16 + u*4];
                f32x4 b4 = *(const f32x4*)&lnb2[g*16 + u*4];
                f32x4 q4 = *(const f32x4*)&qpe[g*16 + u*4];
                float z0 = (y1[u*4+0]-mean2)*rstd2*w4[0] + b4[0] + q4[0];
                float z1 = (y1[u*4+1]-mean2)*rstd2*w4[1] + b4[1] + q4[1];
                float z2 = (y1[u*4+2]-mean2)*rstd2*w4[2] + b4[2] + q4[2];
                float z3 = (y1[u*4+3]-mean2)*rstd2*w4[3] + b4[3] + q4[3];
                pk2[u*2]   = (unsigned)f2bf(z0) | ((unsigned)f2bf(z1) << 16);
                pk2[u*2+1] = (unsigned)f2bf(z2) | ((unsigned)f2bf(z3) << 16);
            }
            *(u32x4*)&outT2[m*C_ + g*16]     = *(u32x4*)&pk2[0];
            *(u32x4*)&outT2[m*C_ + g*16 + 8] = *(u32x4*)&pk2[4];
        }
    }
}

// ---------------- GEMM (BM=16, full P=256, B-from-global) + LN epilogue (Wo path) ----------------
template<int VAR>
__global__ __launch_bounds__(256) void gemm_ln2(const unsigned short* __restrict__ A,
                                                const unsigned short* __restrict__ Wf,
                                                const float* __restrict__ bias,
                                                const float* __restrict__ res,
                                                const float* __restrict__ lnw1, const float* __restrict__ lnb1,
                                                const float* __restrict__ lnw2, const float* __restrict__ lnb2,
                                                const float* __restrict__ qpe,
                                                float* __restrict__ outF,
                                                unsigned short* __restrict__ outB,
                                                unsigned short* __restrict__ outT2,
                                                int K) {
    __shared__ unsigned short As[2][16][40];
    __shared__ float S[16][260];
    int tid = threadIdx.x;
    int wave = tid >> 6, lane = tid & 63;
    int m0 = blockIdx.x * 16;
    int nkt = K >> 5;
    f32x4 acc[4];
    #pragma unroll
    for (int j = 0; j < 4; ++j) acc[j] = (f32x4){0.f,0.f,0.f,0.f};
    const unsigned short* pA = A + (size_t)(m0 + ((tid & 63) >> 2))*K + (tid & 3)*8;
    const unsigned short* bb = Wf + (size_t)(wave*4)*nkt*512 + lane*8;
    if (tid < 64) *(bf16x8*)&As[0][tid >> 2][(tid & 3)*8] = *(const bf16x8*)pA;
    bf16x8 bw[4];
    #pragma unroll
    for (int j = 0; j < 4; ++j) bw[j] = *(const bf16x8*)(bb + (size_t)j*nkt*512);
    __syncthreads();
    for (int t = 0; t < nkt; ++t) {
        int cur = t & 1;
        bool nx = (t + 1 < nkt);
        bf16x8 la, nb0, nb1, nb2, nb3;
        if (nx) {
            nb0 = *(const bf16x8*)(bb + (size_t)0*nkt*512 + (size_t)(t+1)*512);
            nb1 = *(const bf16x8*)(bb + (size_t)1*nkt*512 + (size_t)(t+1)*512);
            nb2 = *(const bf16x8*)(bb + (size_t)2*nkt*512 + (size_t)(t+1)*512);
            nb3 = *(const bf16x8*)(bb + (size_t)3*nkt*512 + (size_t)(t+1)*512);
            if (tid < 64) la = *(const bf16x8*)(pA + (t+1)*32);
        }
        int kf = (lane >> 4) * 8;
        bf16x8 af = *(const bf16x8*)&As[cur][lane & 15][kf];
        acc[0] = __builtin_amdgcn_mfma_f32_16x16x32_bf16(af, bw[0], acc[0], 0, 0, 0);
        acc[1] = __builtin_amdgcn_mfma_f32_16x16x32_bf16(af, bw[1], acc[1], 0, 0, 0);
        acc[2] = __builtin_amdgcn_mfma_f32_16x16x32_bf16(af, bw[2], acc[2], 0, 0, 0);
        acc[3] = __builtin_amdgcn_mfma_f32_16x16x32_bf16(af, bw[3], acc[3], 0, 0, 0);
        if (nx) {
            if (tid < 64) *(bf16x8*)&As[cur^1][tid >> 2][(tid & 3)*8] = la;
            bw[0] = nb0; bw[1] = nb1; bw[2] = nb2; bw[3] = nb3;
        }
        __syncthreads();
    }
    #pragma unroll
    for (int j = 0; j < 4; ++j) {
        int col = wave*64 + j*16 + (lane & 15);
        #pragma unroll
        for (int rg = 0; rg < 4; ++rg) {
            int row = (lane >> 4)*4 + rg;
            S[row][col] = acc[j][rg] + bias[col] + res[(size_t)(m0+row)*C_ + col];
        }
    }
    __syncthreads();
    ln_epilogue<VAR>(S, m0, lnw1, lnb1, lnw2, lnb2, qpe, outF, outB, outT2);
}

// ---------------- fused FFN: relu(t2@W1^T+b1)@W2^T+b2 + res + LN chain ----------------
// VAR 1 = mid-layer (ln_out + next ln_attn + qpe), VAR 2 = last layer (ln_out only)
template<int VAR>
__global__ __launch_bounds__(256) void ffn_ln(const unsigned short* __restrict__ t2,
                                              const unsigned short* __restrict__ F1,   // frags P=1024 K=256
                                              const float* __restrict__ b1v,
                                              const unsigned short* __restrict__ F2,   // frags P=256 K=1024
                                              const float* __restrict__ b2v,
                                              const float* __restrict__ res,
                                              const float* __restrict__ lnw1, const float* __restrict__ lnb1,
                                              const float* __restrict__ lnw2, const float* __restrict__ lnb2,
                                              const float* __restrict__ qpe,
                                              float* __restrict__ outF,
                                              unsigned short* __restrict__ outB,
                                              unsigned short* __restrict__ outT2) {
    __shared__ unsigned short tS[16][264];     // A tile (16 x 256), pad 8
    __shared__ unsigned short hS[16][1032];    // hidden (16 x 1024), pad 8 -> 2-way max conflict
    __shared__ float S[16][260];
    int tid = threadIdx.x;
    int wave = tid >> 6, lane = tid & 63;
    int m0 = blockIdx.x * 16;
    int kf = (lane >> 4) * 8;

    // stage t2 rows once
    #pragma unroll
    for (int u = 0; u < 2; ++u) {
        int id = tid + u*256;
        int rr = id >> 5, cc = id & 31;
        *(bf16x8*)&tS[rr][cc*8] = *(const bf16x8*)&t2[(size_t)(m0+rr)*C_ + cc*8];
    }
    __syncthreads();

    // phase 1: h[16][1024] in 4 passes of 256 cols; wave covers 64 cols/pass
    for (int nc = 0; nc < 4; ++nc) {
        f32x4 acc[4];
        #pragma unroll
        for (int j = 0; j < 4; ++j) acc[j] = (f32x4){0.f,0.f,0.f,0.f};
        const unsigned short* bb = F1 + ((size_t)(nc*16 + wave*4)*8)*512 + lane*8;
        #pragma unroll
        for (int t = 0; t < 8; ++t) {
            bf16x8 af = *(const bf16x8*)&tS[lane & 15][t*32 + kf];
            #pragma unroll
            for (int j = 0; j < 4; ++j) {
                bf16x8 wf = *(const bf16x8*)(bb + ((size_t)j*8 + t)*512);
                acc[j] = __builtin_amdgcn_mfma_f32_16x16x32_bf16(af, wf, acc[j], 0, 0, 0);
            }
        }
        #pragma unroll
        for (int j = 0; j < 4; ++j) {
            int col = nc*256 + wave*64 + j*16 + (lane & 15);
            float bc = b1v[col];
            #pragma unroll
            for (int rg = 0; rg < 4; ++rg) {
                int row = (lane >> 4)*4 + rg;
                hS[row][col] = f2bf(fmaxf(acc[j][rg] + bc, 0.f));
            }
        }
    }
    __syncthreads();

    // phase 2: out[16][256] = hS @ W2^T, K=1024 (nkt=32); wave covers 64 cols
    f32x4 acc2[4];
    #pragma unroll
    for (int j = 0; j < 4; ++j) acc2[j] = (f32x4){0.f,0.f,0.f,0.f};
    const unsigned short* bb2 = F2 + ((size_t)(wave*4)*32)*512 + lane*8;
    for (int t = 0; t < 32; ++t) {
        bf16x8 af = *(const bf16x8*)&hS[lane & 15][t*32 + kf];
        #pragma unroll
        for (int j = 0; j < 4; ++j) {
            bf16x8 wf = *(const bf16x8*)(bb2 + ((size_t)j*32 + t)*512);
            acc2[j] = __builtin_amdgcn_mfma_f32_16x16x32_bf16(af, wf, acc2[j], 0, 0, 0);
        }
    }
    #pragma unroll
    for (int j = 0; j < 4; ++j) {
        int col = wave*64 + j*16 + (lane & 15);
        #pragma unroll
        for (int rg = 0; rg < 4; ++rg) {
            int row = (lane >> 4)*4 + rg;
            S[row][col] = acc2[j][rg] + b2v[col] + res[(size_t)(m0+row)*C_ + col];
        }
    }
    __syncthreads();
    ln_epilogue<VAR>(S, m0, lnw1, lnb1, lnw2, lnb2, qpe, outF, outB, outT2);
}

// ---------------- r via MFMA: per-head GEMM r_h[BN x 256] = q_h[BN x 32] @ Wk_h^T ----------------
__global__ __launch_bounds__(256) void rk_kernel(const unsigned short* __restrict__ q,
                                                 const unsigned short* __restrict__ Wqkv_l,
                                                 unsigned short* __restrict__ r) {
    int n0 = blockIdx.x * 64, m0 = blockIdx.y * 64, h = blockIdx.z;
    __shared__ unsigned short As[64][40];
    __shared__ unsigned short Ws[64][40];
    int tid = threadIdx.x;
    int wave = tid >> 6, lane = tid & 63;
    int wr = wave >> 1, wc = wave & 1;
    *(bf16x8*)&As[tid>>2][(tid&3)*8] =
        *(const bf16x8*)&q[(size_t)(m0 + (tid>>2))*C_ + h*DH_ + (tid&3)*8];
    {
        int d = tid >> 3, cg = tid & 7;
        bf16x8 wv = *(const bf16x8*)&Wqkv_l[(size_t)(C_ + h*DH_ + d)*C_ + n0 + cg*8];
        #pragma unroll
        for (int j = 0; j < 8; ++j) Ws[cg*8 + j][d] = (unsigned short)wv[j];
    }
    __syncthreads();
    int kf = (lane >> 4) * 8;
    bf16x8 af[2], wf[2];
    #pragma unroll
    for (int i = 0; i < 2; ++i) af[i] = *(const bf16x8*)&As[wr*32 + i*16 + (lane & 15)][kf];
    #pragma unroll
    for (int j = 0; j < 2; ++j) wf[j] = *(const bf16x8*)&Ws[wc*32 + j*16 + (lane & 15)][kf];
    f32x4 acc[2][2];
    #pragma unroll
    for (int i = 0; i < 2; ++i)
        #pragma unroll
        for (int j = 0; j < 2; ++j)
            acc[i][j] = __builtin_amdgcn_mfma_f32_16x16x32_bf16(af[i], wf[j],
                          (f32x4){0.f,0.f,0.f,0.f}, 0, 0, 0);
    #pragma unroll
    for (int i = 0; i < 2; ++i)
        #pragma unroll
        for (int j = 0; j < 2; ++j)
            #pragma unroll
            for (int rg = 0; rg < 4; ++rg) {
                int m = m0 + wr*32 + i*16 + (lane >> 4)*4 + rg;
                int pl = wc*32 + j*16 + (lane & 15);
                r[(size_t)m*(NH_*C_) + h*C_ + n0 + pl] = f2bf(acc[i][j][rg]);
            }
}

// ---------------- attention: one WAVE per point, MFMA scores ----------------
__global__ __launch_bounds__(256) void attn_kernel(const unsigned short* __restrict__ q,
                                                   const unsigned short* __restrict__ kv,
                                                   const unsigned short* __restrict__ kpe,
                                                   const unsigned short* __restrict__ r,
                                                   const int* __restrict__ idx,
                                                   unsigned short* __restrict__ ao) {
    int wid = threadIdx.x >> 6, lane = threadIdx.x & 63;
    int point = blockIdx.x*4 + wid;
    __shared__ __align__(16) unsigned short vs[4][K_][264];
    __shared__ __align__(16) float atts[4][NH_][K_];
    int row = lane & 15;
    int off8 = (lane >> 4) * 8;
    int idx_l = idx[point*K_ + row];

    #pragma unroll
    for (int t = 0; t < 8; ++t) {
        int vr = 2*t + (lane >> 5);
        int j = __shfl(idx_l, vr, 64);
        int cc = (lane & 31) * 8;
        *(bf16x8*)&vs[wid][vr][cc] = *(const bf16x8*)&kv[(size_t)j*512 + 256 + cc];
    }

    f32x4 acc = {0.f, 0.f, 0.f, 0.f};
    const bf16x8 zero8 = {0,0,0,0,0,0,0,0};
    #pragma unroll
    for (int s = 0; s < 8; ++s) {
        bf16x8 a = *(const bf16x8*)&kpe[((size_t)point*K_ + row)*C_ + s*32 + off8];
        bf16x8 b = zero8;
        if (row < 8) b = *(const bf16x8*)&r[(size_t)point*NH_*C_ + row*C_ + s*32 + off8];
        acc = __builtin_amdgcn_mfma_f32_16x16x32_bf16(a, b, acc, 0, 0, 0);
    }
    #pragma unroll
    for (int s = 0; s < 8; ++s) {
        bf16x8 a = *(const bf16x8*)&kv[(size_t)idx_l*512 + s*32 + off8];
        bf16x8 b = zero8;
        if (row == 8 + s) b = *(const bf16x8*)&q[(size_t)point*C_ + s*32 + off8];
        acc = __builtin_amdgcn_mfma_f32_16x16x32_bf16(a, b, acc, 0, 0, 0);
    }

    const float scale = 0.1767766952966369f;
    float sv[4], m = -1e30f;
    #pragma unroll
    for (int rg = 0; rg < 4; ++rg) {
        float o = __shfl_xor(acc[rg], 8, 64);
        sv[rg] = (acc[rg] + o) * scale;
        m = fmaxf(m, sv[rg]);
    }
    m = fmaxf(m, __shfl_xor(m, 16, 64));
    m = fmaxf(m, __shfl_xor(m, 32, 64));
    float sum = 0.f;
    #pragma unroll
    for (int rg = 0; rg < 4; ++rg) { sv[rg] = __expf(sv[rg] - m); sum += sv[rg]; }
    sum += __shfl_xor(sum, 16, 64);
    sum += __shfl_xor(sum, 32, 64);
    float inv = 1.f / sum;
    if (row < 8) {
        f32x4 av = { sv[0]*inv, sv[1]*inv, sv[2]*inv, sv[3]*inv };
        *(f32x4*)&atts[wid][row][(lane >> 4) * 4] = av;
    }

    int h = lane >> 3;
    float att_f[16];
    #pragma unroll
    for (int u = 0; u < 4; ++u) {
        f32x4 t4 = *(const f32x4*)&atts[wid][h][u*4];
        att_f[u*4+0] = t4[0]; att_f[u*4+1] = t4[1]; att_f[u*4+2] = t4[2]; att_f[u*4+3] = t4[3];
    }
    int cbase = lane * 4;
    float o0 = 0.f, o1 = 0.f, o2 = 0.f, o3 = 0.f;
    #pragma unroll
    for (int k = 0; k < K_; ++k) {
        unsigned long long vv = *(const unsigned long long*)&vs[wid][k][cbase];
        unsigned lo = (unsigned)vv, hi = (unsigned)(vv >> 32);
        float a = att_f[k];
        o0 += a * __uint_as_float(lo << 16);
        o1 += a * __uint_as_float(lo & 0xffff0000u);
        o2 += a * __uint_as_float(hi << 16);
        o3 += a * __uint_as_float(hi & 0xffff0000u);
    }
    unsigned p0 = (unsigned)f2bf(o0) | ((unsigned)f2bf(o1) << 16);
    unsigned p1 = (unsigned)f2bf(o2) | ((unsigned)f2bf(o3) << 16);
    unsigned out2[2] = { p0, p1 };
    *(unsigned long long*)&ao[(size_t)point*C_ + cbase] = *(const unsigned long long*)out2;
}

extern "C" void kernel_launch(void* const* d_in, const int* in_sizes, int n_in,
                              void* d_out, int out_size, void* d_ws, size_t ws_size,
                              hipStream_t stream) {
    const float* feature  = (const float*)d_in[0];
    const float* xyz      = (const float*)d_in[1];
    const float* pe_W1    = (const float*)d_in[2];
    const float* pe_b1    = (const float*)d_in[3];
    const float* pe_W2    = (const float*)d_in[4];
    const float* pe_b2    = (const float*)d_in[5];
    const float* Wqkv     = (const float*)d_in[6];
    const float* bqkv     = (const float*)d_in[7];
    const float* Wo       = (const float*)d_in[8];
    const float* bo       = (const float*)d_in[9];
    const float* ln_attn_w= (const float*)d_in[10];
    const float* ln_attn_b= (const float*)d_in[11];
    const float* W1       = (const float*)d_in[12];
    const float* b1       = (const float*)d_in[13];
    const float* W2       = (const float*)d_in[14];
    const float* b2       = (const float*)d_in[15];
    const float* ln_ffn_w = (const float*)d_in[16];
    const float* ln_ffn_b = (const float*)d_in[17];
    const float* ln_out_w = (const float*)d_in[18];
    const float* ln_out_b = (const float*)d_in[19];

    // ---- workspace layout ----
    float* ws = (float*)d_ws;
    float* w_out = ws;                                   // BN*C fp32
    float* w_qpe = w_out + (size_t)BN_*C_;               // C fp32
    unsigned short* bptr = (unsigned short*)(w_qpe + C_ + 64);
    unsigned short* b_out = bptr;  bptr += (size_t)BN_*C_;
    unsigned short* b_t2  = bptr;  bptr += (size_t)BN_*C_;
    unsigned short* b_q   = bptr;  bptr += (size_t)BN_*C_;
    unsigned short* b_kv  = bptr;  bptr += (size_t)BN_*512;
    unsigned short* b_ao  = bptr;  bptr += (size_t)BN_*C_;
    unsigned short* w_kpe = bptr;  bptr += (size_t)BN_*K_*C_;
    unsigned short* w_r   = bptr;  bptr += (size_t)BN_*NH_*C_;
    unsigned short* b_hid = bptr;  bptr += (size_t)BN_*K_*C_;
    unsigned short* bWqkv = bptr;  bptr += (size_t)L_*3*C_*C_;   // row-major (rk)
    unsigned short* Fqkv  = bptr;  bptr += (size_t)L_*3*C_*C_;   // frag tiles
    unsigned short* Fo    = bptr;  bptr += (size_t)L_*C_*C_;
    unsigned short* F1    = bptr;  bptr += (size_t)L_*FF_*C_;
    unsigned short* F2    = bptr;  bptr += (size_t)L_*C_*FF_;
    unsigned short* Fpe   = bptr;  bptr += (size_t)C_*C_;
    int* w_idx = (int*)bptr;

    // ---- weight conversions ----
    f2bf_kernel<<<(L_*3*C_*C_+255)/256, 256, 0, stream>>>(Wqkv, bWqkv, L_*3*C_*C_);
    w2frag_kernel<<<(L_*3*C_*C_/512)/4, 256, 0, stream>>>(Wqkv, Fqkv, L_*3*C_, C_);
    w2frag_kernel<<<(L_*C_*C_/512)/4,   256, 0, stream>>>(Wo,   Fo,   L_*C_,   C_);
    w2frag_kernel<<<(L_*FF_*C_/512)/4,  256, 0, stream>>>(W1,   F1,   L_*FF_,  C_);
    w2frag_kernel<<<(L_*C_*FF_/512)/4,  256, 0, stream>>>(W2,   F2,   L_*C_,   FF_);
    w2frag_kernel<<<(C_*C_/512)/4,      256, 0, stream>>>(pe_W2, Fpe, C_,      C_);

    // ---- preprocessing ----
    knn_kernel<<<BN_/4, 256, 0, stream>>>(xyz, w_idx);
    qpe_kernel<<<1, 256, 0, stream>>>(pe_b1, pe_W2, pe_b2, w_qpe);
    reshape_in_ln<<<BN_, 256, 0, stream>>>(feature, ln_attn_w, ln_attn_b, w_qpe,
                                           w_out, b_out, b_t2);
    pe_hidden_kernel<<<BN_, 256, 0, stream>>>(xyz, w_idx, pe_W1, pe_b1, b_hid);
    gemm_k2<0,false,2><<<dim3(C_/64, (BN_*K_)/64), 256, 0, stream>>>(
        b_hid, Fpe, pe_b2, nullptr, nullptr, w_kpe, C_, C_);

    // ---- layers ----
    for (int i = 0; i < L_; ++i) {
        const unsigned short* Fqkv_l = Fqkv + (size_t)i*3*C_*C_;
        const float* bqkv_l = bqkv + (size_t)i*3*C_;

        qkv_kernel2<<<dim3(12, BN_/64), 256, 0, stream>>>(b_t2, b_out, Fqkv_l, bqkv_l, b_q, b_kv);
        rk_kernel<<<dim3(4, BN_/64, NH_), 256, 0, stream>>>(b_q, bWqkv + (size_t)i*3*C_*C_, w_r);
        attn_kernel<<<BN_/4, 256, 0, stream>>>(b_q, b_kv, w_kpe, w_r, w_idx, b_ao);
        gemm_ln2<0><<<BN_/16, 256, 0, stream>>>(
            b_ao, Fo + (size_t)i*C_*C_, bo + i*C_, w_out,
            ln_ffn_w + i*C_, ln_ffn_b + i*C_, nullptr, nullptr, nullptr,
            w_out, nullptr, b_t2, C_);
        if (i < L_-1) {
            ffn_ln<1><<<BN_/16, 256, 0, stream>>>(
                b_t2, F1 + (size_t)i*FF_*C_, b1 + i*FF_,
                F2 + (size_t)i*C_*FF_, b2 + i*C_, w_out,
                ln_out_w + i*C_, ln_out_b + i*C_,
                ln_attn_w + (i+1)*C_, ln_attn_b + (i+1)*C_, w_qpe,
                w_out, b_out, b_t2);
        } else {
            ffn_ln<2><<<BN_/16, 256, 0, stream>>>(
                b_t2, F1 + (size_t)i*FF_*C_, b1 + i*FF_,
                F2 + (size_t)i*C_*FF_, b2 + i*C_, w_out,
                ln_out_w + i*C_, ln_out_b + i*C_, nullptr, nullptr, nullptr,
                w_out, nullptr, nullptr);
        }
    }

    reshape_out_kernel<<<BN_, 256, 0, stream>>>(w_out, (float*)d_out);
}

// Round 15
// 599.015 us; speedup vs baseline: 5.3655x; 1.0003x over previous
//
#include <hip/hip_runtime.h>
#include <math.h>

#define BS_ 2
#define V_ 4
#define H_ 24
#define W_ 24
#define N_ (V_*H_*W_)        // 2304
#define BN_ (BS_*N_)         // 4608
#define C_ 256
#define K_ 16
#define L_ 6
#define NH_ 8
#define DH_ 32
#define FF_ 1024

typedef __attribute__((ext_vector_type(4))) float f32x4;
typedef __attribute__((ext_vector_type(8))) short bf16x8;
typedef __attribute__((ext_vector_type(4))) unsigned u32x4;

__device__ inline unsigned short f2bf(float x) {
    unsigned u = __float_as_uint(x);
    unsigned r = u + 0x7fffu + ((u >> 16) & 1u);
    return (unsigned short)(r >> 16);
}
__device__ inline float bf2f(unsigned short h) {
    return __uint_as_float(((unsigned)h) << 16);
}

// ---------------- fp32 -> bf16 elementwise (row-major copy for rk) ----------------
__global__ __launch_bounds__(256) void f2bf_kernel(const float* __restrict__ in,
                                                   unsigned short* __restrict__ out, int n) {
    int i = blockIdx.x*256 + threadIdx.x;
    if (i < n) out[i] = f2bf(in[i]);
}

// ---------------- weight -> MFMA B-fragment tiles ----------------
// W[P][K] fp32 -> F: tile (tn=n/16, tk=k/32), F[tile*512 + lane*8 + j] =
//   bf16(W[tn*16 + (lane&15)][tk*32 + (lane>>4)*8 + j])
__global__ __launch_bounds__(256) void w2frag_kernel(const float* __restrict__ W,
                                                     unsigned short* __restrict__ F,
                                                     int P, int K) {
    int wid = threadIdx.x >> 6, lane = threadIdx.x & 63;
    int tile = blockIdx.x*4 + wid;
    int nkt = K >> 5;
    int tn = tile / nkt, tk = tile - tn*nkt;
    const float* src = W + (size_t)(tn*16 + (lane & 15))*K + tk*32 + (lane >> 4)*8;
    unsigned short tmp[8];
    #pragma unroll
    for (int j = 0; j < 8; ++j) tmp[j] = f2bf(src[j]);
    *(bf16x8*)&F[(size_t)tile*512 + lane*8] = *(bf16x8*)tmp;
}

// ---------------- reshape in + ln_attn(layer0) + qpe ----------------
__global__ __launch_bounds__(256) void reshape_in_ln(const float* __restrict__ f,
                                                     const float* __restrict__ lnw,
                                                     const float* __restrict__ lnb,
                                                     const float* __restrict__ qpe,
                                                     float* __restrict__ w_out,
                                                     unsigned short* __restrict__ b_out,
                                                     unsigned short* __restrict__ b_t2) {
    int bn = blockIdx.x, c = threadIdx.x;
    int b = bn / N_, rem = bn % N_;
    int v = rem / (H_*W_), hw = rem % (H_*W_);
    float x = f[(((size_t)(b*V_ + v)*C_ + c)*(H_*W_)) + hw];
    w_out[(size_t)bn*C_ + c] = x;
    b_out[(size_t)bn*C_ + c] = f2bf(x);
    __shared__ float red[4];
    float s = x;
    #pragma unroll
    for (int off = 32; off; off >>= 1) s += __shfl_xor(s, off, 64);
    if ((c & 63) == 0) red[c >> 6] = s;
    __syncthreads();
    float mean = (red[0]+red[1]+red[2]+red[3]) * (1.f/C_);
    __syncthreads();
    float dx = x - mean;
    s = dx*dx;
    #pragma unroll
    for (int off = 32; off; off >>= 1) s += __shfl_xor(s, off, 64);
    if ((c & 63) == 0) red[c >> 6] = s;
    __syncthreads();
    float var = (red[0]+red[1]+red[2]+red[3]) * (1.f/C_);
    float y = dx * rsqrtf(var + 1e-5f) * lnw[c] + lnb[c] + qpe[c];
    b_t2[(size_t)bn*C_ + c] = f2bf(y);
}

// ---------------- reshape out: (BN, C) -> (B*V,C,H,W) ----------------
__global__ __launch_bounds__(256) void reshape_out_kernel(const float* __restrict__ in,
                                                          float* __restrict__ o) {
    int bn = blockIdx.x, c = threadIdx.x;
    int b = bn / N_, rem = bn % N_;
    int v = rem / (H_*W_), hw = rem % (H_*W_);
    o[(((size_t)(b*V_ + v)*C_ + c)*(H_*W_)) + hw] = in[(size_t)bn*C_ + c];
}

// ---------------- KNN: one WAVE per query point, 4 points/block ----------------
__global__ __launch_bounds__(256) void knn_kernel(const float* __restrict__ pts,
                                                  int* __restrict__ idx) {
    int wid = threadIdx.x >> 6, lane = threadIdx.x & 63;
    int point = blockIdx.x*4 + wid;
    int b = point / N_;
    int il = point % N_;
    __shared__ float ps[N_*3];
    for (int l = threadIdx.x; l < N_*3; l += 256) ps[l] = pts[(size_t)b*N_*3 + l];
    __syncthreads();
    float qx = ps[il*3], qy = ps[il*3+1], qz = ps[il*3+2];
    unsigned long long key[36];
    #pragma unroll
    for (int s = 0; s < 36; ++s) {
        int j = lane + 64*s;
        float dx = qx - ps[j*3], dy = qy - ps[j*3+1], dz = qz - ps[j*3+2];
        float d2 = dx*dx + dy*dy + dz*dz;
        key[s] = ((unsigned long long)__float_as_uint(d2) << 32) | (unsigned)j;
    }
    for (int it = 0; it < K_; ++it) {
        unsigned long long b0 = key[0], b1 = key[1], b2 = key[2], b3 = key[3];
        #pragma unroll
        for (int s = 4; s < 36; s += 4) {
            b0 = key[s]   < b0 ? key[s]   : b0;
            b1 = key[s+1] < b1 ? key[s+1] : b1;
            b2 = key[s+2] < b2 ? key[s+2] : b2;
            b3 = key[s+3] < b3 ? key[s+3] : b3;
        }
        unsigned long long m01 = b0 < b1 ? b0 : b1;
        unsigned long long m23 = b2 < b3 ? b2 : b3;
        unsigned long long best = m01 < m23 ? m01 : m23;
        #pragma unroll
        for (int off = 32; off; off >>= 1) {
            unsigned long long o = __shfl_xor(best, off, 64);
            if (o < best) best = o;
        }
        int wj = (int)(best & 0xffffffffu);
        if (lane == 0) idx[point*K_ + it] = b*N_ + wj;
        if ((wj & 63) == lane) {
            int sw = wj >> 6;
            #pragma unroll
            for (int s = 0; s < 36; ++s) if (s == sw) key[s] = ~0ull;
        }
    }
}

// ---------------- q_pe = relu(b1)@W2^T + b2 (fp32, tiny) ----------------
__global__ __launch_bounds__(256) void qpe_kernel(const float* __restrict__ b1,
                                                  const float* __restrict__ W2,
                                                  const float* __restrict__ b2,
                                                  float* __restrict__ qpe) {
    __shared__ float h[C_];
    int tid = threadIdx.x;
    h[tid] = fmaxf(b1[tid], 0.f);
    __syncthreads();
    float acc = 0.f;
    for (int j = 0; j < C_; ++j) acc += h[j] * W2[(size_t)tid*C_ + j];
    qpe[tid] = acc + b2[tid];
}

// ---------------- PE hidden (bf16): one block per point, 16 rows each ----------------
__global__ __launch_bounds__(256) void pe_hidden_kernel(const float* __restrict__ pts,
                                                        const int* __restrict__ idx,
                                                        const float* __restrict__ W1,
                                                        const float* __restrict__ b1,
                                                        unsigned short* __restrict__ hidden) {
    int point = blockIdx.x;
    int c = threadIdx.x;
    __shared__ float rel[K_][3];
    if (threadIdx.x < K_*3) {
        int k = threadIdx.x / 3, ax = threadIdx.x % 3;
        int j = idx[point*K_ + k];
        rel[k][ax] = pts[(size_t)j*3 + ax] - pts[(size_t)point*3 + ax];
    }
    __syncthreads();
    float w0 = W1[c*3], w1 = W1[c*3+1], w2 = W1[c*3+2], bb = b1[c];
    #pragma unroll
    for (int k = 0; k < K_; ++k) {
        float v = rel[k][0]*w0 + rel[k][1]*w1 + rel[k][2]*w2 + bb;
        hidden[((size_t)point*K_ + k)*C_ + c] = f2bf(fmaxf(v, 0.f));
    }
}

// ---------------- GEMM body (64x64): A dbuf-LDS, B direct-from-global frag tiles ----------------
template<int ACT, bool RES, int OMODE>
__device__ __forceinline__ void gemm_body2(const unsigned short* __restrict__ A, int sA,
                                           const unsigned short* __restrict__ Wf,
                                           const float* __restrict__ bias, int bcol0,
                                           const float* __restrict__ res,
                                           float* __restrict__ outF,
                                           unsigned short* __restrict__ outB,
                                           int sO, int on0, int m0, int K) {
    __shared__ unsigned short As[2][64][40];
    int tid = threadIdx.x;
    int wave = tid >> 6, lane = tid & 63;
    int wr = wave >> 1, wc = wave & 1;
    int nkt = K >> 5;
    f32x4 acc[2][2];
    #pragma unroll
    for (int i = 0; i < 2; ++i)
        #pragma unroll
        for (int j = 0; j < 2; ++j) acc[i][j] = (f32x4){0.f, 0.f, 0.f, 0.f};

    int r = tid >> 2, ch = tid & 3;
    const unsigned short* pA = A + (size_t)(m0 + r)*sA + ch*8;
    const unsigned short* bb = Wf + (size_t)(wc*2)*nkt*512 + lane*8;
    *(bf16x8*)&As[0][r][ch*8] = *(const bf16x8*)pA;
    bf16x8 bw0 = *(const bf16x8*)bb;
    bf16x8 bw1 = *(const bf16x8*)(bb + (size_t)nkt*512);
    __syncthreads();
    for (int t = 0; t < nkt; ++t) {
        int cur = t & 1;
        bool nx = (t + 1 < nkt);
        bf16x8 la, nb0, nb1;
        if (nx) {
            la  = *(const bf16x8*)(pA + (t+1)*32);
            nb0 = *(const bf16x8*)(bb + (size_t)(t+1)*512);
            nb1 = *(const bf16x8*)(bb + (size_t)nkt*512 + (size_t)(t+1)*512);
        }
        int kf = (lane >> 4) * 8;
        bf16x8 af0 = *(const bf16x8*)&As[cur][wr*32 + (lane & 15)][kf];
        bf16x8 af1 = *(const bf16x8*)&As[cur][wr*32 + 16 + (lane & 15)][kf];
        acc[0][0] = __builtin_amdgcn_mfma_f32_16x16x32_bf16(af0, bw0, acc[0][0], 0, 0, 0);
        acc[0][1] = __builtin_amdgcn_mfma_f32_16x16x32_bf16(af0, bw1, acc[0][1], 0, 0, 0);
        acc[1][0] = __builtin_amdgcn_mfma_f32_16x16x32_bf16(af1, bw0, acc[1][0], 0, 0, 0);
        acc[1][1] = __builtin_amdgcn_mfma_f32_16x16x32_bf16(af1, bw1, acc[1][1], 0, 0, 0);
        if (nx) *(bf16x8*)&As[cur^1][r][ch*8] = la;
        bw0 = nb0; bw1 = nb1;
        __syncthreads();
    }
    #pragma unroll
    for (int i = 0; i < 2; ++i) {
        #pragma unroll
        for (int j = 0; j < 2; ++j) {
            #pragma unroll
            for (int rg = 0; rg < 4; ++rg) {
                int m = m0 + wr*32 + i*16 + (lane >> 4)*4 + rg;
                int pl = wc*32 + j*16 + (lane & 15);
                float v = acc[i][j][rg];
                if (bias) v += bias[bcol0 + pl];
                if (ACT == 1) v = fmaxf(v, 0.f);
                if (RES) v += res[(size_t)m*sO + on0 + pl];
                if (OMODE != 2) outF[(size_t)m*sO + on0 + pl] = v;
                if (OMODE != 0) outB[(size_t)m*sO + on0 + pl] = f2bf(v);
            }
        }
    }
}

template<int ACT, bool RES, int OMODE>
__global__ __launch_bounds__(256) void gemm_k2(const unsigned short* __restrict__ A,
                                               const unsigned short* __restrict__ Wf0,
                                               const float* __restrict__ bias,
                                               const float* __restrict__ res,
                                               float* __restrict__ outF,
                                               unsigned short* __restrict__ outB,
                                               int P, int K) {
    int n0 = blockIdx.x * 64, m0 = blockIdx.y * 64;
    const unsigned short* Wf = Wf0 + (size_t)(n0 >> 4)*(K >> 5)*512;
    gemm_body2<ACT,RES,OMODE>(A, K, Wf, bias, n0, res, outF, outB, P, n0, m0, K);
}

// fused q + kv GEMM: blockIdx.x 0..3 -> q (A=t2), 4..11 -> k,v (A=out)
__global__ __launch_bounds__(256) void qkv_kernel2(const unsigned short* __restrict__ t2,
                                                   const unsigned short* __restrict__ outb,
                                                   const unsigned short* __restrict__ Fqkv_l,
                                                   const float* __restrict__ bqkv_l,
                                                   unsigned short* __restrict__ b_q,
                                                   unsigned short* __restrict__ b_kv) {
    int bx = blockIdx.x;
    int m0 = blockIdx.y * 64;
    const unsigned short* Wf = Fqkv_l + (size_t)(bx*4)*8*512;   // nkt=8 for K=256
    if (bx < 4) {
        gemm_body2<0,false,2>(t2, C_, Wf, bqkv_l, bx*64, nullptr, nullptr, b_q, 256, bx*64, m0, C_);
    } else {
        gemm_body2<0,false,2>(outb, C_, Wf, bqkv_l, bx*64, nullptr, nullptr, b_kv, 512, bx*64 - 256, m0, C_);
    }
}

// ---------------- shared LN epilogue helper (x in S[16][260], row/thread mapping fixed) ----------
// VAR 0 (Wo):   outF = x,  outT2 = bf16(LN1(x))
// VAR 1 (FFN2): outF = y1, outB = bf16(y1), outT2 = bf16(LN2(y1)+qpe)
// VAR 2 (last): outF = y1
template<int VAR>
__device__ __forceinline__ void ln_epilogue(float (*S)[260], int m0,
                                            const float* __restrict__ lnw1, const float* __restrict__ lnb1,
                                            const float* __restrict__ lnw2, const float* __restrict__ lnb2,
                                            const float* __restrict__ qpe,
                                            float* __restrict__ outF,
                                            unsigned short* __restrict__ outB,
                                            unsigned short* __restrict__ outT2) {
    int tid = threadIdx.x;
    int row = tid >> 4, g = tid & 15;
    size_t m = m0 + row;
    float x[16];
    #pragma unroll
    for (int u = 0; u < 4; ++u) {
        f32x4 v4 = *(const f32x4*)&S[row][g*16 + u*4];
        x[u*4+0] = v4[0]; x[u*4+1] = v4[1]; x[u*4+2] = v4[2]; x[u*4+3] = v4[3];
    }
    float s1 = 0.f, s2 = 0.f;
    #pragma unroll
    for (int u = 0; u < 16; ++u) { s1 += x[u]; s2 += x[u]*x[u]; }
    #pragma unroll
    for (int off = 8; off; off >>= 1) { s1 += __shfl_xor(s1, off, 16); s2 += __shfl_xor(s2, off, 16); }
    float mean = s1 * (1.f/C_);
    float var  = s2 * (1.f/C_) - mean*mean;
    float rstd = rsqrtf(var + 1e-5f);
    float y1[16];
    #pragma unroll
    for (int u = 0; u < 4; ++u) {
        f32x4 w4 = *(const f32x4*)&lnw1[g*16 + u*4];
        f32x4 b4 = *(const f32x4*)&lnb1[g*16 + u*4];
        #pragma unroll
        for (int v = 0; v < 4; ++v)
            y1[u*4+v] = (x[u*4+v] - mean)*rstd*w4[v] + b4[v];
    }
    if (VAR == 0) {
        #pragma unroll
        for (int u = 0; u < 4; ++u) {
            f32x4 v4 = { x[u*4], x[u*4+1], x[u*4+2], x[u*4+3] };
            *(f32x4*)&outF[m*C_ + g*16 + u*4] = v4;
        }
        unsigned pk[8];
        #pragma unroll
        for (int u = 0; u < 8; ++u) pk[u] = (unsigned)f2bf(y1[2*u]) | ((unsigned)f2bf(y1[2*u+1]) << 16);
        *(u32x4*)&outT2[m*C_ + g*16]     = *(u32x4*)&pk[0];
        *(u32x4*)&outT2[m*C_ + g*16 + 8] = *(u32x4*)&pk[4];
    } else {
        #pragma unroll
        for (int u = 0; u < 4; ++u) {
            f32x4 v4 = { y1[u*4], y1[u*4+1], y1[u*4+2], y1[u*4+3] };
            *(f32x4*)&outF[m*C_ + g*16 + u*4] = v4;
        }
        if (VAR == 1) {
            unsigned pk[8];
            #pragma unroll
            for (int u = 0; u < 8; ++u) pk[u] = (unsigned)f2bf(y1[2*u]) | ((unsigned)f2bf(y1[2*u+1]) << 16);
            *(u32x4*)&outB[m*C_ + g*16]     = *(u32x4*)&pk[0];
            *(u32x4*)&outB[m*C_ + g*16 + 8] = *(u32x4*)&pk[4];
            float t1 = 0.f, t2s = 0.f;
            #pragma unroll
            for (int u = 0; u < 16; ++u) { t1 += y1[u]; t2s += y1[u]*y1[u]; }
            #pragma unroll
            for (int off = 8; off; off >>= 1) { t1 += __shfl_xor(t1, off, 16); t2s += __shfl_xor(t2s, off, 16); }
            float mean2 = t1 * (1.f/C_);
            float var2  = t2s * (1.f/C_) - mean2*mean2;
            float rstd2 = rsqrtf(var2 + 1e-5f);
            unsigned pk2[8];
            #pragma unroll
            for (int u = 0; u < 4; ++u) {
                f32x4 w4 = *(const f32x4*)&lnw2[g*16 + u*4];
                f32x4 b4 = *(const f32x4*)&lnb2[g*16 + u*4];
                f32x4 q4 = *(const f32x4*)&qpe[g*16 + u*4];
                float z0 = (y1[u*4+0]-mean2)*rstd2*w4[0] + b4[0] + q4[0];
                float z1 = (y1[u*4+1]-mean2)*rstd2*w4[1] + b4[1] + q4[1];
                float z2 = (y1[u*4+2]-mean2)*rstd2*w4[2] + b4[2] + q4[2];
                float z3 = (y1[u*4+3]-mean2)*rstd2*w4[3] + b4[3] + q4[3];
                pk2[u*2]   = (unsigned)f2bf(z0) | ((unsigned)f2bf(z1) << 16);
                pk2[u*2+1] = (unsigned)f2bf(z2) | ((unsigned)f2bf(z3) << 16);
            }
            *(u32x4*)&outT2[m*C_ + g*16]     = *(u32x4*)&pk2[0];
            *(u32x4*)&outT2[m*C_ + g*16 + 8] = *(u32x4*)&pk2[4];
        }
    }
}

// ---------------- GEMM (BM=16, full P=256, B-from-global) + LN epilogue (Wo path) ----------------
template<int VAR>
__global__ __launch_bounds__(256) void gemm_ln2(const unsigned short* __restrict__ A,
                                                const unsigned short* __restrict__ Wf,
                                                const float* __restrict__ bias,
                                                const float* __restrict__ res,
                                                const float* __restrict__ lnw1, const float* __restrict__ lnb1,
                                                const float* __restrict__ lnw2, const float* __restrict__ lnb2,
                                                const float* __restrict__ qpe,
                                                float* __restrict__ outF,
                                                unsigned short* __restrict__ outB,
                                                unsigned short* __restrict__ outT2,
                                                int K) {
    __shared__ unsigned short As[2][16][40];
    __shared__ float S[16][260];
    int tid = threadIdx.x;
    int wave = tid >> 6, lane = tid & 63;
    int m0 = blockIdx.x * 16;
    int nkt = K >> 5;
    f32x4 acc[4];
    #pragma unroll
    for (int j = 0; j < 4; ++j) acc[j] = (f32x4){0.f,0.f,0.f,0.f};
    const unsigned short* pA = A + (size_t)(m0 + ((tid & 63) >> 2))*K + (tid & 3)*8;
    const unsigned short* bb = Wf + (size_t)(wave*4)*nkt*512 + lane*8;
    if (tid < 64) *(bf16x8*)&As[0][tid >> 2][(tid & 3)*8] = *(const bf16x8*)pA;
    bf16x8 bw[4];
    #pragma unroll
    for (int j = 0; j < 4; ++j) bw[j] = *(const bf16x8*)(bb + (size_t)j*nkt*512);
    __syncthreads();
    for (int t = 0; t < nkt; ++t) {
        int cur = t & 1;
        bool nx = (t + 1 < nkt);
        bf16x8 la, nb0, nb1, nb2, nb3;
        if (nx) {
            nb0 = *(const bf16x8*)(bb + (size_t)0*nkt*512 + (size_t)(t+1)*512);
            nb1 = *(const bf16x8*)(bb + (size_t)1*nkt*512 + (size_t)(t+1)*512);
            nb2 = *(const bf16x8*)(bb + (size_t)2*nkt*512 + (size_t)(t+1)*512);
            nb3 = *(const bf16x8*)(bb + (size_t)3*nkt*512 + (size_t)(t+1)*512);
            if (tid < 64) la = *(const bf16x8*)(pA + (t+1)*32);
        }
        int kf = (lane >> 4) * 8;
        bf16x8 af = *(const bf16x8*)&As[cur][lane & 15][kf];
        acc[0] = __builtin_amdgcn_mfma_f32_16x16x32_bf16(af, bw[0], acc[0], 0, 0, 0);
        acc[1] = __builtin_amdgcn_mfma_f32_16x16x32_bf16(af, bw[1], acc[1], 0, 0, 0);
        acc[2] = __builtin_amdgcn_mfma_f32_16x16x32_bf16(af, bw[2], acc[2], 0, 0, 0);
        acc[3] = __builtin_amdgcn_mfma_f32_16x16x32_bf16(af, bw[3], acc[3], 0, 0, 0);
        if (nx) {
            if (tid < 64) *(bf16x8*)&As[cur^1][tid >> 2][(tid & 3)*8] = la;
            bw[0] = nb0; bw[1] = nb1; bw[2] = nb2; bw[3] = nb3;
        }
        __syncthreads();
    }
    #pragma unroll
    for (int j = 0; j < 4; ++j) {
        int col = wave*64 + j*16 + (lane & 15);
        #pragma unroll
        for (int rg = 0; rg < 4; ++rg) {
            int row = (lane >> 4)*4 + rg;
            S[row][col] = acc[j][rg] + bias[col] + res[(size_t)(m0+row)*C_ + col];
        }
    }
    __syncthreads();
    ln_epilogue<VAR>(S, m0, lnw1, lnb1, lnw2, lnb2, qpe, outF, outB, outT2);
}

// ---------------- fused FFN: relu(t2@W1^T+b1)@W2^T+b2 + res + LN chain ----------------
// VAR 1 = mid-layer (ln_out + next ln_attn + qpe), VAR 2 = last layer (ln_out only)
template<int VAR>
__global__ __launch_bounds__(256) void ffn_ln(const unsigned short* __restrict__ t2,
                                              const unsigned short* __restrict__ F1,   // frags P=1024 K=256
                                              const float* __restrict__ b1v,
                                              const unsigned short* __restrict__ F2,   // frags P=256 K=1024
                                              const float* __restrict__ b2v,
                                              const float* __restrict__ res,
                                              const float* __restrict__ lnw1, const float* __restrict__ lnb1,
                                              const float* __restrict__ lnw2, const float* __restrict__ lnb2,
                                              const float* __restrict__ qpe,
                                              float* __restrict__ outF,
                                              unsigned short* __restrict__ outB,
                                              unsigned short* __restrict__ outT2) {
    __shared__ unsigned short tS[16][264];     // A tile (16 x 256), pad 8
    __shared__ unsigned short hS[16][1032];    // hidden (16 x 1024), pad 8 -> 2-way max conflict
    __shared__ float S[16][260];
    int tid = threadIdx.x;
    int wave = tid >> 6, lane = tid & 63;
    int m0 = blockIdx.x * 16;
    int kf = (lane >> 4) * 8;

    // stage t2 rows once
    #pragma unroll
    for (int u = 0; u < 2; ++u) {
        int id = tid + u*256;
        int rr = id >> 5, cc = id & 31;
        *(bf16x8*)&tS[rr][cc*8] = *(const bf16x8*)&t2[(size_t)(m0+rr)*C_ + cc*8];
    }
    __syncthreads();

    // phase 1: h[16][1024] in 4 passes of 256 cols; wave covers 64 cols/pass
    for (int nc = 0; nc < 4; ++nc) {
        f32x4 acc[4];
        #pragma unroll
        for (int j = 0; j < 4; ++j) acc[j] = (f32x4){0.f,0.f,0.f,0.f};
        const unsigned short* bb = F1 + ((size_t)(nc*16 + wave*4)*8)*512 + lane*8;
        #pragma unroll
        for (int t = 0; t < 8; ++t) {
            bf16x8 af = *(const bf16x8*)&tS[lane & 15][t*32 + kf];
            #pragma unroll
            for (int j = 0; j < 4; ++j) {
                bf16x8 wf = *(const bf16x8*)(bb + ((size_t)j*8 + t)*512);
                acc[j] = __builtin_amdgcn_mfma_f32_16x16x32_bf16(af, wf, acc[j], 0, 0, 0);
            }
        }
        #pragma unroll
        for (int j = 0; j < 4; ++j) {
            int col = nc*256 + wave*64 + j*16 + (lane & 15);
            float bc = b1v[col];
            #pragma unroll
            for (int rg = 0; rg < 4; ++rg) {
                int row = (lane >> 4)*4 + rg;
                hS[row][col] = f2bf(fmaxf(acc[j][rg] + bc, 0.f));
            }
        }
    }
    __syncthreads();

    // phase 2: out[16][256] = hS @ W2^T, K=1024 (nkt=32); wave covers 64 cols
    f32x4 acc2[4];
    #pragma unroll
    for (int j = 0; j < 4; ++j) acc2[j] = (f32x4){0.f,0.f,0.f,0.f};
    const unsigned short* bb2 = F2 + ((size_t)(wave*4)*32)*512 + lane*8;
    for (int t = 0; t < 32; ++t) {
        bf16x8 af = *(const bf16x8*)&hS[lane & 15][t*32 + kf];
        #pragma unroll
        for (int j = 0; j < 4; ++j) {
            bf16x8 wf = *(const bf16x8*)(bb2 + ((size_t)j*32 + t)*512);
            acc2[j] = __builtin_amdgcn_mfma_f32_16x16x32_bf16(af, wf, acc2[j], 0, 0, 0);
        }
    }
    #pragma unroll
    for (int j = 0; j < 4; ++j) {
        int col = wave*64 + j*16 + (lane & 15);
        #pragma unroll
        for (int rg = 0; rg < 4; ++rg) {
            int row = (lane >> 4)*4 + rg;
            S[row][col] = acc2[j][rg] + b2v[col] + res[(size_t)(m0+row)*C_ + col];
        }
    }
    __syncthreads();
    ln_epilogue<VAR>(S, m0, lnw1, lnb1, lnw2, lnb2, qpe, outF, outB, outT2);
}

// ---------------- r via MFMA: per-head GEMM r_h[BN x 256] = q_h[BN x 32] @ Wk_h^T ----------------
__global__ __launch_bounds__(256) void rk_kernel(const unsigned short* __restrict__ q,
                                                 const unsigned short* __restrict__ Wqkv_l,
                                                 unsigned short* __restrict__ r) {
    int n0 = blockIdx.x * 64, m0 = blockIdx.y * 64, h = blockIdx.z;
    __shared__ unsigned short As[64][40];
    __shared__ unsigned short Ws[64][40];
    int tid = threadIdx.x;
    int wave = tid >> 6, lane = tid & 63;
    int wr = wave >> 1, wc = wave & 1;
    *(bf16x8*)&As[tid>>2][(tid&3)*8] =
        *(const bf16x8*)&q[(size_t)(m0 + (tid>>2))*C_ + h*DH_ + (tid&3)*8];
    {
        int d = tid >> 3, cg = tid & 7;
        bf16x8 wv = *(const bf16x8*)&Wqkv_l[(size_t)(C_ + h*DH_ + d)*C_ + n0 + cg*8];
        #pragma unroll
        for (int j = 0; j < 8; ++j) Ws[cg*8 + j][d] = (unsigned short)wv[j];
    }
    __syncthreads();
    int kf = (lane >> 4) * 8;
    bf16x8 af[2], wf[2];
    #pragma unroll
    for (int i = 0; i < 2; ++i) af[i] = *(const bf16x8*)&As[wr*32 + i*16 + (lane & 15)][kf];
    #pragma unroll
    for (int j = 0; j < 2; ++j) wf[j] = *(const bf16x8*)&Ws[wc*32 + j*16 + (lane & 15)][kf];
    f32x4 acc[2][2];
    #pragma unroll
    for (int i = 0; i < 2; ++i)
        #pragma unroll
        for (int j = 0; j < 2; ++j)
            acc[i][j] = __builtin_amdgcn_mfma_f32_16x16x32_bf16(af[i], wf[j],
                          (f32x4){0.f,0.f,0.f,0.f}, 0, 0, 0);
    #pragma unroll
    for (int i = 0; i < 2; ++i)
        #pragma unroll
        for (int j = 0; j < 2; ++j)
            #pragma unroll
            for (int rg = 0; rg < 4; ++rg) {
                int m = m0 + wr*32 + i*16 + (lane >> 4)*4 + rg;
                int pl = wc*32 + j*16 + (lane & 15);
                r[(size_t)m*(NH_*C_) + h*C_ + n0 + pl] = f2bf(acc[i][j][rg]);
            }
}

// ---------------- attention: one WAVE per point, MFMA scores ----------------
__global__ __launch_bounds__(256) void attn_kernel(const unsigned short* __restrict__ q,
                                                   const unsigned short* __restrict__ kv,
                                                   const unsigned short* __restrict__ kpe,
                                                   const unsigned short* __restrict__ r,
                                                   const int* __restrict__ idx,
                                                   unsigned short* __restrict__ ao) {
    int wid = threadIdx.x >> 6, lane = threadIdx.x & 63;
    int point = blockIdx.x*4 + wid;
    __shared__ __align__(16) unsigned short vs[4][K_][264];
    __shared__ __align__(16) float atts[4][NH_][K_];
    int row = lane & 15;
    int off8 = (lane >> 4) * 8;
    int idx_l = idx[point*K_ + row];

    #pragma unroll
    for (int t = 0; t < 8; ++t) {
        int vr = 2*t + (lane >> 5);
        int j = __shfl(idx_l, vr, 64);
        int cc = (lane & 31) * 8;
        *(bf16x8*)&vs[wid][vr][cc] = *(const bf16x8*)&kv[(size_t)j*512 + 256 + cc];
    }

    f32x4 acc = {0.f, 0.f, 0.f, 0.f};
    const bf16x8 zero8 = {0,0,0,0,0,0,0,0};
    #pragma unroll
    for (int s = 0; s < 8; ++s) {
        bf16x8 a = *(const bf16x8*)&kpe[((size_t)point*K_ + row)*C_ + s*32 + off8];
        bf16x8 b = zero8;
        if (row < 8) b = *(const bf16x8*)&r[(size_t)point*NH_*C_ + row*C_ + s*32 + off8];
        acc = __builtin_amdgcn_mfma_f32_16x16x32_bf16(a, b, acc, 0, 0, 0);
    }
    #pragma unroll
    for (int s = 0; s < 8; ++s) {
        bf16x8 a = *(const bf16x8*)&kv[(size_t)idx_l*512 + s*32 + off8];
        bf16x8 b = zero8;
        if (row == 8 + s) b = *(const bf16x8*)&q[(size_t)point*C_ + s*32 + off8];
        acc = __builtin_amdgcn_mfma_f32_16x16x32_bf16(a, b, acc, 0, 0, 0);
    }

    const float scale = 0.1767766952966369f;
    float sv[4], m = -1e30f;
    #pragma unroll
    for (int rg = 0; rg < 4; ++rg) {
        float o = __shfl_xor(acc[rg], 8, 64);
        sv[rg] = (acc[rg] + o) * scale;
        m = fmaxf(m, sv[rg]);
    }
    m = fmaxf(m, __shfl_xor(m, 16, 64));
    m = fmaxf(m, __shfl_xor(m, 32, 64));
    float sum = 0.f;
    #pragma unroll
    for (int rg = 0; rg < 4; ++rg) { sv[rg] = __expf(sv[rg] - m); sum += sv[rg]; }
    sum += __shfl_xor(sum, 16, 64);
    sum += __shfl_xor(sum, 32, 64);
    float inv = 1.f / sum;
    if (row < 8) {
        f32x4 av = { sv[0]*inv, sv[1]*inv, sv[2]*inv, sv[3]*inv };
        *(f32x4*)&atts[wid][row][(lane >> 4) * 4] = av;
    }

    int h = lane >> 3;
    float att_f[16];
    #pragma unroll
    for (int u = 0; u < 4; ++u) {
        f32x4 t4 = *(const f32x4*)&atts[wid][h][u*4];
        att_f[u*4+0] = t4[0]; att_f[u*4+1] = t4[1]; att_f[u*4+2] = t4[2]; att_f[u*4+3] = t4[3];
    }
    int cbase = lane * 4;
    float o0 = 0.f, o1 = 0.f, o2 = 0.f, o3 = 0.f;
    #pragma unroll
    for (int k = 0; k < K_; ++k) {
        unsigned long long vv = *(const unsigned long long*)&vs[wid][k][cbase];
        unsigned lo = (unsigned)vv, hi = (unsigned)(vv >> 32);
        float a = att_f[k];
        o0 += a * __uint_as_float(lo << 16);
        o1 += a * __uint_as_float(lo & 0xffff0000u);
        o2 += a * __uint_as_float(hi << 16);
        o3 += a * __uint_as_float(hi & 0xffff0000u);
    }
    unsigned p0 = (unsigned)f2bf(o0) | ((unsigned)f2bf(o1) << 16);
    unsigned p1 = (unsigned)f2bf(o2) | ((unsigned)f2bf(o3) << 16);
    unsigned out2[2] = { p0, p1 };
    *(unsigned long long*)&ao[(size_t)point*C_ + cbase] = *(const unsigned long long*)out2;
}

extern "C" void kernel_launch(void* const* d_in, const int* in_sizes, int n_in,
                              void* d_out, int out_size, void* d_ws, size_t ws_size,
                              hipStream_t stream) {
    const float* feature  = (const float*)d_in[0];
    const float* xyz      = (const float*)d_in[1];
    const float* pe_W1    = (const float*)d_in[2];
    const float* pe_b1    = (const float*)d_in[3];
    const float* pe_W2    = (const float*)d_in[4];
    const float* pe_b2    = (const float*)d_in[5];
    const float* Wqkv     = (const float*)d_in[6];
    const float* bqkv     = (const float*)d_in[7];
    const float* Wo       = (const float*)d_in[8];
    const float* bo       = (const float*)d_in[9];
    const float* ln_attn_w= (const float*)d_in[10];
    const float* ln_attn_b= (const float*)d_in[11];
    const float* W1       = (const float*)d_in[12];
    const float* b1       = (const float*)d_in[13];
    const float* W2       = (const float*)d_in[14];
    const float* b2       = (const float*)d_in[15];
    const float* ln_ffn_w = (const float*)d_in[16];
    const float* ln_ffn_b = (const float*)d_in[17];
    const float* ln_out_w = (const float*)d_in[18];
    const float* ln_out_b = (const float*)d_in[19];

    // ---- workspace layout ----
    float* ws = (float*)d_ws;
    float* w_out = ws;                                   // BN*C fp32
    float* w_qpe = w_out + (size_t)BN_*C_;               // C fp32
    unsigned short* bptr = (unsigned short*)(w_qpe + C_ + 64);
    unsigned short* b_out = bptr;  bptr += (size_t)BN_*C_;
    unsigned short* b_t2  = bptr;  bptr += (size_t)BN_*C_;
    unsigned short* b_q   = bptr;  bptr += (size_t)BN_*C_;
    unsigned short* b_kv  = bptr;  bptr += (size_t)BN_*512;
    unsigned short* b_ao  = bptr;  bptr += (size_t)BN_*C_;
    unsigned short* w_kpe = bptr;  bptr += (size_t)BN_*K_*C_;
    unsigned short* w_r   = bptr;  bptr += (size_t)BN_*NH_*C_;
    unsigned short* b_hid = bptr;  bptr += (size_t)BN_*K_*C_;
    unsigned short* bWqkv = bptr;  bptr += (size_t)L_*3*C_*C_;   // row-major (rk)
    unsigned short* Fqkv  = bptr;  bptr += (size_t)L_*3*C_*C_;   // frag tiles
    unsigned short* Fo    = bptr;  bptr += (size_t)L_*C_*C_;
    unsigned short* F1    = bptr;  bptr += (size_t)L_*FF_*C_;
    unsigned short* F2    = bptr;  bptr += (size_t)L_*C_*FF_;
    unsigned short* Fpe   = bptr;  bptr += (size_t)C_*C_;
    int* w_idx = (int*)bptr;

    // ---- weight conversions ----
    f2bf_kernel<<<(L_*3*C_*C_+255)/256, 256, 0, stream>>>(Wqkv, bWqkv, L_*3*C_*C_);
    w2frag_kernel<<<(L_*3*C_*C_/512)/4, 256, 0, stream>>>(Wqkv, Fqkv, L_*3*C_, C_);
    w2frag_kernel<<<(L_*C_*C_/512)/4,   256, 0, stream>>>(Wo,   Fo,   L_*C_,   C_);
    w2frag_kernel<<<(L_*FF_*C_/512)/4,  256, 0, stream>>>(W1,   F1,   L_*FF_,  C_);
    w2frag_kernel<<<(L_*C_*FF_/512)/4,  256, 0, stream>>>(W2,   F2,   L_*C_,   FF_);
    w2frag_kernel<<<(C_*C_/512)/4,      256, 0, stream>>>(pe_W2, Fpe, C_,      C_);

    // ---- preprocessing ----
    knn_kernel<<<BN_/4, 256, 0, stream>>>(xyz, w_idx);
    qpe_kernel<<<1, 256, 0, stream>>>(pe_b1, pe_W2, pe_b2, w_qpe);
    reshape_in_ln<<<BN_, 256, 0, stream>>>(feature, ln_attn_w, ln_attn_b, w_qpe,
                                           w_out, b_out, b_t2);
    pe_hidden_kernel<<<BN_, 256, 0, stream>>>(xyz, w_idx, pe_W1, pe_b1, b_hid);
    gemm_k2<0,false,2><<<dim3(C_/64, (BN_*K_)/64), 256, 0, stream>>>(
        b_hid, Fpe, pe_b2, nullptr, nullptr, w_kpe, C_, C_);

    // ---- layers ----
    for (int i = 0; i < L_; ++i) {
        const unsigned short* Fqkv_l = Fqkv + (size_t)i*3*C_*C_;
        const float* bqkv_l = bqkv + (size_t)i*3*C_;

        qkv_kernel2<<<dim3(12, BN_/64), 256, 0, stream>>>(b_t2, b_out, Fqkv_l, bqkv_l, b_q, b_kv);
        rk_kernel<<<dim3(4, BN_/64, NH_), 256, 0, stream>>>(b_q, bWqkv + (size_t)i*3*C_*C_, w_r);
        attn_kernel<<<BN_/4, 256, 0, stream>>>(b_q, b_kv, w_kpe, w_r, w_idx, b_ao);
        gemm_ln2<0><<<BN_/16, 256, 0, stream>>>(
            b_ao, Fo + (size_t)i*C_*C_, bo + i*C_, w_out,
            ln_ffn_w + i*C_, ln_ffn_b + i*C_, nullptr, nullptr, nullptr,
            w_out, nullptr, b_t2, C_);
        if (i < L_-1) {
            ffn_ln<1><<<BN_/16, 256, 0, stream>>>(
                b_t2, F1 + (size_t)i*FF_*C_, b1 + i*FF_,
                F2 + (size_t)i*C_*FF_, b2 + i*C_, w_out,
                ln_out_w + i*C_, ln_out_b + i*C_,
                ln_attn_w + (i+1)*C_, ln_attn_b + (i+1)*C_, w_qpe,
                w_out, b_out, b_t2);
        } else {
            ffn_ln<2><<<BN_/16, 256, 0, stream>>>(
                b_t2, F1 + (size_t)i*FF_*C_, b1 + i*FF_,
                F2 + (size_t)i*C_*FF_, b2 + i*C_, w_out,
                ln_out_w + i*C_, ln_out_b + i*C_, nullptr, nullptr, nullptr,
                w_out, nullptr, nullptr);
        }
    }

    reshape_out_kernel<<<BN_, 256, 0, stream>>>(w_out, (float*)d_out);
}